// Round 5
// baseline (270.427 us; speedup 1.0000x reference)
//
#include <hip/hip_runtime.h>
#include <hip/hip_bf16.h>

#define B_  32
#define C_  1024
#define N_  256
#define DQ_ 64

typedef __bf16 bf16_t;
typedef __bf16 bf16x8 __attribute__((ext_vector_type(8)));
typedef float  f32x4  __attribute__((ext_vector_type(4)));

static __device__ __forceinline__ f32x4 mfma16(bf16x8 a, bf16x8 b, f32x4 c) {
  return __builtin_amdgcn_mfma_f32_16x16x32_bf16(a, b, c, 0, 0, 0);
}

static __device__ __forceinline__ bf16x8 ldcvt(const float* p) {
  const float4 a = *(const float4*)p;
  const float4 b = *(const float4*)(p + 4);
  bf16x8 r;
  r[0] = (bf16_t)a.x; r[1] = (bf16_t)a.y; r[2] = (bf16_t)a.z; r[3] = (bf16_t)a.w;
  r[4] = (bf16_t)b.x; r[5] = (bf16_t)b.y; r[6] = (bf16_t)b.z; r[7] = (bf16_t)b.w;
  return r;
}

// Swizzled global->LDS staging: each wave stages 32 rows of 64 bf16 (128 B) via
// 4 x global_load_lds(16B). Row r, slot j (16B chunks) holds global chunk
// (j - r) & 7, so frag ds_read_b128 across l16 lands 2 lanes/bank-group (free).
static __device__ __forceinline__ void stage32(const bf16_t* grow0, size_t gstride,
                                               bf16_t* tile, int wave, int lane) {
#pragma unroll
  for (int t = 0; t < 4; ++t) {
    const int rb = wave * 32 + t * 8;
    const int r  = rb + (lane >> 3);
    const int g  = ((lane & 7) - r) & 7;
    const bf16_t* src = grow0 + (size_t)r * gstride + g * 8;
    __builtin_amdgcn_global_load_lds(
        (const __attribute__((address_space(1))) void*)src,
        (__attribute__((address_space(3))) void*)(tile + rb * 64), 16, 0, 0);
  }
}

// ---------------- Kernel T: x (B,C,N) f32 -> xT (B,N,C) bf16 ----------------
__global__ __launch_bounds__(256) void k_trans(const float* __restrict__ x,
                                               bf16_t* __restrict__ xT) {
  __shared__ bf16_t tile[32][34];
  const int b  = blockIdx.z;
  const int n0 = blockIdx.x * 32, c0 = blockIdx.y * 32;
  const int tx = threadIdx.x, ty = threadIdx.y;
  const float* xb = x + (size_t)b * C_ * N_;
  bf16_t*     xtb = xT + (size_t)b * N_ * C_;
#pragma unroll
  for (int i = 0; i < 4; ++i)
    tile[ty + i * 8][tx] = (bf16_t)xb[(size_t)(c0 + ty + i * 8) * N_ + (n0 + tx)];
  __syncthreads();
#pragma unroll
  for (int i = 0; i < 4; ++i)
    xtb[(size_t)(n0 + ty + i * 8) * C_ + (c0 + tx)] = tile[tx][ty + i * 8];
}

// ---------------- Kernel CVT: Wv, Wq, Wk f32 -> bf16 ----------------
__global__ __launch_bounds__(256) void k_cvt(const float* __restrict__ Wv,
                                             const float* __restrict__ Wq,
                                             const float* __restrict__ Wk,
                                             bf16_t* __restrict__ Wvb,
                                             bf16_t* __restrict__ Wqkb) {
  const int gid = blockIdx.x * 256 + threadIdx.x;
  if (blockIdx.x < 512) {
    const int i = gid * 8;
    *(bf16x8*)(Wvb + i) = ldcvt(Wv + i);
  } else {
    const int g2 = (gid - 512 * 256) * 8;
    if (g2 < 16384) *(bf16x8*)(Wqkb + g2) = ldcvt(Wq + g2);
    else            *(bf16x8*)(Wqkb + g2) = ldcvt(Wk + (g2 - 16384));
  }
}

// ---------------- Kernel 1: fused q+k projection ----------------
__global__ __launch_bounds__(256) void k_qk(const float* __restrict__ x,
                                            const bf16_t* __restrict__ Wqkb,
                                            const float* __restrict__ g1,
                                            const float* __restrict__ b1,
                                            const float* __restrict__ m1,
                                            const float* __restrict__ v1,
                                            const float* __restrict__ g2,
                                            const float* __restrict__ b2,
                                            const float* __restrict__ m2,
                                            const float* __restrict__ v2,
                                            bf16_t* __restrict__ qt,
                                            bf16_t* __restrict__ kt) {
  const int tid  = threadIdx.x;
  const int wave = tid >> 6;
  const int lane = tid & 63;
  const int quad = lane >> 4;
  const int l16  = lane & 15;
  const int b    = blockIdx.y;
  const int c16  = blockIdx.x * 64 + wave * 16;
  const float* xb = x + (size_t)b * C_ * N_;

  f32x4 acc[8];
#pragma unroll
  for (int i = 0; i < 8; ++i) acc[i] = (f32x4){0.f, 0.f, 0.f, 0.f};

  for (int ks = 0; ks < 8; ++ks) {
    const int k0 = ks * 32 + quad * 8;
    const bf16x8 bx = ldcvt(xb + (size_t)(c16 + l16) * N_ + k0);
#pragma unroll
    for (int i = 0; i < 8; ++i) {
      const bf16x8 aw = *(const bf16x8*)(Wqkb + (size_t)(i * 16 + l16) * N_ + k0);
      acc[i] = mfma16(aw, bx, acc[i]);
    }
  }

#pragma unroll
  for (int i = 0; i < 8; ++i) {
    const bool isq = (i < 4);
    bf16_t* dst = isq ? qt : kt;
#pragma unroll
    for (int r = 0; r < 4; ++r) {
      const int o = (i & 3) * 16 + quad * 4 + r;
      const float sc = (isq ? g1[o] : g2[o]) * rsqrtf((isq ? v1[o] : v2[o]) + 1e-5f);
      const float mm = isq ? m1[o] : m2[o];
      const float bt = isq ? b1[o] : b2[o];
      const int c = c16 + l16;
      float y = (acc[i][r] - mm) * sc + bt;
      y = fmaxf(y, 0.f);
      dst[((size_t)b * C_ + c) * DQ_ + o] = (bf16_t)y;
    }
  }
}

// ---------------- Kernel 2: v GEMM, m97-style staged (flat 8192x1024x1024) ----
__global__ __launch_bounds__(256, 2) void k_vgemm(const bf16_t* __restrict__ Wvb,
                                                  const bf16_t* __restrict__ xT,
                                                  const float* __restrict__ g,
                                                  const float* __restrict__ be,
                                                  const float* __restrict__ mu,
                                                  const float* __restrict__ va,
                                                  bf16_t* __restrict__ vT) {
  __shared__ __align__(16) bf16_t As[2][128 * 64];
  __shared__ __align__(16) bf16_t Bs[2][128 * 64];
  const int tid  = threadIdx.x;
  const int wave = tid >> 6;
  const int lane = tid & 63;
  const int quad = lane >> 4;
  const int l16  = lane & 15;
  const int o0 = blockIdx.x * 128;
  const int r0 = blockIdx.y * 128;   // flat row = b*N_ + n
  const bf16_t* Ab = Wvb + (size_t)o0 * C_;
  const bf16_t* Bb = xT + (size_t)r0 * C_;
  const int wr = (wave >> 1) * 64, wc = (wave & 1) * 64;

  stage32(Ab, C_, (bf16_t*)As[0], wave, lane);
  stage32(Bb, C_, (bf16_t*)Bs[0], wave, lane);

  f32x4 acc[4][4];
#pragma unroll
  for (int i = 0; i < 4; ++i)
#pragma unroll
    for (int j = 0; j < 4; ++j) acc[i][j] = (f32x4){0.f, 0.f, 0.f, 0.f};

  for (int ks = 0; ks < 16; ++ks) {
    __syncthreads();
    const bf16_t* ca = As[ks & 1];
    const bf16_t* cb = Bs[ks & 1];
    if (ks < 15) {
      stage32(Ab + (ks + 1) * 64, C_, (bf16_t*)As[(ks + 1) & 1], wave, lane);
      stage32(Bb + (ks + 1) * 64, C_, (bf16_t*)Bs[(ks + 1) & 1], wave, lane);
    }
#pragma unroll
    for (int ksub = 0; ksub < 2; ++ksub) {
      bf16x8 a[4], bfr[4];
#pragma unroll
      for (int i = 0; i < 4; ++i) {
        const int r = wr + i * 16 + l16;
        const int s = ((ksub * 4 + quad) + r) & 7;
        a[i] = *(const bf16x8*)(ca + r * 64 + s * 8);
      }
#pragma unroll
      for (int j = 0; j < 4; ++j) {
        const int r = wc + j * 16 + l16;
        const int s = ((ksub * 4 + quad) + r) & 7;
        bfr[j] = *(const bf16x8*)(cb + r * 64 + s * 8);
      }
#pragma unroll
      for (int i = 0; i < 4; ++i)
#pragma unroll
        for (int j = 0; j < 4; ++j)
          acc[i][j] = mfma16(a[i], bfr[j], acc[i][j]);
    }
  }

#pragma unroll
  for (int i = 0; i < 4; ++i)
#pragma unroll
    for (int r = 0; r < 4; ++r) {
      const int o = o0 + wr + i * 16 + quad * 4 + r;
      const float sc = g[o] * rsqrtf(va[o] + 1e-5f);
      const float mm = mu[o], bt = be[o];
#pragma unroll
      for (int j = 0; j < 4; ++j) {
        const int rG = r0 + wc + j * 16 + l16;
        float y = (acc[i][j][r] - mm) * sc + bt;
        y = fmaxf(y, 0.f);
        vT[(size_t)rG * C_ + o] = (bf16_t)y;
      }
    }
}

// ---------------- Kernel 3: fused sim -> softmax -> out ----------------
// 512 thr / 8 waves. Direct global loads (L2-resident Q/V), explicit 4-slot
// rotating register prefetch in Phase C (fully unrolled, static indices) and
// batched per-t loads in Phase A. Standard __syncthreads barriers (safe);
// Phase C itself is barrier-free. LDS = ebuf only -> 2 blocks/CU.
// ebuf: 32x1024 bf16, chunk-rotated (slot = (chunk + c) & 7 within 8-chunk groups).
static __device__ __forceinline__ int eaddr(int c, int d) {
  const int ch = d >> 3;
  const int ph = (ch & ~7) | ((ch + c) & 7);
  return (c << 10) + (ph << 3) + (d & 7);
}

__global__ __launch_bounds__(512, 4) void k_fused(const bf16_t* __restrict__ qt,
                                                  const bf16_t* __restrict__ kt,
                                                  const bf16_t* __restrict__ vT,
                                                  const float* __restrict__ x,
                                                  const float* __restrict__ alphap,
                                                  float* __restrict__ out) {
  __shared__ __align__(16) bf16_t ebuf[32 * 1024];
  __shared__ float redmin[8][32];
  __shared__ float redsum[8][32];
  __shared__ float rowmin[32];
  __shared__ float rowrinv[32];

  const int tid  = threadIdx.x;
  const int wave = tid >> 6;
  const int lane = tid & 63;
  const int quad = lane >> 4;
  const int l16  = lane & 15;
  const int id   = blockIdx.x;
  const int b    = ((id & 7) << 2) | (id >> 8);        // 32 blocks/batch on one XCD
  const int c0   = ((id >> 3) & 31) << 5;

  const bf16_t* qb  = qt + (size_t)b * C_ * DQ_;
  const bf16_t* ktb = kt + ((size_t)b * C_ + c0) * DQ_;

  bf16x8 am[2][2];
#pragma unroll
  for (int i = 0; i < 2; ++i)
#pragma unroll
    for (int ksub = 0; ksub < 2; ++ksub)
      am[i][ksub] = *(const bf16x8*)(ktb + (size_t)(i * 16 + l16) * DQ_ + ksub * 32 + quad * 8);

  // ---- Phase A: sim (32 c x 1024 d), Q direct from global (L2) ----
  // Fully unrolled; per-t loads batched ahead of the MFMAs.
  const bf16_t* qrow = qb + (size_t)(wave * 32 + l16) * DQ_ + quad * 8;
  f32x4 sim[2][8];
#pragma unroll
  for (int i = 0; i < 2; ++i)
#pragma unroll
    for (int nt = 0; nt < 8; ++nt) sim[i][nt] = (f32x4){0.f, 0.f, 0.f, 0.f};

#pragma unroll
  for (int t = 0; t < 4; ++t) {
    bf16x8 bq[2][2];
#pragma unroll
    for (int jn = 0; jn < 2; ++jn)
#pragma unroll
      for (int ksub = 0; ksub < 2; ++ksub)
        bq[jn][ksub] = *(const bf16x8*)(qrow + (size_t)(t * 256 + jn * 16) * DQ_ + ksub * 32);
#pragma unroll
    for (int jn = 0; jn < 2; ++jn)
#pragma unroll
      for (int ksub = 0; ksub < 2; ++ksub) {
        sim[0][t * 2 + jn] = mfma16(am[0][ksub], bq[jn][ksub], sim[0][t * 2 + jn]);
        sim[1][t * 2 + jn] = mfma16(am[1][ksub], bq[jn][ksub], sim[1][t * 2 + jn]);
      }
  }

  // ---- Phase C register-prefetch bases + prologue (issued before Phase B) ----
  const bf16_t* vb  = vT + (size_t)b * N_ * C_;
  const bf16_t* rb0 = vb + (size_t)(wave * 32 + l16) * C_ + quad * 8;
  const bf16_t* rb1 = rb0 + (size_t)16 * C_;
  bf16x8 vp[4][2][2];
#define LOADV(SLOT, KS) do { \
    vp[SLOT][0][0] = *(const bf16x8*)(rb0 + (KS) * 64); \
    vp[SLOT][0][1] = *(const bf16x8*)(rb0 + (KS) * 64 + 32); \
    vp[SLOT][1][0] = *(const bf16x8*)(rb1 + (KS) * 64); \
    vp[SLOT][1][1] = *(const bf16x8*)(rb1 + (KS) * 64 + 32); \
  } while (0)
  LOADV(0, 0);
  LOADV(1, 1);

  // ---- Phase B: row-min shift, exp, row-sum ----
  float pmin[2][4];
#pragma unroll
  for (int i = 0; i < 2; ++i)
#pragma unroll
    for (int r = 0; r < 4; ++r) pmin[i][r] = sim[i][0][r];
#pragma unroll
  for (int nt = 1; nt < 8; ++nt)
#pragma unroll
    for (int i = 0; i < 2; ++i)
#pragma unroll
      for (int r = 0; r < 4; ++r) pmin[i][r] = fminf(pmin[i][r], sim[i][nt][r]);
#pragma unroll
  for (int m = 1; m < 16; m <<= 1)
#pragma unroll
    for (int i = 0; i < 2; ++i)
#pragma unroll
      for (int r = 0; r < 4; ++r) pmin[i][r] = fminf(pmin[i][r], __shfl_xor(pmin[i][r], m));
  if (l16 == 0)
#pragma unroll
    for (int i = 0; i < 2; ++i)
#pragma unroll
      for (int r = 0; r < 4; ++r) redmin[wave][i * 16 + quad * 4 + r] = pmin[i][r];
  __syncthreads();
  if (tid < 32) {
    float v = redmin[0][tid];
#pragma unroll
    for (int w = 1; w < 8; ++w) v = fminf(v, redmin[w][tid]);
    rowmin[tid] = v;
  }
  __syncthreads();

  float mn[2][4], psum[2][4];
#pragma unroll
  for (int i = 0; i < 2; ++i)
#pragma unroll
    for (int r = 0; r < 4; ++r) {
      mn[i][r] = rowmin[i * 16 + quad * 4 + r];
      psum[i][r] = 0.f;
    }
#pragma unroll
  for (int nt = 0; nt < 8; ++nt) {
    const int d = ((nt >> 1) << 8) + wave * 32 + ((nt & 1) << 4) + l16;
#pragma unroll
    for (int i = 0; i < 2; ++i)
#pragma unroll
      for (int r = 0; r < 4; ++r) {
        const int c = i * 16 + quad * 4 + r;
        const float e = __expf(mn[i][r] - sim[i][nt][r]);
        ebuf[eaddr(c, d)] = (bf16_t)e;
        psum[i][r] += e;
      }
  }
#pragma unroll
  for (int m = 1; m < 16; m <<= 1)
#pragma unroll
    for (int i = 0; i < 2; ++i)
#pragma unroll
      for (int r = 0; r < 4; ++r) psum[i][r] += __shfl_xor(psum[i][r], m);
  if (l16 == 0)
#pragma unroll
    for (int i = 0; i < 2; ++i)
#pragma unroll
      for (int r = 0; r < 4; ++r) redsum[wave][i * 16 + quad * 4 + r] = psum[i][r];
  __syncthreads();
  if (tid < 32) {
    float s = redsum[0][tid];
#pragma unroll
    for (int w = 1; w < 8; ++w) s += redsum[w][tid];
    rowrinv[tid] = 1.f / s;
  }
  __syncthreads();   // ebuf + rowrinv ready for Phase C / epilogue

  // ---- Phase C: out = e @ vT, 4-slot rotating register prefetch, no barriers --
  f32x4 oacc[2][2];
#pragma unroll
  for (int i = 0; i < 2; ++i)
#pragma unroll
    for (int jn = 0; jn < 2; ++jn) oacc[i][jn] = (f32x4){0.f, 0.f, 0.f, 0.f};

  LOADV(2, 2);
#pragma unroll
  for (int ks = 0; ks < 16; ++ks) {
    if (ks + 3 < 16) {
      switch ((ks + 3) & 3) {      // static slot after unroll
        case 0: LOADV(0, ks + 3); break;
        case 1: LOADV(1, ks + 3); break;
        case 2: LOADV(2, ks + 3); break;
        default: LOADV(3, ks + 3); break;
      }
    }
    const int slot = ks & 3;
#pragma unroll
    for (int ksub = 0; ksub < 2; ++ksub) {
      const int gch = ks * 8 + ksub * 4 + quad;
      const int ph  = (gch & ~7) | ((gch + l16) & 7);
      const bf16x8 ae0 = *(const bf16x8*)(ebuf + ((size_t)l16 << 10) + ph * 8);
      const bf16x8 ae1 = *(const bf16x8*)(ebuf + ((size_t)(16 + l16) << 10) + ph * 8);
#pragma unroll
      for (int jn = 0; jn < 2; ++jn) {
        oacc[0][jn] = mfma16(ae0, vp[slot][jn][ksub], oacc[0][jn]);
        oacc[1][jn] = mfma16(ae1, vp[slot][jn][ksub], oacc[1][jn]);
      }
    }
  }
#undef LOADV

  const float alpha = alphap[0];
#pragma unroll
  for (int i = 0; i < 2; ++i)
#pragma unroll
    for (int jn = 0; jn < 2; ++jn)
#pragma unroll
      for (int r = 0; r < 4; ++r) {
        const int c = c0 + i * 16 + quad * 4 + r;
        const int n = wave * 32 + jn * 16 + l16;
        const size_t idx = ((size_t)b * C_ + c) * N_ + n;
        out[idx] = alpha * (oacc[i][jn][r] * rowrinv[i * 16 + quad * 4 + r]) + x[idx];
      }
}

extern "C" void kernel_launch(void* const* d_in, const int* in_sizes, int n_in,
                              void* d_out, int out_size, void* d_ws, size_t ws_size,
                              hipStream_t stream) {
  const float* x    = (const float*)d_in[0];
  const float* Wq   = (const float*)d_in[1];
  const float* Wk   = (const float*)d_in[2];
  const float* Wv   = (const float*)d_in[3];
  const float* bn1g = (const float*)d_in[4];
  const float* bn1b = (const float*)d_in[5];
  const float* bn1m = (const float*)d_in[6];
  const float* bn1v = (const float*)d_in[7];
  const float* bn2g = (const float*)d_in[8];
  const float* bn2b = (const float*)d_in[9];
  const float* bn2m = (const float*)d_in[10];
  const float* bn2v = (const float*)d_in[11];
  const float* bn3g = (const float*)d_in[12];
  const float* bn3b = (const float*)d_in[13];
  const float* bn3m = (const float*)d_in[14];
  const float* bn3v = (const float*)d_in[15];
  const float* alph = (const float*)d_in[16];
  float* outp = (float*)d_out;

  char* ws = (char*)d_ws;
  bf16_t* qt   = (bf16_t*)(ws);                              // 4 MiB  (B,C,DQ)
  bf16_t* kt   = (bf16_t*)(ws + (size_t)(4u << 20));         // 4 MiB  (B,C,DQ)
  bf16_t* vT   = (bf16_t*)(ws + (size_t)(8u << 20));         // 16 MiB (B,N,C)
  bf16_t* xT   = (bf16_t*)(ws + (size_t)(24u << 20));        // 16 MiB (B,N,C)
  bf16_t* Wvb  = (bf16_t*)(ws + (size_t)(40u << 20));        // 2 MiB  (C,C)
  bf16_t* Wqkb = (bf16_t*)(ws + (size_t)(42u << 20));        // 64 KiB (128,N)

  k_trans<<<dim3(8, 32, 32), dim3(32, 8, 1), 0, stream>>>(x, xT);
  k_cvt<<<dim3(528), 256, 0, stream>>>(Wv, Wq, Wk, Wvb, Wqkb);
  k_qk<<<dim3(16, 32), 256, 0, stream>>>(x, Wqkb,
                                         bn1g, bn1b, bn1m, bn1v,
                                         bn2g, bn2b, bn2m, bn2v, qt, kt);
  k_vgemm<<<dim3(8, 64), 256, 0, stream>>>(Wvb, xT, bn3g, bn3b, bn3m, bn3v, vT);
  k_fused<<<dim3(1024), 512, 0, stream>>>(qt, kt, vT, x, alph, outp);
}

// Round 6
// 233.671 us; speedup vs baseline: 1.1573x; 1.1573x over previous
//
#include <hip/hip_runtime.h>
#include <hip/hip_bf16.h>

#define B_  32
#define C_  1024
#define N_  256
#define DQ_ 64

typedef __bf16 bf16_t;
typedef __bf16 bf16x8 __attribute__((ext_vector_type(8)));
typedef float  f32x4  __attribute__((ext_vector_type(4)));

static __device__ __forceinline__ f32x4 mfma16(bf16x8 a, bf16x8 b, f32x4 c) {
  return __builtin_amdgcn_mfma_f32_16x16x32_bf16(a, b, c, 0, 0, 0);
}

static __device__ __forceinline__ bf16x8 ldcvt(const float* p) {
  const float4 a = *(const float4*)p;
  const float4 b = *(const float4*)(p + 4);
  bf16x8 r;
  r[0] = (bf16_t)a.x; r[1] = (bf16_t)a.y; r[2] = (bf16_t)a.z; r[3] = (bf16_t)a.w;
  r[4] = (bf16_t)b.x; r[5] = (bf16_t)b.y; r[6] = (bf16_t)b.z; r[7] = (bf16_t)b.w;
  return r;
}

// Swizzled global->LDS staging: each wave stages 32 rows of 64 bf16 (128 B) via
// 4 x global_load_lds(16B). Row r, slot j (16B chunks) holds global chunk
// (j - r) & 7, so frag ds_read_b128 across l16 lands 2 lanes/bank-group (free).
// NOTE: wave w touches only rows [w*32, w*32+32) of the tile -> per-wave private.
static __device__ __forceinline__ void stage32(const bf16_t* grow0, size_t gstride,
                                               bf16_t* tile, int wave, int lane) {
#pragma unroll
  for (int t = 0; t < 4; ++t) {
    const int rb = wave * 32 + t * 8;
    const int r  = rb + (lane >> 3);
    const int g  = ((lane & 7) - r) & 7;
    const bf16_t* src = grow0 + (size_t)r * gstride + g * 8;
    __builtin_amdgcn_global_load_lds(
        (const __attribute__((address_space(1))) void*)src,
        (__attribute__((address_space(3))) void*)(tile + rb * 64), 16, 0, 0);
  }
}

// ---------------- Kernel T: x (B,C,N) f32 -> xT (B,N,C) bf16 ----------------
__global__ __launch_bounds__(256) void k_trans(const float* __restrict__ x,
                                               bf16_t* __restrict__ xT) {
  __shared__ bf16_t tile[32][34];
  const int b  = blockIdx.z;
  const int n0 = blockIdx.x * 32, c0 = blockIdx.y * 32;
  const int tx = threadIdx.x, ty = threadIdx.y;
  const float* xb = x + (size_t)b * C_ * N_;
  bf16_t*     xtb = xT + (size_t)b * N_ * C_;
#pragma unroll
  for (int i = 0; i < 4; ++i)
    tile[ty + i * 8][tx] = (bf16_t)xb[(size_t)(c0 + ty + i * 8) * N_ + (n0 + tx)];
  __syncthreads();
#pragma unroll
  for (int i = 0; i < 4; ++i)
    xtb[(size_t)(n0 + ty + i * 8) * C_ + (c0 + tx)] = tile[tx][ty + i * 8];
}

// ---------------- Kernel CVT: Wv, Wq, Wk f32 -> bf16 ----------------
__global__ __launch_bounds__(256) void k_cvt(const float* __restrict__ Wv,
                                             const float* __restrict__ Wq,
                                             const float* __restrict__ Wk,
                                             bf16_t* __restrict__ Wvb,
                                             bf16_t* __restrict__ Wqkb) {
  const int gid = blockIdx.x * 256 + threadIdx.x;
  if (blockIdx.x < 512) {
    const int i = gid * 8;
    *(bf16x8*)(Wvb + i) = ldcvt(Wv + i);
  } else {
    const int g2 = (gid - 512 * 256) * 8;
    if (g2 < 16384) *(bf16x8*)(Wqkb + g2) = ldcvt(Wq + g2);
    else            *(bf16x8*)(Wqkb + g2) = ldcvt(Wk + (g2 - 16384));
  }
}

// ---------------- Kernel 1: fused q+k projection ----------------
__global__ __launch_bounds__(256) void k_qk(const float* __restrict__ x,
                                            const bf16_t* __restrict__ Wqkb,
                                            const float* __restrict__ g1,
                                            const float* __restrict__ b1,
                                            const float* __restrict__ m1,
                                            const float* __restrict__ v1,
                                            const float* __restrict__ g2,
                                            const float* __restrict__ b2,
                                            const float* __restrict__ m2,
                                            const float* __restrict__ v2,
                                            bf16_t* __restrict__ qt,
                                            bf16_t* __restrict__ kt) {
  const int tid  = threadIdx.x;
  const int wave = tid >> 6;
  const int lane = tid & 63;
  const int quad = lane >> 4;
  const int l16  = lane & 15;
  const int b    = blockIdx.y;
  const int c16  = blockIdx.x * 64 + wave * 16;
  const float* xb = x + (size_t)b * C_ * N_;

  f32x4 acc[8];
#pragma unroll
  for (int i = 0; i < 8; ++i) acc[i] = (f32x4){0.f, 0.f, 0.f, 0.f};

  for (int ks = 0; ks < 8; ++ks) {
    const int k0 = ks * 32 + quad * 8;
    const bf16x8 bx = ldcvt(xb + (size_t)(c16 + l16) * N_ + k0);
#pragma unroll
    for (int i = 0; i < 8; ++i) {
      const bf16x8 aw = *(const bf16x8*)(Wqkb + (size_t)(i * 16 + l16) * N_ + k0);
      acc[i] = mfma16(aw, bx, acc[i]);
    }
  }

#pragma unroll
  for (int i = 0; i < 8; ++i) {
    const bool isq = (i < 4);
    bf16_t* dst = isq ? qt : kt;
#pragma unroll
    for (int r = 0; r < 4; ++r) {
      const int o = (i & 3) * 16 + quad * 4 + r;
      const float sc = (isq ? g1[o] : g2[o]) * rsqrtf((isq ? v1[o] : v2[o]) + 1e-5f);
      const float mm = isq ? m1[o] : m2[o];
      const float bt = isq ? b1[o] : b2[o];
      const int c = c16 + l16;
      float y = (acc[i][r] - mm) * sc + bt;
      y = fmaxf(y, 0.f);
      dst[((size_t)b * C_ + c) * DQ_ + o] = (bf16_t)y;
    }
  }
}

// ---------------- Kernel 2: v GEMM, m97-style staged (flat 8192x1024x1024) ----
__global__ __launch_bounds__(256, 2) void k_vgemm(const bf16_t* __restrict__ Wvb,
                                                  const bf16_t* __restrict__ xT,
                                                  const float* __restrict__ g,
                                                  const float* __restrict__ be,
                                                  const float* __restrict__ mu,
                                                  const float* __restrict__ va,
                                                  bf16_t* __restrict__ vT) {
  __shared__ __align__(16) bf16_t As[2][128 * 64];
  __shared__ __align__(16) bf16_t Bs[2][128 * 64];
  const int tid  = threadIdx.x;
  const int wave = tid >> 6;
  const int lane = tid & 63;
  const int quad = lane >> 4;
  const int l16  = lane & 15;
  const int o0 = blockIdx.x * 128;
  const int r0 = blockIdx.y * 128;   // flat row = b*N_ + n
  const bf16_t* Ab = Wvb + (size_t)o0 * C_;
  const bf16_t* Bb = xT + (size_t)r0 * C_;
  const int wr = (wave >> 1) * 64, wc = (wave & 1) * 64;

  stage32(Ab, C_, (bf16_t*)As[0], wave, lane);
  stage32(Bb, C_, (bf16_t*)Bs[0], wave, lane);

  f32x4 acc[4][4];
#pragma unroll
  for (int i = 0; i < 4; ++i)
#pragma unroll
    for (int j = 0; j < 4; ++j) acc[i][j] = (f32x4){0.f, 0.f, 0.f, 0.f};

  for (int ks = 0; ks < 16; ++ks) {
    __syncthreads();
    const bf16_t* ca = As[ks & 1];
    const bf16_t* cb = Bs[ks & 1];
    if (ks < 15) {
      stage32(Ab + (ks + 1) * 64, C_, (bf16_t*)As[(ks + 1) & 1], wave, lane);
      stage32(Bb + (ks + 1) * 64, C_, (bf16_t*)Bs[(ks + 1) & 1], wave, lane);
    }
#pragma unroll
    for (int ksub = 0; ksub < 2; ++ksub) {
      bf16x8 a[4], bfr[4];
#pragma unroll
      for (int i = 0; i < 4; ++i) {
        const int r = wr + i * 16 + l16;
        const int s = ((ksub * 4 + quad) + r) & 7;
        a[i] = *(const bf16x8*)(ca + r * 64 + s * 8);
      }
#pragma unroll
      for (int j = 0; j < 4; ++j) {
        const int r = wc + j * 16 + l16;
        const int s = ((ksub * 4 + quad) + r) & 7;
        bfr[j] = *(const bf16x8*)(cb + r * 64 + s * 8);
      }
#pragma unroll
      for (int i = 0; i < 4; ++i)
#pragma unroll
        for (int j = 0; j < 4; ++j)
          acc[i][j] = mfma16(a[i], bfr[j], acc[i][j]);
    }
  }

#pragma unroll
  for (int i = 0; i < 4; ++i)
#pragma unroll
    for (int r = 0; r < 4; ++r) {
      const int o = o0 + wr + i * 16 + quad * 4 + r;
      const float sc = g[o] * rsqrtf(va[o] + 1e-5f);
      const float mm = mu[o], bt = be[o];
#pragma unroll
      for (int j = 0; j < 4; ++j) {
        const int rG = r0 + wc + j * 16 + l16;
        float y = (acc[i][j][r] - mm) * sc + bt;
        y = fmaxf(y, 0.f);
        vT[(size_t)rG * C_ + o] = (bf16_t)y;
      }
    }
}

// ---------------- Kernel 3: fused sim -> softmax -> out ----------------
// 512 thr / 8 waves. LDS-staged Q/V via async global_load_lds (coalesced 128B
// rows), but BARRIER-FREE in Phases A and C: each wave stages/consumes only its
// own 32-row slice of vs, so cross-wave sync is unnecessary -- per-wave counted
// s_waitcnt vmcnt(4) replaces the block-wide drain+barrier (the r1 bottleneck).
// vmcnt(4) = "all but the 4 newest loads done" = current tile landed, next tile
// still in flight. Softmax keeps its 4 __syncthreads (ebuf IS cross-wave).
// ebuf: 32x1024 bf16, chunk-rotated (slot = (chunk + c) & 7 within 8-chunk groups).
static __device__ __forceinline__ int eaddr(int c, int d) {
  const int ch = d >> 3;
  const int ph = (ch & ~7) | ((ch + c) & 7);
  return (c << 10) + (ph << 3) + (d & 7);
}

__global__ __launch_bounds__(512, 2) void k_fused(const bf16_t* __restrict__ qt,
                                                  const bf16_t* __restrict__ kt,
                                                  const bf16_t* __restrict__ vT,
                                                  const float* __restrict__ x,
                                                  const float* __restrict__ alphap,
                                                  float* __restrict__ out) {
  __shared__ __align__(16) bf16_t ebuf[32 * 1024];
  __shared__ __align__(16) bf16_t vs[2][256 * 64];
  __shared__ float redmin[8][32];
  __shared__ float redsum[8][32];
  __shared__ float rowmin[32];
  __shared__ float rowrinv[32];

  const int tid  = threadIdx.x;
  const int wave = tid >> 6;
  const int lane = tid & 63;
  const int quad = lane >> 4;
  const int l16  = lane & 15;
  const int id   = blockIdx.x;
  const int b    = ((id & 7) << 2) | (id >> 8);        // 32 blocks/batch on one XCD
  const int c0   = ((id >> 3) & 31) << 5;

  const bf16_t* qb  = qt + (size_t)b * C_ * DQ_;
  const bf16_t* ktb = kt + ((size_t)b * C_ + c0) * DQ_;

  bf16x8 am[2][2];
#pragma unroll
  for (int i = 0; i < 2; ++i)
#pragma unroll
    for (int ksub = 0; ksub < 2; ++ksub)
      am[i][ksub] = *(const bf16x8*)(ktb + (size_t)(i * 16 + l16) * DQ_ + ksub * 32 + quad * 8);

  // ---- Phase A: sim (32 c x 1024 d), per-wave staged, barrier-free ----
  stage32(qb, DQ_, (bf16_t*)vs[0], wave, lane);
  f32x4 sim[2][8];
#pragma unroll
  for (int i = 0; i < 2; ++i)
#pragma unroll
    for (int nt = 0; nt < 8; ++nt) sim[i][nt] = (f32x4){0.f, 0.f, 0.f, 0.f};

#pragma unroll
  for (int t = 0; t < 4; ++t) {
    if (t < 3) {
      stage32(qb + (size_t)(t + 1) * 256 * DQ_, DQ_, (bf16_t*)vs[(t + 1) & 1], wave, lane);
      asm volatile("s_waitcnt vmcnt(4)" ::: "memory");
    } else {
      asm volatile("s_waitcnt vmcnt(0)" ::: "memory");
    }
    const bf16_t* cur = vs[t & 1];
#pragma unroll
    for (int jn = 0; jn < 2; ++jn) {
      const int r = wave * 32 + jn * 16 + l16;
#pragma unroll
      for (int ksub = 0; ksub < 2; ++ksub) {
        const int s = ((ksub * 4 + quad) + r) & 7;
        const bf16x8 bq = *(const bf16x8*)(cur + r * 64 + s * 8);
        sim[0][t * 2 + jn] = mfma16(am[0][ksub], bq, sim[0][t * 2 + jn]);
        sim[1][t * 2 + jn] = mfma16(am[1][ksub], bq, sim[1][t * 2 + jn]);
      }
    }
  }

  // Prologue staging for Phase C (latency hidden under Phase B)
  const bf16_t* vb = vT + (size_t)b * N_ * C_;
  stage32(vb, C_, (bf16_t*)vs[0], wave, lane);

  // ---- Phase B: row-min shift, exp, row-sum (ebuf is cross-wave: barriers) ----
  float pmin[2][4];
#pragma unroll
  for (int i = 0; i < 2; ++i)
#pragma unroll
    for (int r = 0; r < 4; ++r) pmin[i][r] = sim[i][0][r];
#pragma unroll
  for (int nt = 1; nt < 8; ++nt)
#pragma unroll
    for (int i = 0; i < 2; ++i)
#pragma unroll
      for (int r = 0; r < 4; ++r) pmin[i][r] = fminf(pmin[i][r], sim[i][nt][r]);
#pragma unroll
  for (int m = 1; m < 16; m <<= 1)
#pragma unroll
    for (int i = 0; i < 2; ++i)
#pragma unroll
      for (int r = 0; r < 4; ++r) pmin[i][r] = fminf(pmin[i][r], __shfl_xor(pmin[i][r], m));
  if (l16 == 0)
#pragma unroll
    for (int i = 0; i < 2; ++i)
#pragma unroll
      for (int r = 0; r < 4; ++r) redmin[wave][i * 16 + quad * 4 + r] = pmin[i][r];
  __syncthreads();
  if (tid < 32) {
    float v = redmin[0][tid];
#pragma unroll
    for (int w = 1; w < 8; ++w) v = fminf(v, redmin[w][tid]);
    rowmin[tid] = v;
  }
  __syncthreads();

  float mn[2][4], psum[2][4];
#pragma unroll
  for (int i = 0; i < 2; ++i)
#pragma unroll
    for (int r = 0; r < 4; ++r) {
      mn[i][r] = rowmin[i * 16 + quad * 4 + r];
      psum[i][r] = 0.f;
    }
#pragma unroll
  for (int nt = 0; nt < 8; ++nt) {
    const int d = ((nt >> 1) << 8) + wave * 32 + ((nt & 1) << 4) + l16;
#pragma unroll
    for (int i = 0; i < 2; ++i)
#pragma unroll
      for (int r = 0; r < 4; ++r) {
        const int c = i * 16 + quad * 4 + r;
        const float e = __expf(mn[i][r] - sim[i][nt][r]);
        ebuf[eaddr(c, d)] = (bf16_t)e;
        psum[i][r] += e;
      }
  }
#pragma unroll
  for (int m = 1; m < 16; m <<= 1)
#pragma unroll
    for (int i = 0; i < 2; ++i)
#pragma unroll
      for (int r = 0; r < 4; ++r) psum[i][r] += __shfl_xor(psum[i][r], m);
  if (l16 == 0)
#pragma unroll
    for (int i = 0; i < 2; ++i)
#pragma unroll
      for (int r = 0; r < 4; ++r) redsum[wave][i * 16 + quad * 4 + r] = psum[i][r];
  __syncthreads();
  if (tid < 32) {
    float s = redsum[0][tid];
#pragma unroll
    for (int w = 1; w < 8; ++w) s += redsum[w][tid];
    rowrinv[tid] = 1.f / s;
  }
  __syncthreads();   // ebuf + rowrinv visible; also drains V prologue (long done)

  // ---- Phase C: out = e @ vT, per-wave staged, barrier-free ----
  f32x4 oacc[2][2];
#pragma unroll
  for (int i = 0; i < 2; ++i)
#pragma unroll
    for (int jn = 0; jn < 2; ++jn) oacc[i][jn] = (f32x4){0.f, 0.f, 0.f, 0.f};

#pragma unroll
  for (int ks = 0; ks < 16; ++ks) {
    if (ks < 15) {
      stage32(vb + (ks + 1) * 64, C_, (bf16_t*)vs[(ks + 1) & 1], wave, lane);
      asm volatile("s_waitcnt vmcnt(4)" ::: "memory");
    } else {
      asm volatile("s_waitcnt vmcnt(0)" ::: "memory");
    }
    const bf16_t* cur = vs[ks & 1];
#pragma unroll
    for (int ksub = 0; ksub < 2; ++ksub) {
      const int gch = ks * 8 + ksub * 4 + quad;
      const int ph  = (gch & ~7) | ((gch + l16) & 7);
      const bf16x8 ae0 = *(const bf16x8*)(ebuf + ((size_t)l16 << 10) + ph * 8);
      const bf16x8 ae1 = *(const bf16x8*)(ebuf + ((size_t)(16 + l16) << 10) + ph * 8);
#pragma unroll
      for (int jn = 0; jn < 2; ++jn) {
        const int r = wave * 32 + jn * 16 + l16;
        const int s = ((ksub * 4 + quad) + r) & 7;
        const bf16x8 bv = *(const bf16x8*)(cur + r * 64 + s * 8);
        oacc[0][jn] = mfma16(ae0, bv, oacc[0][jn]);
        oacc[1][jn] = mfma16(ae1, bv, oacc[1][jn]);
      }
    }
  }

  const float alpha = alphap[0];
#pragma unroll
  for (int i = 0; i < 2; ++i)
#pragma unroll
    for (int jn = 0; jn < 2; ++jn)
#pragma unroll
      for (int r = 0; r < 4; ++r) {
        const int c = c0 + i * 16 + quad * 4 + r;
        const int n = wave * 32 + jn * 16 + l16;
        const size_t idx = ((size_t)b * C_ + c) * N_ + n;
        out[idx] = alpha * (oacc[i][jn][r] * rowrinv[i * 16 + quad * 4 + r]) + x[idx];
      }
}

extern "C" void kernel_launch(void* const* d_in, const int* in_sizes, int n_in,
                              void* d_out, int out_size, void* d_ws, size_t ws_size,
                              hipStream_t stream) {
  const float* x    = (const float*)d_in[0];
  const float* Wq   = (const float*)d_in[1];
  const float* Wk   = (const float*)d_in[2];
  const float* Wv   = (const float*)d_in[3];
  const float* bn1g = (const float*)d_in[4];
  const float* bn1b = (const float*)d_in[5];
  const float* bn1m = (const float*)d_in[6];
  const float* bn1v = (const float*)d_in[7];
  const float* bn2g = (const float*)d_in[8];
  const float* bn2b = (const float*)d_in[9];
  const float* bn2m = (const float*)d_in[10];
  const float* bn2v = (const float*)d_in[11];
  const float* bn3g = (const float*)d_in[12];
  const float* bn3b = (const float*)d_in[13];
  const float* bn3m = (const float*)d_in[14];
  const float* bn3v = (const float*)d_in[15];
  const float* alph = (const float*)d_in[16];
  float* outp = (float*)d_out;

  char* ws = (char*)d_ws;
  bf16_t* qt   = (bf16_t*)(ws);                              // 4 MiB  (B,C,DQ)
  bf16_t* kt   = (bf16_t*)(ws + (size_t)(4u << 20));         // 4 MiB  (B,C,DQ)
  bf16_t* vT   = (bf16_t*)(ws + (size_t)(8u << 20));         // 16 MiB (B,N,C)
  bf16_t* xT   = (bf16_t*)(ws + (size_t)(24u << 20));        // 16 MiB (B,N,C)
  bf16_t* Wvb  = (bf16_t*)(ws + (size_t)(40u << 20));        // 2 MiB  (C,C)
  bf16_t* Wqkb = (bf16_t*)(ws + (size_t)(42u << 20));        // 64 KiB (128,N)

  k_trans<<<dim3(8, 32, 32), dim3(32, 8, 1), 0, stream>>>(x, xT);
  k_cvt<<<dim3(528), 256, 0, stream>>>(Wv, Wq, Wk, Wvb, Wqkb);
  k_qk<<<dim3(16, 32), 256, 0, stream>>>(x, Wqkb,
                                         bn1g, bn1b, bn1m, bn1v,
                                         bn2g, bn2b, bn2m, bn2v, qt, kt);
  k_vgemm<<<dim3(8, 64), 256, 0, stream>>>(Wvb, xT, bn3g, bn3b, bn3m, bn3v, vT);
  k_fused<<<dim3(1024), 512, 0, stream>>>(qt, kt, vT, x, alph, outp);
}

// Round 8
// 232.657 us; speedup vs baseline: 1.1623x; 1.0044x over previous
//
#include <hip/hip_runtime.h>
#include <hip/hip_bf16.h>

#define B_  32
#define C_  1024
#define N_  256
#define DQ_ 64

typedef __bf16 bf16_t;
typedef __bf16 bf16x8 __attribute__((ext_vector_type(8)));
typedef float  f32x4  __attribute__((ext_vector_type(4)));

static __device__ __forceinline__ f32x4 mfma16(bf16x8 a, bf16x8 b, f32x4 c) {
  return __builtin_amdgcn_mfma_f32_16x16x32_bf16(a, b, c, 0, 0, 0);
}

static __device__ __forceinline__ bf16x8 ldcvt(const float* p) {
  const float4 a = *(const float4*)p;
  const float4 b = *(const float4*)(p + 4);
  bf16x8 r;
  r[0] = (bf16_t)a.x; r[1] = (bf16_t)a.y; r[2] = (bf16_t)a.z; r[3] = (bf16_t)a.w;
  r[4] = (bf16_t)b.x; r[5] = (bf16_t)b.y; r[6] = (bf16_t)b.z; r[7] = (bf16_t)b.w;
  return r;
}

// Swizzled global->LDS staging: each wave stages 32 rows of 64 bf16 (128 B) via
// 4 x global_load_lds(16B). Row r, slot j (16B chunks) holds global chunk
// (j - r) & 7, so frag ds_read_b128 across l16 lands 2 lanes/bank-group (free).
// NOTE: wave w touches only rows [w*32, w*32+32) of the tile -> per-wave private.
static __device__ __forceinline__ void stage32(const bf16_t* grow0, size_t gstride,
                                               bf16_t* tile, int wave, int lane) {
#pragma unroll
  for (int t = 0; t < 4; ++t) {
    const int rb = wave * 32 + t * 8;
    const int r  = rb + (lane >> 3);
    const int g  = ((lane & 7) - r) & 7;
    const bf16_t* src = grow0 + (size_t)r * gstride + g * 8;
    __builtin_amdgcn_global_load_lds(
        (const __attribute__((address_space(1))) void*)src,
        (__attribute__((address_space(3))) void*)(tile + rb * 64), 16, 0, 0);
  }
}

// ---------------- Kernel T: x (B,C,N) f32 -> xT (B,N,C) bf16 ----------------
__global__ __launch_bounds__(256) void k_trans(const float* __restrict__ x,
                                               bf16_t* __restrict__ xT) {
  __shared__ bf16_t tile[32][34];
  const int b  = blockIdx.z;
  const int n0 = blockIdx.x * 32, c0 = blockIdx.y * 32;
  const int tx = threadIdx.x, ty = threadIdx.y;
  const float* xb = x + (size_t)b * C_ * N_;
  bf16_t*     xtb = xT + (size_t)b * N_ * C_;
#pragma unroll
  for (int i = 0; i < 4; ++i)
    tile[ty + i * 8][tx] = (bf16_t)xb[(size_t)(c0 + ty + i * 8) * N_ + (n0 + tx)];
  __syncthreads();
#pragma unroll
  for (int i = 0; i < 4; ++i)
    xtb[(size_t)(n0 + ty + i * 8) * C_ + (c0 + tx)] = tile[tx][ty + i * 8];
}

// ---------------- Kernel CVT: Wv, Wq, Wk f32 -> bf16 ----------------
__global__ __launch_bounds__(256) void k_cvt(const float* __restrict__ Wv,
                                             const float* __restrict__ Wq,
                                             const float* __restrict__ Wk,
                                             bf16_t* __restrict__ Wvb,
                                             bf16_t* __restrict__ Wqkb) {
  const int gid = blockIdx.x * 256 + threadIdx.x;
  if (blockIdx.x < 512) {
    const int i = gid * 8;
    *(bf16x8*)(Wvb + i) = ldcvt(Wv + i);
  } else {
    const int g2 = (gid - 512 * 256) * 8;
    if (g2 < 16384) *(bf16x8*)(Wqkb + g2) = ldcvt(Wq + g2);
    else            *(bf16x8*)(Wqkb + g2) = ldcvt(Wk + (g2 - 16384));
  }
}

// ---------------- Kernel 1: fused q+k projection ----------------
__global__ __launch_bounds__(256) void k_qk(const float* __restrict__ x,
                                            const bf16_t* __restrict__ Wqkb,
                                            const float* __restrict__ g1,
                                            const float* __restrict__ b1,
                                            const float* __restrict__ m1,
                                            const float* __restrict__ v1,
                                            const float* __restrict__ g2,
                                            const float* __restrict__ b2,
                                            const float* __restrict__ m2,
                                            const float* __restrict__ v2,
                                            bf16_t* __restrict__ qt,
                                            bf16_t* __restrict__ kt) {
  const int tid  = threadIdx.x;
  const int wave = tid >> 6;
  const int lane = tid & 63;
  const int quad = lane >> 4;
  const int l16  = lane & 15;
  const int b    = blockIdx.y;
  const int c16  = blockIdx.x * 64 + wave * 16;
  const float* xb = x + (size_t)b * C_ * N_;

  f32x4 acc[8];
#pragma unroll
  for (int i = 0; i < 8; ++i) acc[i] = (f32x4){0.f, 0.f, 0.f, 0.f};

  for (int ks = 0; ks < 8; ++ks) {
    const int k0 = ks * 32 + quad * 8;
    const bf16x8 bx = ldcvt(xb + (size_t)(c16 + l16) * N_ + k0);
#pragma unroll
    for (int i = 0; i < 8; ++i) {
      const bf16x8 aw = *(const bf16x8*)(Wqkb + (size_t)(i * 16 + l16) * N_ + k0);
      acc[i] = mfma16(aw, bx, acc[i]);
    }
  }

#pragma unroll
  for (int i = 0; i < 8; ++i) {
    const bool isq = (i < 4);
    bf16_t* dst = isq ? qt : kt;
#pragma unroll
    for (int r = 0; r < 4; ++r) {
      const int o = (i & 3) * 16 + quad * 4 + r;
      const float sc = (isq ? g1[o] : g2[o]) * rsqrtf((isq ? v1[o] : v2[o]) + 1e-5f);
      const float mm = isq ? m1[o] : m2[o];
      const float bt = isq ? b1[o] : b2[o];
      const int c = c16 + l16;
      float y = (acc[i][r] - mm) * sc + bt;
      y = fmaxf(y, 0.f);
      dst[((size_t)b * C_ + c) * DQ_ + o] = (bf16_t)y;
    }
  }
}

// ---------------- Kernel 2: v GEMM, m97-style staged (flat 8192x1024x1024) ----
// XCD-aware remap: linear wgid & 7 selects the XCD (round-robin dispatch), so
// group the 8 o-tiles (x) of each row-panel (y) onto ONE XCD: per-XCD working
// set = 8 y-panels of xT (2 MiB) + Wvb (2 MiB) ~= L2. Before: every XCD
// streamed the entire 16.8 MiB xT (~134 MB duplicated HBM fetch).
__global__ __launch_bounds__(256, 2) void k_vgemm(const bf16_t* __restrict__ Wvb,
                                                  const bf16_t* __restrict__ xT,
                                                  const float* __restrict__ g,
                                                  const float* __restrict__ be,
                                                  const float* __restrict__ mu,
                                                  const float* __restrict__ va,
                                                  bf16_t* __restrict__ vT) {
  __shared__ __align__(16) bf16_t As[2][128 * 64];
  __shared__ __align__(16) bf16_t Bs[2][128 * 64];
  const int tid  = threadIdx.x;
  const int wave = tid >> 6;
  const int lane = tid & 63;
  const int quad = lane >> 4;
  const int l16  = lane & 15;
  const int wid  = blockIdx.y * 8 + blockIdx.x;     // linear dispatch id
  const int xcd  = wid & 7;
  const int j    = wid >> 3;
  const int o0 = (j >> 3) * 128;                    // o-tile: streams per XCD
  const int r0 = ((xcd << 3) | (j & 7)) * 128;      // row-panel: pinned to XCD
  const bf16_t* Ab = Wvb + (size_t)o0 * C_;
  const bf16_t* Bb = xT + (size_t)r0 * C_;
  const int wr = (wave >> 1) * 64, wc = (wave & 1) * 64;

  stage32(Ab, C_, (bf16_t*)As[0], wave, lane);
  stage32(Bb, C_, (bf16_t*)Bs[0], wave, lane);

  f32x4 acc[4][4];
#pragma unroll
  for (int i = 0; i < 4; ++i)
#pragma unroll
    for (int j2 = 0; j2 < 4; ++j2) acc[i][j2] = (f32x4){0.f, 0.f, 0.f, 0.f};

  for (int ks = 0; ks < 16; ++ks) {
    __syncthreads();
    const bf16_t* ca = As[ks & 1];
    const bf16_t* cb = Bs[ks & 1];
    if (ks < 15) {
      stage32(Ab + (ks + 1) * 64, C_, (bf16_t*)As[(ks + 1) & 1], wave, lane);
      stage32(Bb + (ks + 1) * 64, C_, (bf16_t*)Bs[(ks + 1) & 1], wave, lane);
    }
#pragma unroll
    for (int ksub = 0; ksub < 2; ++ksub) {
      bf16x8 a[4], bfr[4];
#pragma unroll
      for (int i = 0; i < 4; ++i) {
        const int r = wr + i * 16 + l16;
        const int s = ((ksub * 4 + quad) + r) & 7;
        a[i] = *(const bf16x8*)(ca + r * 64 + s * 8);
      }
#pragma unroll
      for (int j2 = 0; j2 < 4; ++j2) {
        const int r = wc + j2 * 16 + l16;
        const int s = ((ksub * 4 + quad) + r) & 7;
        bfr[j2] = *(const bf16x8*)(cb + r * 64 + s * 8);
      }
#pragma unroll
      for (int i = 0; i < 4; ++i)
#pragma unroll
        for (int j2 = 0; j2 < 4; ++j2)
          acc[i][j2] = mfma16(a[i], bfr[j2], acc[i][j2]);
    }
  }

#pragma unroll
  for (int i = 0; i < 4; ++i)
#pragma unroll
    for (int r = 0; r < 4; ++r) {
      const int o = o0 + wr + i * 16 + quad * 4 + r;
      const float sc = g[o] * rsqrtf(va[o] + 1e-5f);
      const float mm = mu[o], bt = be[o];
#pragma unroll
      for (int j2 = 0; j2 < 4; ++j2) {
        const int rG = r0 + wc + j2 * 16 + l16;
        float y = (acc[i][j2][r] - mm) * sc + bt;
        y = fmaxf(y, 0.f);
        vT[(size_t)rG * C_ + o] = (bf16_t)y;
      }
    }
}

// ---------------- Kernel 3: fused sim -> softmax -> out ----------------
// 512 thr / 8 waves. LDS-staged Q/V via async global_load_lds, barrier-free
// Phases A/C with per-wave counted s_waitcnt vmcnt(4) (r6 win). ebuf rotation
// widened to 16-chunk groups: read lanes l16=0..15 now spread over 16 distinct
// 16B slots (was 8 -> ~4-8-way conflict, 2.1M SQ_LDS_BANK_CONFLICT).
// eaddr: slot = (ch & ~15) | ((ch + c) & 15); bijective per row; ae0/ae1 share
// ph since (c+16)&15 == c&15.
static __device__ __forceinline__ int eaddr(int c, int d) {
  const int ch = d >> 3;
  const int ph = (ch & ~15) | ((ch + c) & 15);
  return (c << 10) + (ph << 3) + (d & 7);
}

__global__ __launch_bounds__(512, 2) void k_fused(const bf16_t* __restrict__ qt,
                                                  const bf16_t* __restrict__ kt,
                                                  const bf16_t* __restrict__ vT,
                                                  const float* __restrict__ x,
                                                  const float* __restrict__ alphap,
                                                  float* __restrict__ out) {
  __shared__ __align__(16) bf16_t ebuf[32 * 1024];
  __shared__ __align__(16) bf16_t vs[2][256 * 64];
  __shared__ float redmin[8][32];
  __shared__ float redsum[8][32];
  __shared__ float rowmin[32];
  __shared__ float rowrinv[32];

  const int tid  = threadIdx.x;
  const int wave = tid >> 6;
  const int lane = tid & 63;
  const int quad = lane >> 4;
  const int l16  = lane & 15;
  const int id   = blockIdx.x;
  const int b    = ((id & 7) << 2) | (id >> 8);        // 32 blocks/batch on one XCD
  const int c0   = ((id >> 3) & 31) << 5;

  const bf16_t* qb  = qt + (size_t)b * C_ * DQ_;
  const bf16_t* ktb = kt + ((size_t)b * C_ + c0) * DQ_;

  bf16x8 am[2][2];
#pragma unroll
  for (int i = 0; i < 2; ++i)
#pragma unroll
    for (int ksub = 0; ksub < 2; ++ksub)
      am[i][ksub] = *(const bf16x8*)(ktb + (size_t)(i * 16 + l16) * DQ_ + ksub * 32 + quad * 8);

  // ---- Phase A: sim (32 c x 1024 d), per-wave staged, barrier-free ----
  stage32(qb, DQ_, (bf16_t*)vs[0], wave, lane);
  f32x4 sim[2][8];
#pragma unroll
  for (int i = 0; i < 2; ++i)
#pragma unroll
    for (int nt = 0; nt < 8; ++nt) sim[i][nt] = (f32x4){0.f, 0.f, 0.f, 0.f};

#pragma unroll
  for (int t = 0; t < 4; ++t) {
    if (t < 3) {
      stage32(qb + (size_t)(t + 1) * 256 * DQ_, DQ_, (bf16_t*)vs[(t + 1) & 1], wave, lane);
      asm volatile("s_waitcnt vmcnt(4)" ::: "memory");
    } else {
      asm volatile("s_waitcnt vmcnt(0)" ::: "memory");
    }
    const bf16_t* cur = vs[t & 1];
#pragma unroll
    for (int jn = 0; jn < 2; ++jn) {
      const int r = wave * 32 + jn * 16 + l16;
#pragma unroll
      for (int ksub = 0; ksub < 2; ++ksub) {
        const int s = ((ksub * 4 + quad) + r) & 7;
        const bf16x8 bq = *(const bf16x8*)(cur + r * 64 + s * 8);
        sim[0][t * 2 + jn] = mfma16(am[0][ksub], bq, sim[0][t * 2 + jn]);
        sim[1][t * 2 + jn] = mfma16(am[1][ksub], bq, sim[1][t * 2 + jn]);
      }
    }
  }

  // Prologue staging for Phase C (latency hidden under Phase B)
  const bf16_t* vb = vT + (size_t)b * N_ * C_;
  stage32(vb, C_, (bf16_t*)vs[0], wave, lane);

  // ---- Phase B: row-min shift, exp, row-sum (ebuf is cross-wave: barriers) ----
  float pmin[2][4];
#pragma unroll
  for (int i = 0; i < 2; ++i)
#pragma unroll
    for (int r = 0; r < 4; ++r) pmin[i][r] = sim[i][0][r];
#pragma unroll
  for (int nt = 1; nt < 8; ++nt)
#pragma unroll
    for (int i = 0; i < 2; ++i)
#pragma unroll
      for (int r = 0; r < 4; ++r) pmin[i][r] = fminf(pmin[i][r], sim[i][nt][r]);
#pragma unroll
  for (int m = 1; m < 16; m <<= 1)
#pragma unroll
    for (int i = 0; i < 2; ++i)
#pragma unroll
      for (int r = 0; r < 4; ++r) pmin[i][r] = fminf(pmin[i][r], __shfl_xor(pmin[i][r], m));
  if (l16 == 0)
#pragma unroll
    for (int i = 0; i < 2; ++i)
#pragma unroll
      for (int r = 0; r < 4; ++r) redmin[wave][i * 16 + quad * 4 + r] = pmin[i][r];
  __syncthreads();
  if (tid < 32) {
    float v = redmin[0][tid];
#pragma unroll
    for (int w = 1; w < 8; ++w) v = fminf(v, redmin[w][tid]);
    rowmin[tid] = v;
  }
  __syncthreads();

  float mn[2][4], psum[2][4];
#pragma unroll
  for (int i = 0; i < 2; ++i)
#pragma unroll
    for (int r = 0; r < 4; ++r) {
      mn[i][r] = rowmin[i * 16 + quad * 4 + r];
      psum[i][r] = 0.f;
    }
#pragma unroll
  for (int nt = 0; nt < 8; ++nt) {
    const int d = ((nt >> 1) << 8) + wave * 32 + ((nt & 1) << 4) + l16;
#pragma unroll
    for (int i = 0; i < 2; ++i)
#pragma unroll
      for (int r = 0; r < 4; ++r) {
        const int c = i * 16 + quad * 4 + r;
        const float e = __expf(mn[i][r] - sim[i][nt][r]);
        ebuf[eaddr(c, d)] = (bf16_t)e;
        psum[i][r] += e;
      }
  }
#pragma unroll
  for (int m = 1; m < 16; m <<= 1)
#pragma unroll
    for (int i = 0; i < 2; ++i)
#pragma unroll
      for (int r = 0; r < 4; ++r) psum[i][r] += __shfl_xor(psum[i][r], m);
  if (l16 == 0)
#pragma unroll
    for (int i = 0; i < 2; ++i)
#pragma unroll
      for (int r = 0; r < 4; ++r) redsum[wave][i * 16 + quad * 4 + r] = psum[i][r];
  __syncthreads();
  if (tid < 32) {
    float s = redsum[0][tid];
#pragma unroll
    for (int w = 1; w < 8; ++w) s += redsum[w][tid];
    rowrinv[tid] = 1.f / s;
  }
  __syncthreads();   // ebuf + rowrinv visible; also drains V prologue (long done)

  // ---- Phase C: out = e @ vT, per-wave staged, barrier-free ----
  f32x4 oacc[2][2];
#pragma unroll
  for (int i = 0; i < 2; ++i)
#pragma unroll
    for (int jn = 0; jn < 2; ++jn) oacc[i][jn] = (f32x4){0.f, 0.f, 0.f, 0.f};

#pragma unroll
  for (int ks = 0; ks < 16; ++ks) {
    if (ks < 15) {
      stage32(vb + (ks + 1) * 64, C_, (bf16_t*)vs[(ks + 1) & 1], wave, lane);
      asm volatile("s_waitcnt vmcnt(4)" ::: "memory");
    } else {
      asm volatile("s_waitcnt vmcnt(0)" ::: "memory");
    }
    const bf16_t* cur = vs[ks & 1];
#pragma unroll
    for (int ksub = 0; ksub < 2; ++ksub) {
      const int gch = ks * 8 + ksub * 4 + quad;
      const int ph  = (gch & ~15) | ((gch + l16) & 15);
      const bf16x8 ae0 = *(const bf16x8*)(ebuf + ((size_t)l16 << 10) + ph * 8);
      const bf16x8 ae1 = *(const bf16x8*)(ebuf + ((size_t)(16 + l16) << 10) + ph * 8);
#pragma unroll
      for (int jn = 0; jn < 2; ++jn) {
        const int r = wave * 32 + jn * 16 + l16;
        const int s = ((ksub * 4 + quad) + r) & 7;
        const bf16x8 bv = *(const bf16x8*)(cur + r * 64 + s * 8);
        oacc[0][jn] = mfma16(ae0, bv, oacc[0][jn]);
        oacc[1][jn] = mfma16(ae1, bv, oacc[1][jn]);
      }
    }
  }

  const float alpha = alphap[0];
#pragma unroll
  for (int i = 0; i < 2; ++i)
#pragma unroll
    for (int jn = 0; jn < 2; ++jn)
#pragma unroll
      for (int r = 0; r < 4; ++r) {
        const int c = c0 + i * 16 + quad * 4 + r;
        const int n = wave * 32 + jn * 16 + l16;
        const size_t idx = ((size_t)b * C_ + c) * N_ + n;
        out[idx] = alpha * (oacc[i][jn][r] * rowrinv[i * 16 + quad * 4 + r]) + x[idx];
      }
}

extern "C" void kernel_launch(void* const* d_in, const int* in_sizes, int n_in,
                              void* d_out, int out_size, void* d_ws, size_t ws_size,
                              hipStream_t stream) {
  const float* x    = (const float*)d_in[0];
  const float* Wq   = (const float*)d_in[1];
  const float* Wk   = (const float*)d_in[2];
  const float* Wv   = (const float*)d_in[3];
  const float* bn1g = (const float*)d_in[4];
  const float* bn1b = (const float*)d_in[5];
  const float* bn1m = (const float*)d_in[6];
  const float* bn1v = (const float*)d_in[7];
  const float* bn2g = (const float*)d_in[8];
  const float* bn2b = (const float*)d_in[9];
  const float* bn2m = (const float*)d_in[10];
  const float* bn2v = (const float*)d_in[11];
  const float* bn3g = (const float*)d_in[12];
  const float* bn3b = (const float*)d_in[13];
  const float* bn3m = (const float*)d_in[14];
  const float* bn3v = (const float*)d_in[15];
  const float* alph = (const float*)d_in[16];
  float* outp = (float*)d_out;

  char* ws = (char*)d_ws;
  bf16_t* qt   = (bf16_t*)(ws);                              // 4 MiB  (B,C,DQ)
  bf16_t* kt   = (bf16_t*)(ws + (size_t)(4u << 20));         // 4 MiB  (B,C,DQ)
  bf16_t* vT   = (bf16_t*)(ws + (size_t)(8u << 20));         // 16 MiB (B,N,C)
  bf16_t* xT   = (bf16_t*)(ws + (size_t)(24u << 20));        // 16 MiB (B,N,C)
  bf16_t* Wvb  = (bf16_t*)(ws + (size_t)(40u << 20));        // 2 MiB  (C,C)
  bf16_t* Wqkb = (bf16_t*)(ws + (size_t)(42u << 20));        // 64 KiB (128,N)

  k_trans<<<dim3(8, 32, 32), dim3(32, 8, 1), 0, stream>>>(x, xT);
  k_cvt<<<dim3(528), 256, 0, stream>>>(Wv, Wq, Wk, Wvb, Wqkb);
  k_qk<<<dim3(16, 32), 256, 0, stream>>>(x, Wqkb,
                                         bn1g, bn1b, bn1m, bn1v,
                                         bn2g, bn2b, bn2m, bn2v, qt, kt);
  k_vgemm<<<dim3(8, 64), 256, 0, stream>>>(Wvb, xT, bn3g, bn3b, bn3m, bn3v, vT);
  k_fused<<<dim3(1024), 512, 0, stream>>>(qt, kt, vT, x, alph, outp);
}

// Round 9
// 232.332 us; speedup vs baseline: 1.1640x; 1.0014x over previous
//
#include <hip/hip_runtime.h>
#include <hip/hip_bf16.h>

#define B_  32
#define C_  1024
#define N_  256
#define DQ_ 64

typedef __bf16 bf16_t;
typedef __bf16 bf16x8 __attribute__((ext_vector_type(8)));
typedef float  f32x4  __attribute__((ext_vector_type(4)));

static __device__ __forceinline__ f32x4 mfma16(bf16x8 a, bf16x8 b, f32x4 c) {
  return __builtin_amdgcn_mfma_f32_16x16x32_bf16(a, b, c, 0, 0, 0);
}

static __device__ __forceinline__ bf16x8 ldcvt(const float* p) {
  const float4 a = *(const float4*)p;
  const float4 b = *(const float4*)(p + 4);
  bf16x8 r;
  r[0] = (bf16_t)a.x; r[1] = (bf16_t)a.y; r[2] = (bf16_t)a.z; r[3] = (bf16_t)a.w;
  r[4] = (bf16_t)b.x; r[5] = (bf16_t)b.y; r[6] = (bf16_t)b.z; r[7] = (bf16_t)b.w;
  return r;
}

// Swizzled global->LDS staging: each wave stages 32 rows of 64 bf16 (128 B) via
// 4 x global_load_lds(16B). Row r, slot j (16B chunks) holds global chunk
// (j - r) & 7, so frag ds_read_b128 across l16 lands 2 lanes/bank-group (free).
// NOTE: wave w touches only rows [w*32, w*32+32) of the tile -> per-wave private.
static __device__ __forceinline__ void stage32(const bf16_t* grow0, size_t gstride,
                                               bf16_t* tile, int wave, int lane) {
#pragma unroll
  for (int t = 0; t < 4; ++t) {
    const int rb = wave * 32 + t * 8;
    const int r  = rb + (lane >> 3);
    const int g  = ((lane & 7) - r) & 7;
    const bf16_t* src = grow0 + (size_t)r * gstride + g * 8;
    __builtin_amdgcn_global_load_lds(
        (const __attribute__((address_space(1))) void*)src,
        (__attribute__((address_space(3))) void*)(tile + rb * 64), 16, 0, 0);
  }
}

// ---------------- Kernel T: x (B,C,N) f32 -> xT (B,N,C) bf16 ----------------
__global__ __launch_bounds__(256) void k_trans(const float* __restrict__ x,
                                               bf16_t* __restrict__ xT) {
  __shared__ bf16_t tile[32][34];
  const int b  = blockIdx.z;
  const int n0 = blockIdx.x * 32, c0 = blockIdx.y * 32;
  const int tx = threadIdx.x, ty = threadIdx.y;
  const float* xb = x + (size_t)b * C_ * N_;
  bf16_t*     xtb = xT + (size_t)b * N_ * C_;
#pragma unroll
  for (int i = 0; i < 4; ++i)
    tile[ty + i * 8][tx] = (bf16_t)xb[(size_t)(c0 + ty + i * 8) * N_ + (n0 + tx)];
  __syncthreads();
#pragma unroll
  for (int i = 0; i < 4; ++i)
    xtb[(size_t)(n0 + ty + i * 8) * C_ + (c0 + tx)] = tile[tx][ty + i * 8];
}

// ---------------- Kernel CVT: Wv, Wq, Wk f32 -> bf16 ----------------
__global__ __launch_bounds__(256) void k_cvt(const float* __restrict__ Wv,
                                             const float* __restrict__ Wq,
                                             const float* __restrict__ Wk,
                                             bf16_t* __restrict__ Wvb,
                                             bf16_t* __restrict__ Wqkb) {
  const int gid = blockIdx.x * 256 + threadIdx.x;
  if (blockIdx.x < 512) {
    const int i = gid * 8;
    *(bf16x8*)(Wvb + i) = ldcvt(Wv + i);
  } else {
    const int g2 = (gid - 512 * 256) * 8;
    if (g2 < 16384) *(bf16x8*)(Wqkb + g2) = ldcvt(Wq + g2);
    else            *(bf16x8*)(Wqkb + g2) = ldcvt(Wk + (g2 - 16384));
  }
}

// ---------------- Kernel 1: fused q+k projection ----------------
__global__ __launch_bounds__(256) void k_qk(const float* __restrict__ x,
                                            const bf16_t* __restrict__ Wqkb,
                                            const float* __restrict__ g1,
                                            const float* __restrict__ b1,
                                            const float* __restrict__ m1,
                                            const float* __restrict__ v1,
                                            const float* __restrict__ g2,
                                            const float* __restrict__ b2,
                                            const float* __restrict__ m2,
                                            const float* __restrict__ v2,
                                            bf16_t* __restrict__ qt,
                                            bf16_t* __restrict__ kt) {
  const int tid  = threadIdx.x;
  const int wave = tid >> 6;
  const int lane = tid & 63;
  const int quad = lane >> 4;
  const int l16  = lane & 15;
  const int b    = blockIdx.y;
  const int c16  = blockIdx.x * 64 + wave * 16;
  const float* xb = x + (size_t)b * C_ * N_;

  f32x4 acc[8];
#pragma unroll
  for (int i = 0; i < 8; ++i) acc[i] = (f32x4){0.f, 0.f, 0.f, 0.f};

  for (int ks = 0; ks < 8; ++ks) {
    const int k0 = ks * 32 + quad * 8;
    const bf16x8 bx = ldcvt(xb + (size_t)(c16 + l16) * N_ + k0);
#pragma unroll
    for (int i = 0; i < 8; ++i) {
      const bf16x8 aw = *(const bf16x8*)(Wqkb + (size_t)(i * 16 + l16) * N_ + k0);
      acc[i] = mfma16(aw, bx, acc[i]);
    }
  }

#pragma unroll
  for (int i = 0; i < 8; ++i) {
    const bool isq = (i < 4);
    bf16_t* dst = isq ? qt : kt;
#pragma unroll
    for (int r = 0; r < 4; ++r) {
      const int o = (i & 3) * 16 + quad * 4 + r;
      const float sc = (isq ? g1[o] : g2[o]) * rsqrtf((isq ? v1[o] : v2[o]) + 1e-5f);
      const float mm = isq ? m1[o] : m2[o];
      const float bt = isq ? b1[o] : b2[o];
      const int c = c16 + l16;
      float y = (acc[i][r] - mm) * sc + bt;
      y = fmaxf(y, 0.f);
      dst[((size_t)b * C_ + c) * DQ_ + o] = (bf16_t)y;
    }
  }
}

// ---------------- Kernel 2: v GEMM, m97-style staged (flat 8192x1024x1024) ----
// XCD-aware remap (r8-verified win ~17us): linear wgid & 7 selects the XCD, so
// group the 8 o-tiles of each row-panel onto ONE XCD: per-XCD working set =
// 8 y-panels of xT (2 MiB) + Wvb (2 MiB) ~= L2, instead of every XCD streaming
// the whole 16.8 MiB xT.
__global__ __launch_bounds__(256, 2) void k_vgemm(const bf16_t* __restrict__ Wvb,
                                                  const bf16_t* __restrict__ xT,
                                                  const float* __restrict__ g,
                                                  const float* __restrict__ be,
                                                  const float* __restrict__ mu,
                                                  const float* __restrict__ va,
                                                  bf16_t* __restrict__ vT) {
  __shared__ __align__(16) bf16_t As[2][128 * 64];
  __shared__ __align__(16) bf16_t Bs[2][128 * 64];
  const int tid  = threadIdx.x;
  const int wave = tid >> 6;
  const int lane = tid & 63;
  const int quad = lane >> 4;
  const int l16  = lane & 15;
  const int wid  = blockIdx.y * 8 + blockIdx.x;     // linear dispatch id
  const int xcd  = wid & 7;
  const int j    = wid >> 3;
  const int o0 = (j >> 3) * 128;                    // o-tile: streams per XCD
  const int r0 = ((xcd << 3) | (j & 7)) * 128;      // row-panel: pinned to XCD
  const bf16_t* Ab = Wvb + (size_t)o0 * C_;
  const bf16_t* Bb = xT + (size_t)r0 * C_;
  const int wr = (wave >> 1) * 64, wc = (wave & 1) * 64;

  stage32(Ab, C_, (bf16_t*)As[0], wave, lane);
  stage32(Bb, C_, (bf16_t*)Bs[0], wave, lane);

  f32x4 acc[4][4];
#pragma unroll
  for (int i = 0; i < 4; ++i)
#pragma unroll
    for (int j2 = 0; j2 < 4; ++j2) acc[i][j2] = (f32x4){0.f, 0.f, 0.f, 0.f};

  for (int ks = 0; ks < 16; ++ks) {
    __syncthreads();
    const bf16_t* ca = As[ks & 1];
    const bf16_t* cb = Bs[ks & 1];
    if (ks < 15) {
      stage32(Ab + (ks + 1) * 64, C_, (bf16_t*)As[(ks + 1) & 1], wave, lane);
      stage32(Bb + (ks + 1) * 64, C_, (bf16_t*)Bs[(ks + 1) & 1], wave, lane);
    }
#pragma unroll
    for (int ksub = 0; ksub < 2; ++ksub) {
      bf16x8 a[4], bfr[4];
#pragma unroll
      for (int i = 0; i < 4; ++i) {
        const int r = wr + i * 16 + l16;
        const int s = ((ksub * 4 + quad) + r) & 7;
        a[i] = *(const bf16x8*)(ca + r * 64 + s * 8);
      }
#pragma unroll
      for (int j2 = 0; j2 < 4; ++j2) {
        const int r = wc + j2 * 16 + l16;
        const int s = ((ksub * 4 + quad) + r) & 7;
        bfr[j2] = *(const bf16x8*)(cb + r * 64 + s * 8);
      }
#pragma unroll
      for (int i = 0; i < 4; ++i)
#pragma unroll
        for (int j2 = 0; j2 < 4; ++j2)
          acc[i][j2] = mfma16(a[i], bfr[j2], acc[i][j2]);
    }
  }

#pragma unroll
  for (int i = 0; i < 4; ++i)
#pragma unroll
    for (int r = 0; r < 4; ++r) {
      const int o = o0 + wr + i * 16 + quad * 4 + r;
      const float sc = g[o] * rsqrtf(va[o] + 1e-5f);
      const float mm = mu[o], bt = be[o];
#pragma unroll
      for (int j2 = 0; j2 < 4; ++j2) {
        const int rG = r0 + wc + j2 * 16 + l16;
        float y = (acc[i][j2][r] - mm) * sc + bt;
        y = fmaxf(y, 0.f);
        vT[(size_t)rG * C_ + o] = (bf16_t)y;
      }
    }
}

// ---------------- Kernel 3: fused sim -> softmax -> out ----------------
// 512 thr / 8 waves. LDS-staged Q/V via async global_load_lds, barrier-free
// Phases A/C with per-wave counted s_waitcnt vmcnt(4) (r6-verified, 68.5us).
// ebuf: 8-chunk rotation (r6-proven; the r7 16-wide variant was bank-neutral
// by derivation -- ph&7 identical -- and measured slower; reverted).
static __device__ __forceinline__ int eaddr(int c, int d) {
  const int ch = d >> 3;
  const int ph = (ch & ~7) | ((ch + c) & 7);
  return (c << 10) + (ph << 3) + (d & 7);
}

__global__ __launch_bounds__(512, 2) void k_fused(const bf16_t* __restrict__ qt,
                                                  const bf16_t* __restrict__ kt,
                                                  const bf16_t* __restrict__ vT,
                                                  const float* __restrict__ x,
                                                  const float* __restrict__ alphap,
                                                  float* __restrict__ out) {
  __shared__ __align__(16) bf16_t ebuf[32 * 1024];
  __shared__ __align__(16) bf16_t vs[2][256 * 64];
  __shared__ float redmin[8][32];
  __shared__ float redsum[8][32];
  __shared__ float rowmin[32];
  __shared__ float rowrinv[32];

  const int tid  = threadIdx.x;
  const int wave = tid >> 6;
  const int lane = tid & 63;
  const int quad = lane >> 4;
  const int l16  = lane & 15;
  const int id   = blockIdx.x;
  const int b    = ((id & 7) << 2) | (id >> 8);        // 32 blocks/batch on one XCD
  const int c0   = ((id >> 3) & 31) << 5;

  const bf16_t* qb  = qt + (size_t)b * C_ * DQ_;
  const bf16_t* ktb = kt + ((size_t)b * C_ + c0) * DQ_;

  bf16x8 am[2][2];
#pragma unroll
  for (int i = 0; i < 2; ++i)
#pragma unroll
    for (int ksub = 0; ksub < 2; ++ksub)
      am[i][ksub] = *(const bf16x8*)(ktb + (size_t)(i * 16 + l16) * DQ_ + ksub * 32 + quad * 8);

  // ---- Phase A: sim (32 c x 1024 d), per-wave staged, barrier-free ----
  stage32(qb, DQ_, (bf16_t*)vs[0], wave, lane);
  f32x4 sim[2][8];
#pragma unroll
  for (int i = 0; i < 2; ++i)
#pragma unroll
    for (int nt = 0; nt < 8; ++nt) sim[i][nt] = (f32x4){0.f, 0.f, 0.f, 0.f};

#pragma unroll
  for (int t = 0; t < 4; ++t) {
    if (t < 3) {
      stage32(qb + (size_t)(t + 1) * 256 * DQ_, DQ_, (bf16_t*)vs[(t + 1) & 1], wave, lane);
      asm volatile("s_waitcnt vmcnt(4)" ::: "memory");
    } else {
      asm volatile("s_waitcnt vmcnt(0)" ::: "memory");
    }
    const bf16_t* cur = vs[t & 1];
#pragma unroll
    for (int jn = 0; jn < 2; ++jn) {
      const int r = wave * 32 + jn * 16 + l16;
#pragma unroll
      for (int ksub = 0; ksub < 2; ++ksub) {
        const int s = ((ksub * 4 + quad) + r) & 7;
        const bf16x8 bq = *(const bf16x8*)(cur + r * 64 + s * 8);
        sim[0][t * 2 + jn] = mfma16(am[0][ksub], bq, sim[0][t * 2 + jn]);
        sim[1][t * 2 + jn] = mfma16(am[1][ksub], bq, sim[1][t * 2 + jn]);
      }
    }
  }

  // Prologue staging for Phase C (latency hidden under Phase B)
  const bf16_t* vb = vT + (size_t)b * N_ * C_;
  stage32(vb, C_, (bf16_t*)vs[0], wave, lane);

  // ---- Phase B: row-min shift, exp, row-sum (ebuf is cross-wave: barriers) ----
  float pmin[2][4];
#pragma unroll
  for (int i = 0; i < 2; ++i)
#pragma unroll
    for (int r = 0; r < 4; ++r) pmin[i][r] = sim[i][0][r];
#pragma unroll
  for (int nt = 1; nt < 8; ++nt)
#pragma unroll
    for (int i = 0; i < 2; ++i)
#pragma unroll
      for (int r = 0; r < 4; ++r) pmin[i][r] = fminf(pmin[i][r], sim[i][nt][r]);
#pragma unroll
  for (int m = 1; m < 16; m <<= 1)
#pragma unroll
    for (int i = 0; i < 2; ++i)
#pragma unroll
      for (int r = 0; r < 4; ++r) pmin[i][r] = fminf(pmin[i][r], __shfl_xor(pmin[i][r], m));
  if (l16 == 0)
#pragma unroll
    for (int i = 0; i < 2; ++i)
#pragma unroll
      for (int r = 0; r < 4; ++r) redmin[wave][i * 16 + quad * 4 + r] = pmin[i][r];
  __syncthreads();
  if (tid < 32) {
    float v = redmin[0][tid];
#pragma unroll
    for (int w = 1; w < 8; ++w) v = fminf(v, redmin[w][tid]);
    rowmin[tid] = v;
  }
  __syncthreads();

  float mn[2][4], psum[2][4];
#pragma unroll
  for (int i = 0; i < 2; ++i)
#pragma unroll
    for (int r = 0; r < 4; ++r) {
      mn[i][r] = rowmin[i * 16 + quad * 4 + r];
      psum[i][r] = 0.f;
    }
#pragma unroll
  for (int nt = 0; nt < 8; ++nt) {
    const int d = ((nt >> 1) << 8) + wave * 32 + ((nt & 1) << 4) + l16;
#pragma unroll
    for (int i = 0; i < 2; ++i)
#pragma unroll
      for (int r = 0; r < 4; ++r) {
        const int c = i * 16 + quad * 4 + r;
        const float e = __expf(mn[i][r] - sim[i][nt][r]);
        ebuf[eaddr(c, d)] = (bf16_t)e;
        psum[i][r] += e;
      }
  }
#pragma unroll
  for (int m = 1; m < 16; m <<= 1)
#pragma unroll
    for (int i = 0; i < 2; ++i)
#pragma unroll
      for (int r = 0; r < 4; ++r) psum[i][r] += __shfl_xor(psum[i][r], m);
  if (l16 == 0)
#pragma unroll
    for (int i = 0; i < 2; ++i)
#pragma unroll
      for (int r = 0; r < 4; ++r) redsum[wave][i * 16 + quad * 4 + r] = psum[i][r];
  __syncthreads();
  if (tid < 32) {
    float s = redsum[0][tid];
#pragma unroll
    for (int w = 1; w < 8; ++w) s += redsum[w][tid];
    rowrinv[tid] = 1.f / s;
  }
  __syncthreads();   // ebuf + rowrinv visible; also drains V prologue (long done)

  // ---- Phase C: out = e @ vT, per-wave staged, barrier-free ----
  f32x4 oacc[2][2];
#pragma unroll
  for (int i = 0; i < 2; ++i)
#pragma unroll
    for (int jn = 0; jn < 2; ++jn) oacc[i][jn] = (f32x4){0.f, 0.f, 0.f, 0.f};

#pragma unroll
  for (int ks = 0; ks < 16; ++ks) {
    if (ks < 15) {
      stage32(vb + (ks + 1) * 64, C_, (bf16_t*)vs[(ks + 1) & 1], wave, lane);
      asm volatile("s_waitcnt vmcnt(4)" ::: "memory");
    } else {
      asm volatile("s_waitcnt vmcnt(0)" ::: "memory");
    }
    const bf16_t* cur = vs[ks & 1];
#pragma unroll
    for (int ksub = 0; ksub < 2; ++ksub) {
      const int gch = ks * 8 + ksub * 4 + quad;
      const int ph  = (gch & ~7) | ((gch + l16) & 7);
      const bf16x8 ae0 = *(const bf16x8*)(ebuf + ((size_t)l16 << 10) + ph * 8);
      const bf16x8 ae1 = *(const bf16x8*)(ebuf + ((size_t)(16 + l16) << 10) + ph * 8);
#pragma unroll
      for (int jn = 0; jn < 2; ++jn) {
        const int r = wave * 32 + jn * 16 + l16;
        const int s = ((ksub * 4 + quad) + r) & 7;
        const bf16x8 bv = *(const bf16x8*)(cur + r * 64 + s * 8);
        oacc[0][jn] = mfma16(ae0, bv, oacc[0][jn]);
        oacc[1][jn] = mfma16(ae1, bv, oacc[1][jn]);
      }
    }
  }

  const float alpha = alphap[0];
#pragma unroll
  for (int i = 0; i < 2; ++i)
#pragma unroll
    for (int jn = 0; jn < 2; ++jn)
#pragma unroll
      for (int r = 0; r < 4; ++r) {
        const int c = c0 + i * 16 + quad * 4 + r;
        const int n = wave * 32 + jn * 16 + l16;
        const size_t idx = ((size_t)b * C_ + c) * N_ + n;
        out[idx] = alpha * (oacc[i][jn][r] * rowrinv[i * 16 + quad * 4 + r]) + x[idx];
      }
}

extern "C" void kernel_launch(void* const* d_in, const int* in_sizes, int n_in,
                              void* d_out, int out_size, void* d_ws, size_t ws_size,
                              hipStream_t stream) {
  const float* x    = (const float*)d_in[0];
  const float* Wq   = (const float*)d_in[1];
  const float* Wk   = (const float*)d_in[2];
  const float* Wv   = (const float*)d_in[3];
  const float* bn1g = (const float*)d_in[4];
  const float* bn1b = (const float*)d_in[5];
  const float* bn1m = (const float*)d_in[6];
  const float* bn1v = (const float*)d_in[7];
  const float* bn2g = (const float*)d_in[8];
  const float* bn2b = (const float*)d_in[9];
  const float* bn2m = (const float*)d_in[10];
  const float* bn2v = (const float*)d_in[11];
  const float* bn3g = (const float*)d_in[12];
  const float* bn3b = (const float*)d_in[13];
  const float* bn3m = (const float*)d_in[14];
  const float* bn3v = (const float*)d_in[15];
  const float* alph = (const float*)d_in[16];
  float* outp = (float*)d_out;

  char* ws = (char*)d_ws;
  bf16_t* qt   = (bf16_t*)(ws);                              // 4 MiB  (B,C,DQ)
  bf16_t* kt   = (bf16_t*)(ws + (size_t)(4u << 20));         // 4 MiB  (B,C,DQ)
  bf16_t* vT   = (bf16_t*)(ws + (size_t)(8u << 20));         // 16 MiB (B,N,C)
  bf16_t* xT   = (bf16_t*)(ws + (size_t)(24u << 20));        // 16 MiB (B,N,C)
  bf16_t* Wvb  = (bf16_t*)(ws + (size_t)(40u << 20));        // 2 MiB  (C,C)
  bf16_t* Wqkb = (bf16_t*)(ws + (size_t)(42u << 20));        // 64 KiB (128,N)

  k_trans<<<dim3(8, 32, 32), dim3(32, 8, 1), 0, stream>>>(x, xT);
  k_cvt<<<dim3(528), 256, 0, stream>>>(Wv, Wq, Wk, Wvb, Wqkb);
  k_qk<<<dim3(16, 32), 256, 0, stream>>>(x, Wqkb,
                                         bn1g, bn1b, bn1m, bn1v,
                                         bn2g, bn2b, bn2m, bn2v, qt, kt);
  k_vgemm<<<dim3(8, 64), 256, 0, stream>>>(Wvb, xT, bn3g, bn3b, bn3m, bn3v, vT);
  k_fused<<<dim3(1024), 512, 0, stream>>>(qt, kt, vT, x, alph, outp);
}

// Round 10
// 230.635 us; speedup vs baseline: 1.1725x; 1.0074x over previous
//
#include <hip/hip_runtime.h>
#include <hip/hip_bf16.h>

#define B_  32
#define C_  1024
#define N_  256
#define DQ_ 64

typedef __bf16 bf16_t;
typedef __bf16 bf16x4 __attribute__((ext_vector_type(4)));
typedef __bf16 bf16x8 __attribute__((ext_vector_type(8)));
typedef float  f32x4  __attribute__((ext_vector_type(4)));

static __device__ __forceinline__ f32x4 mfma16(bf16x8 a, bf16x8 b, f32x4 c) {
  return __builtin_amdgcn_mfma_f32_16x16x32_bf16(a, b, c, 0, 0, 0);
}

static __device__ __forceinline__ bf16x8 ldcvt(const float* p) {
  const float4 a = *(const float4*)p;
  const float4 b = *(const float4*)(p + 4);
  bf16x8 r;
  r[0] = (bf16_t)a.x; r[1] = (bf16_t)a.y; r[2] = (bf16_t)a.z; r[3] = (bf16_t)a.w;
  r[4] = (bf16_t)b.x; r[5] = (bf16_t)b.y; r[6] = (bf16_t)b.z; r[7] = (bf16_t)b.w;
  return r;
}

// Swizzled global->LDS staging: each wave stages 32 rows of 64 bf16 (128 B) via
// 4 x global_load_lds(16B). Row r, slot j (16B chunks) holds global chunk
// (j - r) & 7, so frag ds_read_b128 across l16 lands 2 lanes/bank-group (free).
// NOTE: wave w touches only rows [w*32, w*32+32) of the tile -> per-wave private.
static __device__ __forceinline__ void stage32(const bf16_t* grow0, size_t gstride,
                                               bf16_t* tile, int wave, int lane) {
#pragma unroll
  for (int t = 0; t < 4; ++t) {
    const int rb = wave * 32 + t * 8;
    const int r  = rb + (lane >> 3);
    const int g  = ((lane & 7) - r) & 7;
    const bf16_t* src = grow0 + (size_t)r * gstride + g * 8;
    __builtin_amdgcn_global_load_lds(
        (const __attribute__((address_space(1))) void*)src,
        (__attribute__((address_space(3))) void*)(tile + rb * 64), 16, 0, 0);
  }
}

// ---------------- Kernel T: x (B,C,N) f32 -> xT (B,N,C) bf16 ----------------
// Vectorized rewrite (r10): 64x64 tiles, float4 global reads, 8B LDS writes
// (tile[c][n] layout), 16B global writes. Old version used scalar 4B reads and
// 2B writes (1/16th store efficiency).
__global__ __launch_bounds__(256) void k_trans(const float* __restrict__ x,
                                               bf16_t* __restrict__ xT) {
  __shared__ __align__(16) bf16_t tile[64][68];   // [c-local][n-local], stride 136B (8-aligned)
  const int b  = blockIdx.z;
  const int n0 = blockIdx.x * 64, c0 = blockIdx.y * 64;
  const int t  = threadIdx.x;
  const float* xb  = x + (size_t)b * C_ * N_ + (size_t)c0 * N_ + n0;
  bf16_t*      xtb = xT + (size_t)b * N_ * C_ + (size_t)n0 * C_ + c0;

  const int cl = t >> 4;            // 0..15
  const int n4 = (t & 15) << 2;     // 0,4,..,60
#pragma unroll
  for (int p = 0; p < 4; ++p) {
    const int c = (p << 4) + cl;
    const float4 v = *(const float4*)(xb + (size_t)c * N_ + n4);
    bf16x4 w;
    w[0] = (bf16_t)v.x; w[1] = (bf16_t)v.y; w[2] = (bf16_t)v.z; w[3] = (bf16_t)v.w;
    *(bf16x4*)(&tile[c][n4]) = w;
  }
  __syncthreads();

  const int nr = t >> 3;            // 0..31
  const int c8 = (t & 7) << 3;      // 0,8,..,56
#pragma unroll
  for (int p = 0; p < 2; ++p) {
    const int n = (p << 5) + nr;
    bf16x8 o;
#pragma unroll
    for (int j = 0; j < 8; ++j) o[j] = tile[c8 + j][n];
    *(bf16x8*)(xtb + (size_t)n * C_ + c8) = o;
  }
}

// ---------------- Kernel CVT: Wv, Wq, Wk f32 -> bf16 ----------------
__global__ __launch_bounds__(256) void k_cvt(const float* __restrict__ Wv,
                                             const float* __restrict__ Wq,
                                             const float* __restrict__ Wk,
                                             bf16_t* __restrict__ Wvb,
                                             bf16_t* __restrict__ Wqkb) {
  const int gid = blockIdx.x * 256 + threadIdx.x;
  if (blockIdx.x < 512) {
    const int i = gid * 8;
    *(bf16x8*)(Wvb + i) = ldcvt(Wv + i);
  } else {
    const int g2 = (gid - 512 * 256) * 8;
    if (g2 < 16384) *(bf16x8*)(Wqkb + g2) = ldcvt(Wq + g2);
    else            *(bf16x8*)(Wqkb + g2) = ldcvt(Wk + (g2 - 16384));
  }
}

// ---------------- Kernel 1: fused q+k projection ----------------
__global__ __launch_bounds__(256) void k_qk(const float* __restrict__ x,
                                            const bf16_t* __restrict__ Wqkb,
                                            const float* __restrict__ g1,
                                            const float* __restrict__ b1,
                                            const float* __restrict__ m1,
                                            const float* __restrict__ v1,
                                            const float* __restrict__ g2,
                                            const float* __restrict__ b2,
                                            const float* __restrict__ m2,
                                            const float* __restrict__ v2,
                                            bf16_t* __restrict__ qt,
                                            bf16_t* __restrict__ kt) {
  const int tid  = threadIdx.x;
  const int wave = tid >> 6;
  const int lane = tid & 63;
  const int quad = lane >> 4;
  const int l16  = lane & 15;
  const int b    = blockIdx.y;
  const int c16  = blockIdx.x * 64 + wave * 16;
  const float* xb = x + (size_t)b * C_ * N_;

  f32x4 acc[8];
#pragma unroll
  for (int i = 0; i < 8; ++i) acc[i] = (f32x4){0.f, 0.f, 0.f, 0.f};

  for (int ks = 0; ks < 8; ++ks) {
    const int k0 = ks * 32 + quad * 8;
    const bf16x8 bx = ldcvt(xb + (size_t)(c16 + l16) * N_ + k0);
#pragma unroll
    for (int i = 0; i < 8; ++i) {
      const bf16x8 aw = *(const bf16x8*)(Wqkb + (size_t)(i * 16 + l16) * N_ + k0);
      acc[i] = mfma16(aw, bx, acc[i]);
    }
  }

#pragma unroll
  for (int i = 0; i < 8; ++i) {
    const bool isq = (i < 4);
    bf16_t* dst = isq ? qt : kt;
#pragma unroll
    for (int r = 0; r < 4; ++r) {
      const int o = (i & 3) * 16 + quad * 4 + r;
      const float sc = (isq ? g1[o] : g2[o]) * rsqrtf((isq ? v1[o] : v2[o]) + 1e-5f);
      const float mm = isq ? m1[o] : m2[o];
      const float bt = isq ? b1[o] : b2[o];
      const int c = c16 + l16;
      float y = (acc[i][r] - mm) * sc + bt;
      y = fmaxf(y, 0.f);
      dst[((size_t)b * C_ + c) * DQ_ + o] = (bf16_t)y;
    }
  }
}

// ---------------- Kernel 2: v GEMM, m97-style staged (flat 8192x1024x1024) ----
// XCD-aware remap (r8-verified win ~17us): linear wgid & 7 selects the XCD, so
// group the 8 o-tiles of each row-panel onto ONE XCD: per-XCD working set =
// 8 y-panels of xT (2 MiB) + Wvb (2 MiB) ~= L2, instead of every XCD streaming
// the whole 16.8 MiB xT.
__global__ __launch_bounds__(256, 2) void k_vgemm(const bf16_t* __restrict__ Wvb,
                                                  const bf16_t* __restrict__ xT,
                                                  const float* __restrict__ g,
                                                  const float* __restrict__ be,
                                                  const float* __restrict__ mu,
                                                  const float* __restrict__ va,
                                                  bf16_t* __restrict__ vT) {
  __shared__ __align__(16) bf16_t As[2][128 * 64];
  __shared__ __align__(16) bf16_t Bs[2][128 * 64];
  const int tid  = threadIdx.x;
  const int wave = tid >> 6;
  const int lane = tid & 63;
  const int quad = lane >> 4;
  const int l16  = lane & 15;
  const int wid  = blockIdx.y * 8 + blockIdx.x;     // linear dispatch id
  const int xcd  = wid & 7;
  const int j    = wid >> 3;
  const int o0 = (j >> 3) * 128;                    // o-tile: streams per XCD
  const int r0 = ((xcd << 3) | (j & 7)) * 128;      // row-panel: pinned to XCD
  const bf16_t* Ab = Wvb + (size_t)o0 * C_;
  const bf16_t* Bb = xT + (size_t)r0 * C_;
  const int wr = (wave >> 1) * 64, wc = (wave & 1) * 64;

  stage32(Ab, C_, (bf16_t*)As[0], wave, lane);
  stage32(Bb, C_, (bf16_t*)Bs[0], wave, lane);

  f32x4 acc[4][4];
#pragma unroll
  for (int i = 0; i < 4; ++i)
#pragma unroll
    for (int j2 = 0; j2 < 4; ++j2) acc[i][j2] = (f32x4){0.f, 0.f, 0.f, 0.f};

  for (int ks = 0; ks < 16; ++ks) {
    __syncthreads();
    const bf16_t* ca = As[ks & 1];
    const bf16_t* cb = Bs[ks & 1];
    if (ks < 15) {
      stage32(Ab + (ks + 1) * 64, C_, (bf16_t*)As[(ks + 1) & 1], wave, lane);
      stage32(Bb + (ks + 1) * 64, C_, (bf16_t*)Bs[(ks + 1) & 1], wave, lane);
    }
#pragma unroll
    for (int ksub = 0; ksub < 2; ++ksub) {
      bf16x8 a[4], bfr[4];
#pragma unroll
      for (int i = 0; i < 4; ++i) {
        const int r = wr + i * 16 + l16;
        const int s = ((ksub * 4 + quad) + r) & 7;
        a[i] = *(const bf16x8*)(ca + r * 64 + s * 8);
      }
#pragma unroll
      for (int j2 = 0; j2 < 4; ++j2) {
        const int r = wc + j2 * 16 + l16;
        const int s = ((ksub * 4 + quad) + r) & 7;
        bfr[j2] = *(const bf16x8*)(cb + r * 64 + s * 8);
      }
#pragma unroll
      for (int i = 0; i < 4; ++i)
#pragma unroll
        for (int j2 = 0; j2 < 4; ++j2)
          acc[i][j2] = mfma16(a[i], bfr[j2], acc[i][j2]);
    }
  }

#pragma unroll
  for (int i = 0; i < 4; ++i)
#pragma unroll
    for (int r = 0; r < 4; ++r) {
      const int o = o0 + wr + i * 16 + quad * 4 + r;
      const float sc = g[o] * rsqrtf(va[o] + 1e-5f);
      const float mm = mu[o], bt = be[o];
#pragma unroll
      for (int j2 = 0; j2 < 4; ++j2) {
        const int rG = r0 + wc + j2 * 16 + l16;
        float y = (acc[i][j2][r] - mm) * sc + bt;
        y = fmaxf(y, 0.f);
        vT[(size_t)rG * C_ + o] = (bf16_t)y;
      }
    }
}

// ---------------- Kernel 3: fused sim -> softmax -> out ----------------
// 512 thr / 8 waves. LDS-staged Q/V via async global_load_lds, barrier-free
// Phases A/C with per-wave counted s_waitcnt vmcnt(4) (r6-verified, 68.5us).
// ebuf: 8-chunk rotation (r6-proven; r7 16-wide variant was bank-neutral by
// derivation and measured slower; reverted in r9, confirmed ~71us).
static __device__ __forceinline__ int eaddr(int c, int d) {
  const int ch = d >> 3;
  const int ph = (ch & ~7) | ((ch + c) & 7);
  return (c << 10) + (ph << 3) + (d & 7);
}

__global__ __launch_bounds__(512, 2) void k_fused(const bf16_t* __restrict__ qt,
                                                  const bf16_t* __restrict__ kt,
                                                  const bf16_t* __restrict__ vT,
                                                  const float* __restrict__ x,
                                                  const float* __restrict__ alphap,
                                                  float* __restrict__ out) {
  __shared__ __align__(16) bf16_t ebuf[32 * 1024];
  __shared__ __align__(16) bf16_t vs[2][256 * 64];
  __shared__ float redmin[8][32];
  __shared__ float redsum[8][32];
  __shared__ float rowmin[32];
  __shared__ float rowrinv[32];

  const int tid  = threadIdx.x;
  const int wave = tid >> 6;
  const int lane = tid & 63;
  const int quad = lane >> 4;
  const int l16  = lane & 15;
  const int id   = blockIdx.x;
  const int b    = ((id & 7) << 2) | (id >> 8);        // 32 blocks/batch on one XCD
  const int c0   = ((id >> 3) & 31) << 5;

  const bf16_t* qb  = qt + (size_t)b * C_ * DQ_;
  const bf16_t* ktb = kt + ((size_t)b * C_ + c0) * DQ_;

  bf16x8 am[2][2];
#pragma unroll
  for (int i = 0; i < 2; ++i)
#pragma unroll
    for (int ksub = 0; ksub < 2; ++ksub)
      am[i][ksub] = *(const bf16x8*)(ktb + (size_t)(i * 16 + l16) * DQ_ + ksub * 32 + quad * 8);

  // ---- Phase A: sim (32 c x 1024 d), per-wave staged, barrier-free ----
  stage32(qb, DQ_, (bf16_t*)vs[0], wave, lane);
  f32x4 sim[2][8];
#pragma unroll
  for (int i = 0; i < 2; ++i)
#pragma unroll
    for (int nt = 0; nt < 8; ++nt) sim[i][nt] = (f32x4){0.f, 0.f, 0.f, 0.f};

#pragma unroll
  for (int t = 0; t < 4; ++t) {
    if (t < 3) {
      stage32(qb + (size_t)(t + 1) * 256 * DQ_, DQ_, (bf16_t*)vs[(t + 1) & 1], wave, lane);
      asm volatile("s_waitcnt vmcnt(4)" ::: "memory");
    } else {
      asm volatile("s_waitcnt vmcnt(0)" ::: "memory");
    }
    const bf16_t* cur = vs[t & 1];
#pragma unroll
    for (int jn = 0; jn < 2; ++jn) {
      const int r = wave * 32 + jn * 16 + l16;
#pragma unroll
      for (int ksub = 0; ksub < 2; ++ksub) {
        const int s = ((ksub * 4 + quad) + r) & 7;
        const bf16x8 bq = *(const bf16x8*)(cur + r * 64 + s * 8);
        sim[0][t * 2 + jn] = mfma16(am[0][ksub], bq, sim[0][t * 2 + jn]);
        sim[1][t * 2 + jn] = mfma16(am[1][ksub], bq, sim[1][t * 2 + jn]);
      }
    }
  }

  // Prologue staging for Phase C (latency hidden under Phase B)
  const bf16_t* vb = vT + (size_t)b * N_ * C_;
  stage32(vb, C_, (bf16_t*)vs[0], wave, lane);

  // ---- Phase B: row-min shift, exp, row-sum (ebuf is cross-wave: barriers) ----
  float pmin[2][4];
#pragma unroll
  for (int i = 0; i < 2; ++i)
#pragma unroll
    for (int r = 0; r < 4; ++r) pmin[i][r] = sim[i][0][r];
#pragma unroll
  for (int nt = 1; nt < 8; ++nt)
#pragma unroll
    for (int i = 0; i < 2; ++i)
#pragma unroll
      for (int r = 0; r < 4; ++r) pmin[i][r] = fminf(pmin[i][r], sim[i][nt][r]);
#pragma unroll
  for (int m = 1; m < 16; m <<= 1)
#pragma unroll
    for (int i = 0; i < 2; ++i)
#pragma unroll
      for (int r = 0; r < 4; ++r) pmin[i][r] = fminf(pmin[i][r], __shfl_xor(pmin[i][r], m));
  if (l16 == 0)
#pragma unroll
    for (int i = 0; i < 2; ++i)
#pragma unroll
      for (int r = 0; r < 4; ++r) redmin[wave][i * 16 + quad * 4 + r] = pmin[i][r];
  __syncthreads();
  if (tid < 32) {
    float v = redmin[0][tid];
#pragma unroll
    for (int w = 1; w < 8; ++w) v = fminf(v, redmin[w][tid]);
    rowmin[tid] = v;
  }
  __syncthreads();

  float mn[2][4], psum[2][4];
#pragma unroll
  for (int i = 0; i < 2; ++i)
#pragma unroll
    for (int r = 0; r < 4; ++r) {
      mn[i][r] = rowmin[i * 16 + quad * 4 + r];
      psum[i][r] = 0.f;
    }
#pragma unroll
  for (int nt = 0; nt < 8; ++nt) {
    const int d = ((nt >> 1) << 8) + wave * 32 + ((nt & 1) << 4) + l16;
#pragma unroll
    for (int i = 0; i < 2; ++i)
#pragma unroll
      for (int r = 0; r < 4; ++r) {
        const int c = i * 16 + quad * 4 + r;
        const float e = __expf(mn[i][r] - sim[i][nt][r]);
        ebuf[eaddr(c, d)] = (bf16_t)e;
        psum[i][r] += e;
      }
  }
#pragma unroll
  for (int m = 1; m < 16; m <<= 1)
#pragma unroll
    for (int i = 0; i < 2; ++i)
#pragma unroll
      for (int r = 0; r < 4; ++r) psum[i][r] += __shfl_xor(psum[i][r], m);
  if (l16 == 0)
#pragma unroll
    for (int i = 0; i < 2; ++i)
#pragma unroll
      for (int r = 0; r < 4; ++r) redsum[wave][i * 16 + quad * 4 + r] = psum[i][r];
  __syncthreads();
  if (tid < 32) {
    float s = redsum[0][tid];
#pragma unroll
    for (int w = 1; w < 8; ++w) s += redsum[w][tid];
    rowrinv[tid] = 1.f / s;
  }
  __syncthreads();   // ebuf + rowrinv visible; also drains V prologue (long done)

  // ---- Phase C: out = e @ vT, per-wave staged, barrier-free ----
  f32x4 oacc[2][2];
#pragma unroll
  for (int i = 0; i < 2; ++i)
#pragma unroll
    for (int jn = 0; jn < 2; ++jn) oacc[i][jn] = (f32x4){0.f, 0.f, 0.f, 0.f};

#pragma unroll
  for (int ks = 0; ks < 16; ++ks) {
    if (ks < 15) {
      stage32(vb + (ks + 1) * 64, C_, (bf16_t*)vs[(ks + 1) & 1], wave, lane);
      asm volatile("s_waitcnt vmcnt(4)" ::: "memory");
    } else {
      asm volatile("s_waitcnt vmcnt(0)" ::: "memory");
    }
    const bf16_t* cur = vs[ks & 1];
#pragma unroll
    for (int ksub = 0; ksub < 2; ++ksub) {
      const int gch = ks * 8 + ksub * 4 + quad;
      const int ph  = (gch & ~7) | ((gch + l16) & 7);
      const bf16x8 ae0 = *(const bf16x8*)(ebuf + ((size_t)l16 << 10) + ph * 8);
      const bf16x8 ae1 = *(const bf16x8*)(ebuf + ((size_t)(16 + l16) << 10) + ph * 8);
#pragma unroll
      for (int jn = 0; jn < 2; ++jn) {
        const int r = wave * 32 + jn * 16 + l16;
        const int s = ((ksub * 4 + quad) + r) & 7;
        const bf16x8 bv = *(const bf16x8*)(cur + r * 64 + s * 8);
        oacc[0][jn] = mfma16(ae0, bv, oacc[0][jn]);
        oacc[1][jn] = mfma16(ae1, bv, oacc[1][jn]);
      }
    }
  }

  const float alpha = alphap[0];
#pragma unroll
  for (int i = 0; i < 2; ++i)
#pragma unroll
    for (int jn = 0; jn < 2; ++jn)
#pragma unroll
      for (int r = 0; r < 4; ++r) {
        const int c = c0 + i * 16 + quad * 4 + r;
        const int n = wave * 32 + jn * 16 + l16;
        const size_t idx = ((size_t)b * C_ + c) * N_ + n;
        out[idx] = alpha * (oacc[i][jn][r] * rowrinv[i * 16 + quad * 4 + r]) + x[idx];
      }
}

extern "C" void kernel_launch(void* const* d_in, const int* in_sizes, int n_in,
                              void* d_out, int out_size, void* d_ws, size_t ws_size,
                              hipStream_t stream) {
  const float* x    = (const float*)d_in[0];
  const float* Wq   = (const float*)d_in[1];
  const float* Wk   = (const float*)d_in[2];
  const float* Wv   = (const float*)d_in[3];
  const float* bn1g = (const float*)d_in[4];
  const float* bn1b = (const float*)d_in[5];
  const float* bn1m = (const float*)d_in[6];
  const float* bn1v = (const float*)d_in[7];
  const float* bn2g = (const float*)d_in[8];
  const float* bn2b = (const float*)d_in[9];
  const float* bn2m = (const float*)d_in[10];
  const float* bn2v = (const float*)d_in[11];
  const float* bn3g = (const float*)d_in[12];
  const float* bn3b = (const float*)d_in[13];
  const float* bn3m = (const float*)d_in[14];
  const float* bn3v = (const float*)d_in[15];
  const float* alph = (const float*)d_in[16];
  float* outp = (float*)d_out;

  char* ws = (char*)d_ws;
  bf16_t* qt   = (bf16_t*)(ws);                              // 4 MiB  (B,C,DQ)
  bf16_t* kt   = (bf16_t*)(ws + (size_t)(4u << 20));         // 4 MiB  (B,C,DQ)
  bf16_t* vT   = (bf16_t*)(ws + (size_t)(8u << 20));         // 16 MiB (B,N,C)
  bf16_t* xT   = (bf16_t*)(ws + (size_t)(24u << 20));        // 16 MiB (B,N,C)
  bf16_t* Wvb  = (bf16_t*)(ws + (size_t)(40u << 20));        // 2 MiB  (C,C)
  bf16_t* Wqkb = (bf16_t*)(ws + (size_t)(42u << 20));        // 64 KiB (128,N)

  k_trans<<<dim3(4, 16, 32), 256, 0, stream>>>(x, xT);
  k_cvt<<<dim3(528), 256, 0, stream>>>(Wv, Wq, Wk, Wvb, Wqkb);
  k_qk<<<dim3(16, 32), 256, 0, stream>>>(x, Wqkb,
                                         bn1g, bn1b, bn1m, bn1v,
                                         bn2g, bn2b, bn2m, bn2v, qt, kt);
  k_vgemm<<<dim3(8, 64), 256, 0, stream>>>(Wvb, xT, bn3g, bn3b, bn3m, bn3v, vT);
  k_fused<<<dim3(1024), 512, 0, stream>>>(qt, kt, vT, x, alph, outp);
}

// Round 11
// 227.831 us; speedup vs baseline: 1.1870x; 1.0123x over previous
//
#include <hip/hip_runtime.h>
#include <hip/hip_bf16.h>

#define B_  32
#define C_  1024
#define N_  256
#define DQ_ 64

typedef __bf16 bf16_t;
typedef __bf16 bf16x4 __attribute__((ext_vector_type(4)));
typedef __bf16 bf16x8 __attribute__((ext_vector_type(8)));
typedef float  f32x4  __attribute__((ext_vector_type(4)));

static __device__ __forceinline__ f32x4 mfma16(bf16x8 a, bf16x8 b, f32x4 c) {
  return __builtin_amdgcn_mfma_f32_16x16x32_bf16(a, b, c, 0, 0, 0);
}

static __device__ __forceinline__ bf16x8 ldcvt(const float* p) {
  const float4 a = *(const float4*)p;
  const float4 b = *(const float4*)(p + 4);
  bf16x8 r;
  r[0] = (bf16_t)a.x; r[1] = (bf16_t)a.y; r[2] = (bf16_t)a.z; r[3] = (bf16_t)a.w;
  r[4] = (bf16_t)b.x; r[5] = (bf16_t)b.y; r[6] = (bf16_t)b.z; r[7] = (bf16_t)b.w;
  return r;
}

// Swizzled global->LDS staging: each wave stages 32 rows of 64 bf16 (128 B) via
// 4 x global_load_lds(16B). Row r, slot j (16B chunks) holds global chunk
// (j - r) & 7, so frag ds_read_b128 across l16 lands 2 lanes/bank-group (free).
// NOTE: wave w touches only rows [w*32, w*32+32) of the tile -> per-wave private.
static __device__ __forceinline__ void stage32(const bf16_t* grow0, size_t gstride,
                                               bf16_t* tile, int wave, int lane) {
#pragma unroll
  for (int t = 0; t < 4; ++t) {
    const int rb = wave * 32 + t * 8;
    const int r  = rb + (lane >> 3);
    const int g  = ((lane & 7) - r) & 7;
    const bf16_t* src = grow0 + (size_t)r * gstride + g * 8;
    __builtin_amdgcn_global_load_lds(
        (const __attribute__((address_space(1))) void*)src,
        (__attribute__((address_space(3))) void*)(tile + rb * 64), 16, 0, 0);
  }
}

// ---------------- Kernel CVT: Wv, Wq, Wk f32 -> bf16 ----------------
__global__ __launch_bounds__(256) void k_cvt(const float* __restrict__ Wv,
                                             const float* __restrict__ Wq,
                                             const float* __restrict__ Wk,
                                             bf16_t* __restrict__ Wvb,
                                             bf16_t* __restrict__ Wqkb) {
  const int gid = blockIdx.x * 256 + threadIdx.x;
  if (blockIdx.x < 512) {
    const int i = gid * 8;
    *(bf16x8*)(Wvb + i) = ldcvt(Wv + i);
  } else {
    const int g2 = (gid - 512 * 256) * 8;
    if (g2 < 16384) *(bf16x8*)(Wqkb + g2) = ldcvt(Wq + g2);
    else            *(bf16x8*)(Wqkb + g2) = ldcvt(Wk + (g2 - 16384));
  }
}

// ---------------- Kernel 1: fused q+k projection + x transpose (r11) ----------
// Absorbs k_trans: the block already loads the full 64c x 256n x-tile as bf16
// for the MFMA B-operand; park it in LDS and emit xT with 128B-contiguous row
// writes. BN scale/shift precomputed to LDS (was ~6 vector global loads per
// output element); q/k stores vectorized to bf16x4 (was scalar 2B).
__global__ __launch_bounds__(256) void k_qkt(const float* __restrict__ x,
                                             const bf16_t* __restrict__ Wqkb,
                                             const float* __restrict__ g1,
                                             const float* __restrict__ b1,
                                             const float* __restrict__ m1,
                                             const float* __restrict__ v1,
                                             const float* __restrict__ g2,
                                             const float* __restrict__ b2,
                                             const float* __restrict__ m2,
                                             const float* __restrict__ v2,
                                             bf16_t* __restrict__ qt,
                                             bf16_t* __restrict__ kt,
                                             bf16_t* __restrict__ xT) {
  __shared__ __align__(16) bf16_t txp[64][264];   // 64c x 256n, pad 8 (row 528B, 16B-aligned)
  __shared__ float bnsc[128], bnsh[128];          // [0:64)=q, [64:128)=k
  const int tid  = threadIdx.x;
  const int wave = tid >> 6;
  const int lane = tid & 63;
  const int quad = lane >> 4;
  const int l16  = lane & 15;
  const int b    = blockIdx.y;
  const int c16  = blockIdx.x * 64 + wave * 16;
  const int cl   = wave * 16 + l16;               // local c 0..63
  const float* xb = x + (size_t)b * C_ * N_;

  if (tid < 128) {
    const int o = tid & 63;
    const bool isq = tid < 64;
    const float sc = (isq ? g1[o] : g2[o]) * rsqrtf((isq ? v1[o] : v2[o]) + 1e-5f);
    bnsc[tid] = sc;
    bnsh[tid] = (isq ? b1[o] : b2[o]) - (isq ? m1[o] : m2[o]) * sc;
  }

  f32x4 acc[8];
#pragma unroll
  for (int i = 0; i < 8; ++i) acc[i] = (f32x4){0.f, 0.f, 0.f, 0.f};

  for (int ks = 0; ks < 8; ++ks) {
    const int k0 = ks * 32 + quad * 8;
    const bf16x8 bx = ldcvt(xb + (size_t)(c16 + l16) * N_ + k0);
    *(bf16x8*)(&txp[cl][k0]) = bx;
#pragma unroll
    for (int i = 0; i < 8; ++i) {
      const bf16x8 aw = *(const bf16x8*)(Wqkb + (size_t)(i * 16 + l16) * N_ + k0);
      acc[i] = mfma16(aw, bx, acc[i]);
    }
  }
  __syncthreads();

  // xT write: thread t owns row n = t; 64 c-contig values = 128 B contiguous.
  {
    bf16_t* xtb = xT + (size_t)b * N_ * C_ + (size_t)tid * C_ + blockIdx.x * 64;
#pragma unroll
    for (int cc = 0; cc < 8; ++cc) {
      bf16x8 o8;
#pragma unroll
      for (int j = 0; j < 8; ++j) o8[j] = txp[cc * 8 + j][tid];
      *(bf16x8*)(xtb + cc * 8) = o8;
    }
  }

  // q/k epilogue: BN from LDS, bf16x4 stores.
  const int c = c16 + l16;
#pragma unroll
  for (int i = 0; i < 8; ++i) {
    const bool isq = (i < 4);
    bf16_t* dst = isq ? qt : kt;
    const int o0  = (i & 3) * 16 + quad * 4;
    const int bno = (isq ? 0 : 64) + o0;
    bf16x4 w;
#pragma unroll
    for (int r = 0; r < 4; ++r) {
      float y = acc[i][r] * bnsc[bno + r] + bnsh[bno + r];
      y = fmaxf(y, 0.f);
      w[r] = (bf16_t)y;
    }
    *(bf16x4*)(dst + ((size_t)b * C_ + c) * DQ_ + o0) = w;
  }
}

// ---------------- Kernel 2: v GEMM, m97-style staged (flat 8192x1024x1024) ----
// XCD-aware remap (r8-verified win ~17us): linear wgid & 7 selects the XCD, so
// group the 8 o-tiles of each row-panel onto ONE XCD: per-XCD working set =
// 8 y-panels of xT (2 MiB) + Wvb (2 MiB) ~= L2, instead of every XCD streaming
// the whole 16.8 MiB xT.
__global__ __launch_bounds__(256, 2) void k_vgemm(const bf16_t* __restrict__ Wvb,
                                                  const bf16_t* __restrict__ xT,
                                                  const float* __restrict__ g,
                                                  const float* __restrict__ be,
                                                  const float* __restrict__ mu,
                                                  const float* __restrict__ va,
                                                  bf16_t* __restrict__ vT) {
  __shared__ __align__(16) bf16_t As[2][128 * 64];
  __shared__ __align__(16) bf16_t Bs[2][128 * 64];
  const int tid  = threadIdx.x;
  const int wave = tid >> 6;
  const int lane = tid & 63;
  const int quad = lane >> 4;
  const int l16  = lane & 15;
  const int wid  = blockIdx.y * 8 + blockIdx.x;     // linear dispatch id
  const int xcd  = wid & 7;
  const int j    = wid >> 3;
  const int o0 = (j >> 3) * 128;                    // o-tile: streams per XCD
  const int r0 = ((xcd << 3) | (j & 7)) * 128;      // row-panel: pinned to XCD
  const bf16_t* Ab = Wvb + (size_t)o0 * C_;
  const bf16_t* Bb = xT + (size_t)r0 * C_;
  const int wr = (wave >> 1) * 64, wc = (wave & 1) * 64;

  stage32(Ab, C_, (bf16_t*)As[0], wave, lane);
  stage32(Bb, C_, (bf16_t*)Bs[0], wave, lane);

  f32x4 acc[4][4];
#pragma unroll
  for (int i = 0; i < 4; ++i)
#pragma unroll
    for (int j2 = 0; j2 < 4; ++j2) acc[i][j2] = (f32x4){0.f, 0.f, 0.f, 0.f};

  for (int ks = 0; ks < 16; ++ks) {
    __syncthreads();
    const bf16_t* ca = As[ks & 1];
    const bf16_t* cb = Bs[ks & 1];
    if (ks < 15) {
      stage32(Ab + (ks + 1) * 64, C_, (bf16_t*)As[(ks + 1) & 1], wave, lane);
      stage32(Bb + (ks + 1) * 64, C_, (bf16_t*)Bs[(ks + 1) & 1], wave, lane);
    }
#pragma unroll
    for (int ksub = 0; ksub < 2; ++ksub) {
      bf16x8 a[4], bfr[4];
#pragma unroll
      for (int i = 0; i < 4; ++i) {
        const int r = wr + i * 16 + l16;
        const int s = ((ksub * 4 + quad) + r) & 7;
        a[i] = *(const bf16x8*)(ca + r * 64 + s * 8);
      }
#pragma unroll
      for (int j2 = 0; j2 < 4; ++j2) {
        const int r = wc + j2 * 16 + l16;
        const int s = ((ksub * 4 + quad) + r) & 7;
        bfr[j2] = *(const bf16x8*)(cb + r * 64 + s * 8);
      }
#pragma unroll
      for (int i = 0; i < 4; ++i)
#pragma unroll
        for (int j2 = 0; j2 < 4; ++j2)
          acc[i][j2] = mfma16(a[i], bfr[j2], acc[i][j2]);
    }
  }

#pragma unroll
  for (int i = 0; i < 4; ++i)
#pragma unroll
    for (int r = 0; r < 4; ++r) {
      const int o = o0 + wr + i * 16 + quad * 4 + r;
      const float sc = g[o] * rsqrtf(va[o] + 1e-5f);
      const float mm = mu[o], bt = be[o];
#pragma unroll
      for (int j2 = 0; j2 < 4; ++j2) {
        const int rG = r0 + wc + j2 * 16 + l16;
        float y = (acc[i][j2][r] - mm) * sc + bt;
        y = fmaxf(y, 0.f);
        vT[(size_t)rG * C_ + o] = (bf16_t)y;
      }
    }
}

// ---------------- Kernel 3: fused sim -> softmax -> out ----------------
// 512 thr / 8 waves. LDS-staged Q/V via async global_load_lds, barrier-free
// Phases A/C with per-wave counted s_waitcnt vmcnt(4) (r6-verified, 68.5us).
// ebuf: 8-chunk rotation (r6-proven; r7 16-wide variant was bank-neutral by
// derivation and measured slower; reverted in r9, confirmed ~71us).
static __device__ __forceinline__ int eaddr(int c, int d) {
  const int ch = d >> 3;
  const int ph = (ch & ~7) | ((ch + c) & 7);
  return (c << 10) + (ph << 3) + (d & 7);
}

__global__ __launch_bounds__(512, 2) void k_fused(const bf16_t* __restrict__ qt,
                                                  const bf16_t* __restrict__ kt,
                                                  const bf16_t* __restrict__ vT,
                                                  const float* __restrict__ x,
                                                  const float* __restrict__ alphap,
                                                  float* __restrict__ out) {
  __shared__ __align__(16) bf16_t ebuf[32 * 1024];
  __shared__ __align__(16) bf16_t vs[2][256 * 64];
  __shared__ float redmin[8][32];
  __shared__ float redsum[8][32];
  __shared__ float rowmin[32];
  __shared__ float rowrinv[32];

  const int tid  = threadIdx.x;
  const int wave = tid >> 6;
  const int lane = tid & 63;
  const int quad = lane >> 4;
  const int l16  = lane & 15;
  const int id   = blockIdx.x;
  const int b    = ((id & 7) << 2) | (id >> 8);        // 32 blocks/batch on one XCD
  const int c0   = ((id >> 3) & 31) << 5;

  const bf16_t* qb  = qt + (size_t)b * C_ * DQ_;
  const bf16_t* ktb = kt + ((size_t)b * C_ + c0) * DQ_;

  bf16x8 am[2][2];
#pragma unroll
  for (int i = 0; i < 2; ++i)
#pragma unroll
    for (int ksub = 0; ksub < 2; ++ksub)
      am[i][ksub] = *(const bf16x8*)(ktb + (size_t)(i * 16 + l16) * DQ_ + ksub * 32 + quad * 8);

  // ---- Phase A: sim (32 c x 1024 d), per-wave staged, barrier-free ----
  stage32(qb, DQ_, (bf16_t*)vs[0], wave, lane);
  f32x4 sim[2][8];
#pragma unroll
  for (int i = 0; i < 2; ++i)
#pragma unroll
    for (int nt = 0; nt < 8; ++nt) sim[i][nt] = (f32x4){0.f, 0.f, 0.f, 0.f};

#pragma unroll
  for (int t = 0; t < 4; ++t) {
    if (t < 3) {
      stage32(qb + (size_t)(t + 1) * 256 * DQ_, DQ_, (bf16_t*)vs[(t + 1) & 1], wave, lane);
      asm volatile("s_waitcnt vmcnt(4)" ::: "memory");
    } else {
      asm volatile("s_waitcnt vmcnt(0)" ::: "memory");
    }
    const bf16_t* cur = vs[t & 1];
#pragma unroll
    for (int jn = 0; jn < 2; ++jn) {
      const int r = wave * 32 + jn * 16 + l16;
#pragma unroll
      for (int ksub = 0; ksub < 2; ++ksub) {
        const int s = ((ksub * 4 + quad) + r) & 7;
        const bf16x8 bq = *(const bf16x8*)(cur + r * 64 + s * 8);
        sim[0][t * 2 + jn] = mfma16(am[0][ksub], bq, sim[0][t * 2 + jn]);
        sim[1][t * 2 + jn] = mfma16(am[1][ksub], bq, sim[1][t * 2 + jn]);
      }
    }
  }

  // Prologue staging for Phase C (latency hidden under Phase B)
  const bf16_t* vb = vT + (size_t)b * N_ * C_;
  stage32(vb, C_, (bf16_t*)vs[0], wave, lane);

  // ---- Phase B: row-min shift, exp, row-sum (ebuf is cross-wave: barriers) ----
  float pmin[2][4];
#pragma unroll
  for (int i = 0; i < 2; ++i)
#pragma unroll
    for (int r = 0; r < 4; ++r) pmin[i][r] = sim[i][0][r];
#pragma unroll
  for (int nt = 1; nt < 8; ++nt)
#pragma unroll
    for (int i = 0; i < 2; ++i)
#pragma unroll
      for (int r = 0; r < 4; ++r) pmin[i][r] = fminf(pmin[i][r], sim[i][nt][r]);
#pragma unroll
  for (int m = 1; m < 16; m <<= 1)
#pragma unroll
    for (int i = 0; i < 2; ++i)
#pragma unroll
      for (int r = 0; r < 4; ++r) pmin[i][r] = fminf(pmin[i][r], __shfl_xor(pmin[i][r], m));
  if (l16 == 0)
#pragma unroll
    for (int i = 0; i < 2; ++i)
#pragma unroll
      for (int r = 0; r < 4; ++r) redmin[wave][i * 16 + quad * 4 + r] = pmin[i][r];
  __syncthreads();
  if (tid < 32) {
    float v = redmin[0][tid];
#pragma unroll
    for (int w = 1; w < 8; ++w) v = fminf(v, redmin[w][tid]);
    rowmin[tid] = v;
  }
  __syncthreads();

  float mn[2][4], psum[2][4];
#pragma unroll
  for (int i = 0; i < 2; ++i)
#pragma unroll
    for (int r = 0; r < 4; ++r) {
      mn[i][r] = rowmin[i * 16 + quad * 4 + r];
      psum[i][r] = 0.f;
    }
#pragma unroll
  for (int nt = 0; nt < 8; ++nt) {
    const int d = ((nt >> 1) << 8) + wave * 32 + ((nt & 1) << 4) + l16;
#pragma unroll
    for (int i = 0; i < 2; ++i)
#pragma unroll
      for (int r = 0; r < 4; ++r) {
        const int c = i * 16 + quad * 4 + r;
        const float e = __expf(mn[i][r] - sim[i][nt][r]);
        ebuf[eaddr(c, d)] = (bf16_t)e;
        psum[i][r] += e;
      }
  }
#pragma unroll
  for (int m = 1; m < 16; m <<= 1)
#pragma unroll
    for (int i = 0; i < 2; ++i)
#pragma unroll
      for (int r = 0; r < 4; ++r) psum[i][r] += __shfl_xor(psum[i][r], m);
  if (l16 == 0)
#pragma unroll
    for (int i = 0; i < 2; ++i)
#pragma unroll
      for (int r = 0; r < 4; ++r) redsum[wave][i * 16 + quad * 4 + r] = psum[i][r];
  __syncthreads();
  if (tid < 32) {
    float s = redsum[0][tid];
#pragma unroll
    for (int w = 1; w < 8; ++w) s += redsum[w][tid];
    rowrinv[tid] = 1.f / s;
  }
  __syncthreads();   // ebuf + rowrinv visible; also drains V prologue (long done)

  // ---- Phase C: out = e @ vT, per-wave staged, barrier-free ----
  f32x4 oacc[2][2];
#pragma unroll
  for (int i = 0; i < 2; ++i)
#pragma unroll
    for (int jn = 0; jn < 2; ++jn) oacc[i][jn] = (f32x4){0.f, 0.f, 0.f, 0.f};

#pragma unroll
  for (int ks = 0; ks < 16; ++ks) {
    if (ks < 15) {
      stage32(vb + (ks + 1) * 64, C_, (bf16_t*)vs[(ks + 1) & 1], wave, lane);
      asm volatile("s_waitcnt vmcnt(4)" ::: "memory");
    } else {
      asm volatile("s_waitcnt vmcnt(0)" ::: "memory");
    }
    const bf16_t* cur = vs[ks & 1];
#pragma unroll
    for (int ksub = 0; ksub < 2; ++ksub) {
      const int gch = ks * 8 + ksub * 4 + quad;
      const int ph  = (gch & ~7) | ((gch + l16) & 7);
      const bf16x8 ae0 = *(const bf16x8*)(ebuf + ((size_t)l16 << 10) + ph * 8);
      const bf16x8 ae1 = *(const bf16x8*)(ebuf + ((size_t)(16 + l16) << 10) + ph * 8);
#pragma unroll
      for (int jn = 0; jn < 2; ++jn) {
        const int r = wave * 32 + jn * 16 + l16;
        const int s = ((ksub * 4 + quad) + r) & 7;
        const bf16x8 bv = *(const bf16x8*)(cur + r * 64 + s * 8);
        oacc[0][jn] = mfma16(ae0, bv, oacc[0][jn]);
        oacc[1][jn] = mfma16(ae1, bv, oacc[1][jn]);
      }
    }
  }

  const float alpha = alphap[0];
#pragma unroll
  for (int i = 0; i < 2; ++i)
#pragma unroll
    for (int jn = 0; jn < 2; ++jn)
#pragma unroll
      for (int r = 0; r < 4; ++r) {
        const int c = c0 + i * 16 + quad * 4 + r;
        const int n = wave * 32 + jn * 16 + l16;
        const size_t idx = ((size_t)b * C_ + c) * N_ + n;
        out[idx] = alpha * (oacc[i][jn][r] * rowrinv[i * 16 + quad * 4 + r]) + x[idx];
      }
}

extern "C" void kernel_launch(void* const* d_in, const int* in_sizes, int n_in,
                              void* d_out, int out_size, void* d_ws, size_t ws_size,
                              hipStream_t stream) {
  const float* x    = (const float*)d_in[0];
  const float* Wq   = (const float*)d_in[1];
  const float* Wk   = (const float*)d_in[2];
  const float* Wv   = (const float*)d_in[3];
  const float* bn1g = (const float*)d_in[4];
  const float* bn1b = (const float*)d_in[5];
  const float* bn1m = (const float*)d_in[6];
  const float* bn1v = (const float*)d_in[7];
  const float* bn2g = (const float*)d_in[8];
  const float* bn2b = (const float*)d_in[9];
  const float* bn2m = (const float*)d_in[10];
  const float* bn2v = (const float*)d_in[11];
  const float* bn3g = (const float*)d_in[12];
  const float* bn3b = (const float*)d_in[13];
  const float* bn3m = (const float*)d_in[14];
  const float* bn3v = (const float*)d_in[15];
  const float* alph = (const float*)d_in[16];
  float* outp = (float*)d_out;

  char* ws = (char*)d_ws;
  bf16_t* qt   = (bf16_t*)(ws);                              // 4 MiB  (B,C,DQ)
  bf16_t* kt   = (bf16_t*)(ws + (size_t)(4u << 20));         // 4 MiB  (B,C,DQ)
  bf16_t* vT   = (bf16_t*)(ws + (size_t)(8u << 20));         // 16 MiB (B,N,C)
  bf16_t* xT   = (bf16_t*)(ws + (size_t)(24u << 20));        // 16 MiB (B,N,C)
  bf16_t* Wvb  = (bf16_t*)(ws + (size_t)(40u << 20));        // 2 MiB  (C,C)
  bf16_t* Wqkb = (bf16_t*)(ws + (size_t)(42u << 20));        // 64 KiB (128,N)

  k_cvt<<<dim3(528), 256, 0, stream>>>(Wv, Wq, Wk, Wvb, Wqkb);
  k_qkt<<<dim3(16, 32), 256, 0, stream>>>(x, Wqkb,
                                          bn1g, bn1b, bn1m, bn1v,
                                          bn2g, bn2b, bn2m, bn2v, qt, kt, xT);
  k_vgemm<<<dim3(8, 64), 256, 0, stream>>>(Wvb, xT, bn3g, bn3b, bn3m, bn3v, vT);
  k_fused<<<dim3(1024), 512, 0, stream>>>(qt, kt, vT, x, alph, outp);
}

// Round 13
// 226.967 us; speedup vs baseline: 1.1915x; 1.0038x over previous
//
#include <hip/hip_runtime.h>
#include <hip/hip_bf16.h>

#define B_  32
#define C_  1024
#define N_  256
#define DQ_ 64

typedef __bf16 bf16_t;
typedef __bf16 bf16x4 __attribute__((ext_vector_type(4)));
typedef __bf16 bf16x8 __attribute__((ext_vector_type(8)));
typedef float  f32x4  __attribute__((ext_vector_type(4)));

static __device__ __forceinline__ f32x4 mfma16(bf16x8 a, bf16x8 b, f32x4 c) {
  return __builtin_amdgcn_mfma_f32_16x16x32_bf16(a, b, c, 0, 0, 0);
}

static __device__ __forceinline__ bf16x8 ldcvt(const float* p) {
  const float4 a = *(const float4*)p;
  const float4 b = *(const float4*)(p + 4);
  bf16x8 r;
  r[0] = (bf16_t)a.x; r[1] = (bf16_t)a.y; r[2] = (bf16_t)a.z; r[3] = (bf16_t)a.w;
  r[4] = (bf16_t)b.x; r[5] = (bf16_t)b.y; r[6] = (bf16_t)b.z; r[7] = (bf16_t)b.w;
  return r;
}

// Swizzled global->LDS staging, 32 rows/wave (4 loads). Row r, slot j holds
// global chunk (j - r) & 7. Wave w touches only rows [w*32, w*32+32).
static __device__ __forceinline__ void stage32(const bf16_t* grow0, size_t gstride,
                                               bf16_t* tile, int wave, int lane) {
#pragma unroll
  for (int t = 0; t < 4; ++t) {
    const int rb = wave * 32 + t * 8;
    const int r  = rb + (lane >> 3);
    const int g  = ((lane & 7) - r) & 7;
    const bf16_t* src = grow0 + (size_t)r * gstride + g * 8;
    __builtin_amdgcn_global_load_lds(
        (const __attribute__((address_space(1))) void*)src,
        (__attribute__((address_space(3))) void*)(tile + rb * 64), 16, 0, 0);
  }
}

// ---------------- Kernel CVT: Wv, Wq, Wk f32 -> bf16 ----------------
__global__ __launch_bounds__(256) void k_cvt(const float* __restrict__ Wv,
                                             const float* __restrict__ Wq,
                                             const float* __restrict__ Wk,
                                             bf16_t* __restrict__ Wvb,
                                             bf16_t* __restrict__ Wqkb) {
  const int gid = blockIdx.x * 256 + threadIdx.x;
  if (blockIdx.x < 512) {
    const int i = gid * 8;
    *(bf16x8*)(Wvb + i) = ldcvt(Wv + i);
  } else {
    const int g2 = (gid - 512 * 256) * 8;
    if (g2 < 16384) *(bf16x8*)(Wqkb + g2) = ldcvt(Wq + g2);
    else            *(bf16x8*)(Wqkb + g2) = ldcvt(Wk + (g2 - 16384));
  }
}

// ---------------- Kernel 1: fused q+k projection + x transpose (r11) ----------
__global__ __launch_bounds__(256) void k_qkt(const float* __restrict__ x,
                                             const bf16_t* __restrict__ Wqkb,
                                             const float* __restrict__ g1,
                                             const float* __restrict__ b1,
                                             const float* __restrict__ m1,
                                             const float* __restrict__ v1,
                                             const float* __restrict__ g2,
                                             const float* __restrict__ b2,
                                             const float* __restrict__ m2,
                                             const float* __restrict__ v2,
                                             bf16_t* __restrict__ qt,
                                             bf16_t* __restrict__ kt,
                                             bf16_t* __restrict__ xT) {
  __shared__ __align__(16) bf16_t txp[64][264];
  __shared__ float bnsc[128], bnsh[128];
  const int tid  = threadIdx.x;
  const int wave = tid >> 6;
  const int lane = tid & 63;
  const int quad = lane >> 4;
  const int l16  = lane & 15;
  const int b    = blockIdx.y;
  const int c16  = blockIdx.x * 64 + wave * 16;
  const int cl   = wave * 16 + l16;
  const float* xb = x + (size_t)b * C_ * N_;

  if (tid < 128) {
    const int o = tid & 63;
    const bool isq = tid < 64;
    const float sc = (isq ? g1[o] : g2[o]) * rsqrtf((isq ? v1[o] : v2[o]) + 1e-5f);
    bnsc[tid] = sc;
    bnsh[tid] = (isq ? b1[o] : b2[o]) - (isq ? m1[o] : m2[o]) * sc;
  }

  f32x4 acc[8];
#pragma unroll
  for (int i = 0; i < 8; ++i) acc[i] = (f32x4){0.f, 0.f, 0.f, 0.f};

  for (int ks = 0; ks < 8; ++ks) {
    const int k0 = ks * 32 + quad * 8;
    const bf16x8 bx = ldcvt(xb + (size_t)(c16 + l16) * N_ + k0);
    *(bf16x8*)(&txp[cl][k0]) = bx;
#pragma unroll
    for (int i = 0; i < 8; ++i) {
      const bf16x8 aw = *(const bf16x8*)(Wqkb + (size_t)(i * 16 + l16) * N_ + k0);
      acc[i] = mfma16(aw, bx, acc[i]);
    }
  }
  __syncthreads();

  {
    bf16_t* xtb = xT + (size_t)b * N_ * C_ + (size_t)tid * C_ + blockIdx.x * 64;
#pragma unroll
    for (int cc = 0; cc < 8; ++cc) {
      bf16x8 o8;
#pragma unroll
      for (int j = 0; j < 8; ++j) o8[j] = txp[cc * 8 + j][tid];
      *(bf16x8*)(xtb + cc * 8) = o8;
    }
  }

  const int c = c16 + l16;
#pragma unroll
  for (int i = 0; i < 8; ++i) {
    const bool isq = (i < 4);
    bf16_t* dst = isq ? qt : kt;
    const int o0  = (i & 3) * 16 + quad * 4;
    const int bno = (isq ? 0 : 64) + o0;
    bf16x4 w;
#pragma unroll
    for (int r = 0; r < 4; ++r) {
      float y = acc[i][r] * bnsc[bno + r] + bnsh[bno + r];
      y = fmaxf(y, 0.f);
      w[r] = (bf16_t)y;
    }
    *(bf16x4*)(dst + ((size_t)b * C_ + c) * DQ_ + o0) = w;
  }
}

// ---------------- Kernel 2: v GEMM (XCD-pinned remap, r8-verified) ----------
__global__ __launch_bounds__(256, 2) void k_vgemm(const bf16_t* __restrict__ Wvb,
                                                  const bf16_t* __restrict__ xT,
                                                  const float* __restrict__ g,
                                                  const float* __restrict__ be,
                                                  const float* __restrict__ mu,
                                                  const float* __restrict__ va,
                                                  bf16_t* __restrict__ vT) {
  __shared__ __align__(16) bf16_t As[2][128 * 64];
  __shared__ __align__(16) bf16_t Bs[2][128 * 64];
  const int tid  = threadIdx.x;
  const int wave = tid >> 6;
  const int lane = tid & 63;
  const int quad = lane >> 4;
  const int l16  = lane & 15;
  const int wid  = blockIdx.y * 8 + blockIdx.x;
  const int xcd  = wid & 7;
  const int j    = wid >> 3;
  const int o0 = (j >> 3) * 128;
  const int r0 = ((xcd << 3) | (j & 7)) * 128;
  const bf16_t* Ab = Wvb + (size_t)o0 * C_;
  const bf16_t* Bb = xT + (size_t)r0 * C_;
  const int wr = (wave >> 1) * 64, wc = (wave & 1) * 64;

  stage32(Ab, C_, (bf16_t*)As[0], wave, lane);
  stage32(Bb, C_, (bf16_t*)Bs[0], wave, lane);

  f32x4 acc[4][4];
#pragma unroll
  for (int i = 0; i < 4; ++i)
#pragma unroll
    for (int j2 = 0; j2 < 4; ++j2) acc[i][j2] = (f32x4){0.f, 0.f, 0.f, 0.f};

  for (int ks = 0; ks < 16; ++ks) {
    __syncthreads();
    const bf16_t* ca = As[ks & 1];
    const bf16_t* cb = Bs[ks & 1];
    if (ks < 15) {
      stage32(Ab + (ks + 1) * 64, C_, (bf16_t*)As[(ks + 1) & 1], wave, lane);
      stage32(Bb + (ks + 1) * 64, C_, (bf16_t*)Bs[(ks + 1) & 1], wave, lane);
    }
#pragma unroll
    for (int ksub = 0; ksub < 2; ++ksub) {
      bf16x8 a[4], bfr[4];
#pragma unroll
      for (int i = 0; i < 4; ++i) {
        const int r = wr + i * 16 + l16;
        const int s = ((ksub * 4 + quad) + r) & 7;
        a[i] = *(const bf16x8*)(ca + r * 64 + s * 8);
      }
#pragma unroll
      for (int j2 = 0; j2 < 4; ++j2) {
        const int r = wc + j2 * 16 + l16;
        const int s = ((ksub * 4 + quad) + r) & 7;
        bfr[j2] = *(const bf16x8*)(cb + r * 64 + s * 8);
      }
#pragma unroll
      for (int i = 0; i < 4; ++i)
#pragma unroll
        for (int j2 = 0; j2 < 4; ++j2)
          acc[i][j2] = mfma16(a[i], bfr[j2], acc[i][j2]);
    }
  }

#pragma unroll
  for (int i = 0; i < 4; ++i)
#pragma unroll
    for (int r = 0; r < 4; ++r) {
      const int o = o0 + wr + i * 16 + quad * 4 + r;
      const float sc = g[o] * rsqrtf(va[o] + 1e-5f);
      const float mm = mu[o], bt = be[o];
#pragma unroll
      for (int j2 = 0; j2 < 4; ++j2) {
        const int rG = r0 + wc + j2 * 16 + l16;
        float y = (acc[i][j2][r] - mm) * sc + bt;
        y = fmaxf(y, 0.f);
        vT[(size_t)rG * C_ + o] = (bf16_t)y;
      }
    }
}

// ---------------- Kernel 3: fused sim -> softmax -> out (r9-verified 8-wave) --
// 512 thr / 8 waves. LDS-staged Q/V via async global_load_lds, barrier-free
// Phases A/C with per-wave counted s_waitcnt vmcnt(4). The r12 16-wave variant
// raced (absmax blowup) -- root cause unidentified; reverted to this verified
// structure.
static __device__ __forceinline__ int eaddr(int c, int d) {
  const int ch = d >> 3;
  const int ph = (ch & ~7) | ((ch + c) & 7);
  return (c << 10) + (ph << 3) + (d & 7);
}

__global__ __launch_bounds__(512, 2) void k_fused(const bf16_t* __restrict__ qt,
                                                  const bf16_t* __restrict__ kt,
                                                  const bf16_t* __restrict__ vT,
                                                  const float* __restrict__ x,
                                                  const float* __restrict__ alphap,
                                                  float* __restrict__ out) {
  __shared__ __align__(16) bf16_t ebuf[32 * 1024];
  __shared__ __align__(16) bf16_t vs[2][256 * 64];
  __shared__ float redmin[8][32];
  __shared__ float redsum[8][32];
  __shared__ float rowmin[32];
  __shared__ float rowrinv[32];

  const int tid  = threadIdx.x;
  const int wave = tid >> 6;
  const int lane = tid & 63;
  const int quad = lane >> 4;
  const int l16  = lane & 15;
  const int id   = blockIdx.x;
  const int b    = ((id & 7) << 2) | (id >> 8);        // 32 blocks/batch on one XCD
  const int c0   = ((id >> 3) & 31) << 5;

  const bf16_t* qb  = qt + (size_t)b * C_ * DQ_;
  const bf16_t* ktb = kt + ((size_t)b * C_ + c0) * DQ_;

  bf16x8 am[2][2];
#pragma unroll
  for (int i = 0; i < 2; ++i)
#pragma unroll
    for (int ksub = 0; ksub < 2; ++ksub)
      am[i][ksub] = *(const bf16x8*)(ktb + (size_t)(i * 16 + l16) * DQ_ + ksub * 32 + quad * 8);

  // ---- Phase A: sim (32 c x 1024 d), per-wave staged, barrier-free ----
  stage32(qb, DQ_, (bf16_t*)vs[0], wave, lane);
  f32x4 sim[2][8];
#pragma unroll
  for (int i = 0; i < 2; ++i)
#pragma unroll
    for (int nt = 0; nt < 8; ++nt) sim[i][nt] = (f32x4){0.f, 0.f, 0.f, 0.f};

#pragma unroll
  for (int t = 0; t < 4; ++t) {
    if (t < 3) {
      stage32(qb + (size_t)(t + 1) * 256 * DQ_, DQ_, (bf16_t*)vs[(t + 1) & 1], wave, lane);
      asm volatile("s_waitcnt vmcnt(4)" ::: "memory");
    } else {
      asm volatile("s_waitcnt vmcnt(0)" ::: "memory");
    }
    const bf16_t* cur = vs[t & 1];
#pragma unroll
    for (int jn = 0; jn < 2; ++jn) {
      const int r = wave * 32 + jn * 16 + l16;
#pragma unroll
      for (int ksub = 0; ksub < 2; ++ksub) {
        const int s = ((ksub * 4 + quad) + r) & 7;
        const bf16x8 bq = *(const bf16x8*)(cur + r * 64 + s * 8);
        sim[0][t * 2 + jn] = mfma16(am[0][ksub], bq, sim[0][t * 2 + jn]);
        sim[1][t * 2 + jn] = mfma16(am[1][ksub], bq, sim[1][t * 2 + jn]);
      }
    }
  }

  // Prologue staging for Phase C (latency hidden under Phase B)
  const bf16_t* vb = vT + (size_t)b * N_ * C_;
  stage32(vb, C_, (bf16_t*)vs[0], wave, lane);

  // ---- Phase B: row-min shift, exp, row-sum (ebuf is cross-wave: barriers) ----
  float pmin[2][4];
#pragma unroll
  for (int i = 0; i < 2; ++i)
#pragma unroll
    for (int r = 0; r < 4; ++r) pmin[i][r] = sim[i][0][r];
#pragma unroll
  for (int nt = 1; nt < 8; ++nt)
#pragma unroll
    for (int i = 0; i < 2; ++i)
#pragma unroll
      for (int r = 0; r < 4; ++r) pmin[i][r] = fminf(pmin[i][r], sim[i][nt][r]);
#pragma unroll
  for (int m = 1; m < 16; m <<= 1)
#pragma unroll
    for (int i = 0; i < 2; ++i)
#pragma unroll
      for (int r = 0; r < 4; ++r) pmin[i][r] = fminf(pmin[i][r], __shfl_xor(pmin[i][r], m));
  if (l16 == 0)
#pragma unroll
    for (int i = 0; i < 2; ++i)
#pragma unroll
      for (int r = 0; r < 4; ++r) redmin[wave][i * 16 + quad * 4 + r] = pmin[i][r];
  __syncthreads();
  if (tid < 32) {
    float v = redmin[0][tid];
#pragma unroll
    for (int w = 1; w < 8; ++w) v = fminf(v, redmin[w][tid]);
    rowmin[tid] = v;
  }
  __syncthreads();

  float mn[2][4], psum[2][4];
#pragma unroll
  for (int i = 0; i < 2; ++i)
#pragma unroll
    for (int r = 0; r < 4; ++r) {
      mn[i][r] = rowmin[i * 16 + quad * 4 + r];
      psum[i][r] = 0.f;
    }
#pragma unroll
  for (int nt = 0; nt < 8; ++nt) {
    const int d = ((nt >> 1) << 8) + wave * 32 + ((nt & 1) << 4) + l16;
#pragma unroll
    for (int i = 0; i < 2; ++i)
#pragma unroll
      for (int r = 0; r < 4; ++r) {
        const int c = i * 16 + quad * 4 + r;
        const float e = __expf(mn[i][r] - sim[i][nt][r]);
        ebuf[eaddr(c, d)] = (bf16_t)e;
        psum[i][r] += e;
      }
  }
#pragma unroll
  for (int m = 1; m < 16; m <<= 1)
#pragma unroll
    for (int i = 0; i < 2; ++i)
#pragma unroll
      for (int r = 0; r < 4; ++r) psum[i][r] += __shfl_xor(psum[i][r], m);
  if (l16 == 0)
#pragma unroll
    for (int i = 0; i < 2; ++i)
#pragma unroll
      for (int r = 0; r < 4; ++r) redsum[wave][i * 16 + quad * 4 + r] = psum[i][r];
  __syncthreads();
  if (tid < 32) {
    float s = redsum[0][tid];
#pragma unroll
    for (int w = 1; w < 8; ++w) s += redsum[w][tid];
    rowrinv[tid] = 1.f / s;
  }
  __syncthreads();   // ebuf + rowrinv visible; also drains V prologue

  // ---- Phase C: out = e @ vT, per-wave staged, barrier-free ----
  f32x4 oacc[2][2];
#pragma unroll
  for (int i = 0; i < 2; ++i)
#pragma unroll
    for (int jn = 0; jn < 2; ++jn) oacc[i][jn] = (f32x4){0.f, 0.f, 0.f, 0.f};

#pragma unroll
  for (int ks = 0; ks < 16; ++ks) {
    if (ks < 15) {
      stage32(vb + (ks + 1) * 64, C_, (bf16_t*)vs[(ks + 1) & 1], wave, lane);
      asm volatile("s_waitcnt vmcnt(4)" ::: "memory");
    } else {
      asm volatile("s_waitcnt vmcnt(0)" ::: "memory");
    }
    const bf16_t* cur = vs[ks & 1];
#pragma unroll
    for (int ksub = 0; ksub < 2; ++ksub) {
      const int gch = ks * 8 + ksub * 4 + quad;
      const int ph  = (gch & ~7) | ((gch + l16) & 7);
      const bf16x8 ae0 = *(const bf16x8*)(ebuf + ((size_t)l16 << 10) + ph * 8);
      const bf16x8 ae1 = *(const bf16x8*)(ebuf + ((size_t)(16 + l16) << 10) + ph * 8);
#pragma unroll
      for (int jn = 0; jn < 2; ++jn) {
        const int r = wave * 32 + jn * 16 + l16;
        const int s = ((ksub * 4 + quad) + r) & 7;
        const bf16x8 bv = *(const bf16x8*)(cur + r * 64 + s * 8);
        oacc[0][jn] = mfma16(ae0, bv, oacc[0][jn]);
        oacc[1][jn] = mfma16(ae1, bv, oacc[1][jn]);
      }
    }
  }

  const float alpha = alphap[0];
#pragma unroll
  for (int i = 0; i < 2; ++i)
#pragma unroll
    for (int jn = 0; jn < 2; ++jn)
#pragma unroll
      for (int r = 0; r < 4; ++r) {
        const int c = c0 + i * 16 + quad * 4 + r;
        const int n = wave * 32 + jn * 16 + l16;
        const size_t idx = ((size_t)b * C_ + c) * N_ + n;
        out[idx] = alpha * (oacc[i][jn][r] * rowrinv[i * 16 + quad * 4 + r]) + x[idx];
      }
}

extern "C" void kernel_launch(void* const* d_in, const int* in_sizes, int n_in,
                              void* d_out, int out_size, void* d_ws, size_t ws_size,
                              hipStream_t stream) {
  const float* x    = (const float*)d_in[0];
  const float* Wq   = (const float*)d_in[1];
  const float* Wk   = (const float*)d_in[2];
  const float* Wv   = (const float*)d_in[3];
  const float* bn1g = (const float*)d_in[4];
  const float* bn1b = (const float*)d_in[5];
  const float* bn1m = (const float*)d_in[6];
  const float* bn1v = (const float*)d_in[7];
  const float* bn2g = (const float*)d_in[8];
  const float* bn2b = (const float*)d_in[9];
  const float* bn2m = (const float*)d_in[10];
  const float* bn2v = (const float*)d_in[11];
  const float* bn3g = (const float*)d_in[12];
  const float* bn3b = (const float*)d_in[13];
  const float* bn3m = (const float*)d_in[14];
  const float* bn3v = (const float*)d_in[15];
  const float* alph = (const float*)d_in[16];
  float* outp = (float*)d_out;

  char* ws = (char*)d_ws;
  bf16_t* qt   = (bf16_t*)(ws);                              // 4 MiB  (B,C,DQ)
  bf16_t* kt   = (bf16_t*)(ws + (size_t)(4u << 20));         // 4 MiB  (B,C,DQ)
  bf16_t* vT   = (bf16_t*)(ws + (size_t)(8u << 20));         // 16 MiB (B,N,C)
  bf16_t* xT   = (bf16_t*)(ws + (size_t)(24u << 20));        // 16 MiB (B,N,C)
  bf16_t* Wvb  = (bf16_t*)(ws + (size_t)(40u << 20));        // 2 MiB  (C,C)
  bf16_t* Wqkb = (bf16_t*)(ws + (size_t)(42u << 20));        // 64 KiB (128,N)

  k_cvt<<<dim3(528), 256, 0, stream>>>(Wv, Wq, Wk, Wvb, Wqkb);
  k_qkt<<<dim3(16, 32), 256, 0, stream>>>(x, Wqkb,
                                          bn1g, bn1b, bn1m, bn1v,
                                          bn2g, bn2b, bn2m, bn2v, qt, kt, xT);
  k_vgemm<<<dim3(8, 64), 256, 0, stream>>>(Wvb, xT, bn3g, bn3b, bn3m, bn3v, vT);
  k_fused<<<dim3(1024), 512, 0, stream>>>(qt, kt, vT, x, alph, outp);
}

// Round 15
// 225.901 us; speedup vs baseline: 1.1971x; 1.0047x over previous
//
#include <hip/hip_runtime.h>
#include <hip/hip_bf16.h>

#define B_  32
#define C_  1024
#define N_  256
#define DQ_ 64

typedef __bf16 bf16_t;
typedef __bf16 bf16x4 __attribute__((ext_vector_type(4)));
typedef __bf16 bf16x8 __attribute__((ext_vector_type(8)));
typedef float  f32x4  __attribute__((ext_vector_type(4)));

static __device__ __forceinline__ f32x4 mfma16(bf16x8 a, bf16x8 b, f32x4 c) {
  return __builtin_amdgcn_mfma_f32_16x16x32_bf16(a, b, c, 0, 0, 0);
}

static __device__ __forceinline__ bf16x8 ldcvt(const float* p) {
  const float4 a = *(const float4*)p;
  const float4 b = *(const float4*)(p + 4);
  bf16x8 r;
  r[0] = (bf16_t)a.x; r[1] = (bf16_t)a.y; r[2] = (bf16_t)a.z; r[3] = (bf16_t)a.w;
  r[4] = (bf16_t)b.x; r[5] = (bf16_t)b.y; r[6] = (bf16_t)b.z; r[7] = (bf16_t)b.w;
  return r;
}

// Swizzled global->LDS staging, 32 rows/wave (4 loads). Row r, slot j holds
// global chunk (j - r) & 7. Wave w touches only rows [w*32, w*32+32).
static __device__ __forceinline__ void stage32(const bf16_t* grow0, size_t gstride,
                                               bf16_t* tile, int wave, int lane) {
#pragma unroll
  for (int t = 0; t < 4; ++t) {
    const int rb = wave * 32 + t * 8;
    const int r  = rb + (lane >> 3);
    const int g  = ((lane & 7) - r) & 7;
    const bf16_t* src = grow0 + (size_t)r * gstride + g * 8;
    __builtin_amdgcn_global_load_lds(
        (const __attribute__((address_space(1))) void*)src,
        (__attribute__((address_space(3))) void*)(tile + rb * 64), 16, 0, 0);
  }
}

// ---------------- Kernel CVT: Wv, Wq, Wk f32 -> bf16 ----------------
__global__ __launch_bounds__(256) void k_cvt(const float* __restrict__ Wv,
                                             const float* __restrict__ Wq,
                                             const float* __restrict__ Wk,
                                             bf16_t* __restrict__ Wvb,
                                             bf16_t* __restrict__ Wqkb) {
  const int gid = blockIdx.x * 256 + threadIdx.x;
  if (blockIdx.x < 512) {
    const int i = gid * 8;
    *(bf16x8*)(Wvb + i) = ldcvt(Wv + i);
  } else {
    const int g2 = (gid - 512 * 256) * 8;
    if (g2 < 16384) *(bf16x8*)(Wqkb + g2) = ldcvt(Wq + g2);
    else            *(bf16x8*)(Wqkb + g2) = ldcvt(Wk + (g2 - 16384));
  }
}

// ---------------- Kernel 1: fused q+k projection + x transpose (r11) ----------
__global__ __launch_bounds__(256) void k_qkt(const float* __restrict__ x,
                                             const bf16_t* __restrict__ Wqkb,
                                             const float* __restrict__ g1,
                                             const float* __restrict__ b1,
                                             const float* __restrict__ m1,
                                             const float* __restrict__ v1,
                                             const float* __restrict__ g2,
                                             const float* __restrict__ b2,
                                             const float* __restrict__ m2,
                                             const float* __restrict__ v2,
                                             bf16_t* __restrict__ qt,
                                             bf16_t* __restrict__ kt,
                                             bf16_t* __restrict__ xT) {
  __shared__ __align__(16) bf16_t txp[64][264];
  __shared__ float bnsc[128], bnsh[128];
  const int tid  = threadIdx.x;
  const int wave = tid >> 6;
  const int lane = tid & 63;
  const int quad = lane >> 4;
  const int l16  = lane & 15;
  const int b    = blockIdx.y;
  const int c16  = blockIdx.x * 64 + wave * 16;
  const int cl   = wave * 16 + l16;
  const float* xb = x + (size_t)b * C_ * N_;

  if (tid < 128) {
    const int o = tid & 63;
    const bool isq = tid < 64;
    const float sc = (isq ? g1[o] : g2[o]) * rsqrtf((isq ? v1[o] : v2[o]) + 1e-5f);
    bnsc[tid] = sc;
    bnsh[tid] = (isq ? b1[o] : b2[o]) - (isq ? m1[o] : m2[o]) * sc;
  }

  f32x4 acc[8];
#pragma unroll
  for (int i = 0; i < 8; ++i) acc[i] = (f32x4){0.f, 0.f, 0.f, 0.f};

  for (int ks = 0; ks < 8; ++ks) {
    const int k0 = ks * 32 + quad * 8;
    const bf16x8 bx = ldcvt(xb + (size_t)(c16 + l16) * N_ + k0);
    *(bf16x8*)(&txp[cl][k0]) = bx;
#pragma unroll
    for (int i = 0; i < 8; ++i) {
      const bf16x8 aw = *(const bf16x8*)(Wqkb + (size_t)(i * 16 + l16) * N_ + k0);
      acc[i] = mfma16(aw, bx, acc[i]);
    }
  }
  __syncthreads();

  {
    bf16_t* xtb = xT + (size_t)b * N_ * C_ + (size_t)tid * C_ + blockIdx.x * 64;
#pragma unroll
    for (int cc = 0; cc < 8; ++cc) {
      bf16x8 o8;
#pragma unroll
      for (int j = 0; j < 8; ++j) o8[j] = txp[cc * 8 + j][tid];
      *(bf16x8*)(xtb + cc * 8) = o8;
    }
  }

  const int c = c16 + l16;
#pragma unroll
  for (int i = 0; i < 8; ++i) {
    const bool isq = (i < 4);
    bf16_t* dst = isq ? qt : kt;
    const int o0  = (i & 3) * 16 + quad * 4;
    const int bno = (isq ? 0 : 64) + o0;
    bf16x4 w;
#pragma unroll
    for (int r = 0; r < 4; ++r) {
      float y = acc[i][r] * bnsc[bno + r] + bnsh[bno + r];
      y = fmaxf(y, 0.f);
      w[r] = (bf16_t)y;
    }
    *(bf16x4*)(dst + ((size_t)b * C_ + c) * DQ_ + o0) = w;
  }
}

// ---------------- Kernel 2: v GEMM (XCD-pinned remap, r8-verified) ----------
__global__ __launch_bounds__(256, 2) void k_vgemm(const bf16_t* __restrict__ Wvb,
                                                  const bf16_t* __restrict__ xT,
                                                  const float* __restrict__ g,
                                                  const float* __restrict__ be,
                                                  const float* __restrict__ mu,
                                                  const float* __restrict__ va,
                                                  bf16_t* __restrict__ vT) {
  __shared__ __align__(16) bf16_t As[2][128 * 64];
  __shared__ __align__(16) bf16_t Bs[2][128 * 64];
  const int tid  = threadIdx.x;
  const int wave = tid >> 6;
  const int lane = tid & 63;
  const int quad = lane >> 4;
  const int l16  = lane & 15;
  const int wid  = blockIdx.y * 8 + blockIdx.x;
  const int xcd  = wid & 7;
  const int j    = wid >> 3;
  const int o0 = (j >> 3) * 128;
  const int r0 = ((xcd << 3) | (j & 7)) * 128;
  const bf16_t* Ab = Wvb + (size_t)o0 * C_;
  const bf16_t* Bb = xT + (size_t)r0 * C_;
  const int wr = (wave >> 1) * 64, wc = (wave & 1) * 64;

  stage32(Ab, C_, (bf16_t*)As[0], wave, lane);
  stage32(Bb, C_, (bf16_t*)Bs[0], wave, lane);

  f32x4 acc[4][4];
#pragma unroll
  for (int i = 0; i < 4; ++i)
#pragma unroll
    for (int j2 = 0; j2 < 4; ++j2) acc[i][j2] = (f32x4){0.f, 0.f, 0.f, 0.f};

  for (int ks = 0; ks < 16; ++ks) {
    __syncthreads();
    const bf16_t* ca = As[ks & 1];
    const bf16_t* cb = Bs[ks & 1];
    if (ks < 15) {
      stage32(Ab + (ks + 1) * 64, C_, (bf16_t*)As[(ks + 1) & 1], wave, lane);
      stage32(Bb + (ks + 1) * 64, C_, (bf16_t*)Bs[(ks + 1) & 1], wave, lane);
    }
#pragma unroll
    for (int ksub = 0; ksub < 2; ++ksub) {
      bf16x8 a[4], bfr[4];
#pragma unroll
      for (int i = 0; i < 4; ++i) {
        const int r = wr + i * 16 + l16;
        const int s = ((ksub * 4 + quad) + r) & 7;
        a[i] = *(const bf16x8*)(ca + r * 64 + s * 8);
      }
#pragma unroll
      for (int j2 = 0; j2 < 4; ++j2) {
        const int r = wc + j2 * 16 + l16;
        const int s = ((ksub * 4 + quad) + r) & 7;
        bfr[j2] = *(const bf16x8*)(cb + r * 64 + s * 8);
      }
#pragma unroll
      for (int i = 0; i < 4; ++i)
#pragma unroll
        for (int j2 = 0; j2 < 4; ++j2)
          acc[i][j2] = mfma16(a[i], bfr[j2], acc[i][j2]);
    }
  }

#pragma unroll
  for (int i = 0; i < 4; ++i)
#pragma unroll
    for (int r = 0; r < 4; ++r) {
      const int o = o0 + wr + i * 16 + quad * 4 + r;
      const float sc = g[o] * rsqrtf(va[o] + 1e-5f);
      const float mm = mu[o], bt = be[o];
#pragma unroll
      for (int j2 = 0; j2 < 4; ++j2) {
        const int rG = r0 + wc + j2 * 16 + l16;
        float y = (acc[i][j2][r] - mm) * sc + bt;
        y = fmaxf(y, 0.f);
        vT[(size_t)rG * C_ + o] = (bf16_t)y;
      }
    }
}

// ---------------- Kernel 3: fused sim -> softmax -> out (r14: persistent) -----
// 512 thr / 8 waves, grid 256 (1/CU), each block loops 4 iterations with the
// identical (b,c0) mapping as the old 1024-block grid (id'=id+256k => same XCD
// locality, algebraically exact). Adds: next-iter Q-tile0 prefetch issued after
// the last vs read (hides under the x-read/out-write epilogue), and setprio(1)
// around MFMA clusters (T5: waves are phase-desynced in the barrier-free
// structure). Cross-iter safety: each wave's epilogue(i) precedes its barrier#1
// of iter i+1 in program order, and ebuf/rowrinv writes of i+1 happen only
// after barriers all waves reach => no race on shared state.
static __device__ __forceinline__ int eaddr(int c, int d) {
  const int ch = d >> 3;
  const int ph = (ch & ~7) | ((ch + c) & 7);
  return (c << 10) + (ph << 3) + (d & 7);
}

__global__ __launch_bounds__(512, 2) void k_fused(const bf16_t* __restrict__ qt,
                                                  const bf16_t* __restrict__ kt,
                                                  const bf16_t* __restrict__ vT,
                                                  const float* __restrict__ x,
                                                  const float* __restrict__ alphap,
                                                  float* __restrict__ out) {
  __shared__ __align__(16) bf16_t ebuf[32 * 1024];
  __shared__ __align__(16) bf16_t vs[2][256 * 64];
  __shared__ float redmin[8][32];
  __shared__ float redsum[8][32];
  __shared__ float rowmin[32];
  __shared__ float rowrinv[32];

  const int tid  = threadIdx.x;
  const int wave = tid >> 6;
  const int lane = tid & 63;
  const int quad = lane >> 4;
  const int l16  = lane & 15;
  const int id   = blockIdx.x;                 // 0..255
  const int c0   = ((id >> 3) & 31) << 5;

#pragma unroll 1
  for (int it = 0; it < 4; ++it) {
    const int b = ((id & 7) << 2) | it;
    const bf16_t* qb  = qt + (size_t)b * C_ * DQ_;
    const bf16_t* ktb = kt + ((size_t)b * C_ + c0) * DQ_;
    const bf16_t* vb  = vT + (size_t)b * N_ * C_;

    bf16x8 am[2][2];
#pragma unroll
    for (int i = 0; i < 2; ++i)
#pragma unroll
      for (int ksub = 0; ksub < 2; ++ksub)
        am[i][ksub] = *(const bf16x8*)(ktb + (size_t)(i * 16 + l16) * DQ_ + ksub * 32 + quad * 8);

    // ---- Phase A: sim (32 c x 1024 d), per-wave staged, barrier-free ----
    if (it == 0) stage32(qb, DQ_, (bf16_t*)vs[0], wave, lane);  // else: prefetched
    f32x4 sim[2][8];
#pragma unroll
    for (int i = 0; i < 2; ++i)
#pragma unroll
      for (int nt = 0; nt < 8; ++nt) sim[i][nt] = (f32x4){0.f, 0.f, 0.f, 0.f};

#pragma unroll
    for (int t = 0; t < 4; ++t) {
      if (t < 3) {
        stage32(qb + (size_t)(t + 1) * 256 * DQ_, DQ_, (bf16_t*)vs[(t + 1) & 1], wave, lane);
        asm volatile("s_waitcnt vmcnt(4)" ::: "memory");
      } else {
        asm volatile("s_waitcnt vmcnt(0)" ::: "memory");
      }
      const bf16_t* cur = vs[t & 1];
      __builtin_amdgcn_s_setprio(1);
#pragma unroll
      for (int jn = 0; jn < 2; ++jn) {
        const int r = wave * 32 + jn * 16 + l16;
#pragma unroll
        for (int ksub = 0; ksub < 2; ++ksub) {
          const int s = ((ksub * 4 + quad) + r) & 7;
          const bf16x8 bq = *(const bf16x8*)(cur + r * 64 + s * 8);
          sim[0][t * 2 + jn] = mfma16(am[0][ksub], bq, sim[0][t * 2 + jn]);
          sim[1][t * 2 + jn] = mfma16(am[1][ksub], bq, sim[1][t * 2 + jn]);
        }
      }
      __builtin_amdgcn_s_setprio(0);
    }

    // Prologue staging for Phase C (latency hidden under Phase B)
    stage32(vb, C_, (bf16_t*)vs[0], wave, lane);

    // ---- Phase B: row-min shift, exp, row-sum (ebuf cross-wave: barriers) ----
    float pmin[2][4];
#pragma unroll
    for (int i = 0; i < 2; ++i)
#pragma unroll
      for (int r = 0; r < 4; ++r) pmin[i][r] = sim[i][0][r];
#pragma unroll
    for (int nt = 1; nt < 8; ++nt)
#pragma unroll
      for (int i = 0; i < 2; ++i)
#pragma unroll
        for (int r = 0; r < 4; ++r) pmin[i][r] = fminf(pmin[i][r], sim[i][nt][r]);
#pragma unroll
    for (int m = 1; m < 16; m <<= 1)
#pragma unroll
      for (int i = 0; i < 2; ++i)
#pragma unroll
        for (int r = 0; r < 4; ++r) pmin[i][r] = fminf(pmin[i][r], __shfl_xor(pmin[i][r], m));
    if (l16 == 0)
#pragma unroll
      for (int i = 0; i < 2; ++i)
#pragma unroll
        for (int r = 0; r < 4; ++r) redmin[wave][i * 16 + quad * 4 + r] = pmin[i][r];
    __syncthreads();
    if (tid < 32) {
      float v = redmin[0][tid];
#pragma unroll
      for (int w = 1; w < 8; ++w) v = fminf(v, redmin[w][tid]);
      rowmin[tid] = v;
    }
    __syncthreads();

    float mn[2][4], psum[2][4];
#pragma unroll
    for (int i = 0; i < 2; ++i)
#pragma unroll
      for (int r = 0; r < 4; ++r) {
        mn[i][r] = rowmin[i * 16 + quad * 4 + r];
        psum[i][r] = 0.f;
      }
#pragma unroll
    for (int nt = 0; nt < 8; ++nt) {
      const int d = ((nt >> 1) << 8) + wave * 32 + ((nt & 1) << 4) + l16;
#pragma unroll
      for (int i = 0; i < 2; ++i)
#pragma unroll
        for (int r = 0; r < 4; ++r) {
          const int c = i * 16 + quad * 4 + r;
          const float e = __expf(mn[i][r] - sim[i][nt][r]);
          ebuf[eaddr(c, d)] = (bf16_t)e;
          psum[i][r] += e;
        }
    }
#pragma unroll
    for (int m = 1; m < 16; m <<= 1)
#pragma unroll
      for (int i = 0; i < 2; ++i)
#pragma unroll
        for (int r = 0; r < 4; ++r) psum[i][r] += __shfl_xor(psum[i][r], m);
    if (l16 == 0)
#pragma unroll
      for (int i = 0; i < 2; ++i)
#pragma unroll
        for (int r = 0; r < 4; ++r) redsum[wave][i * 16 + quad * 4 + r] = psum[i][r];
    __syncthreads();
    if (tid < 32) {
      float s = redsum[0][tid];
#pragma unroll
      for (int w = 1; w < 8; ++w) s += redsum[w][tid];
      rowrinv[tid] = 1.f / s;
    }
    __syncthreads();   // ebuf + rowrinv visible; also drains V prologue

    // ---- Phase C: out = e @ vT, per-wave staged, barrier-free ----
    f32x4 oacc[2][2];
#pragma unroll
    for (int i = 0; i < 2; ++i)
#pragma unroll
      for (int jn = 0; jn < 2; ++jn) oacc[i][jn] = (f32x4){0.f, 0.f, 0.f, 0.f};

#pragma unroll
    for (int ks = 0; ks < 16; ++ks) {
      if (ks < 15) {
        stage32(vb + (ks + 1) * 64, C_, (bf16_t*)vs[(ks + 1) & 1], wave, lane);
        asm volatile("s_waitcnt vmcnt(4)" ::: "memory");
      } else {
        asm volatile("s_waitcnt vmcnt(0)" ::: "memory");
      }
      const bf16_t* cur = vs[ks & 1];
      __builtin_amdgcn_s_setprio(1);
#pragma unroll
      for (int ksub = 0; ksub < 2; ++ksub) {
        const int gch = ks * 8 + ksub * 4 + quad;
        const int ph  = (gch & ~7) | ((gch + l16) & 7);
        const bf16x8 ae0 = *(const bf16x8*)(ebuf + ((size_t)l16 << 10) + ph * 8);
        const bf16x8 ae1 = *(const bf16x8*)(ebuf + ((size_t)(16 + l16) << 10) + ph * 8);
#pragma unroll
        for (int jn = 0; jn < 2; ++jn) {
          const int r = wave * 32 + jn * 16 + l16;
          const int s = ((ksub * 4 + quad) + r) & 7;
          const bf16x8 bv = *(const bf16x8*)(cur + r * 64 + s * 8);
          oacc[0][jn] = mfma16(ae0, bv, oacc[0][jn]);
          oacc[1][jn] = mfma16(ae1, bv, oacc[1][jn]);
        }
      }
      __builtin_amdgcn_s_setprio(0);
    }

    // Prefetch next iteration's Q tile0 into vs[0]: all vs reads are complete
    // (vmcnt(0) at ks=15); DMA latency hides under the epilogue below.
    if (it < 3) {
      const int bn = ((id & 7) << 2) | (it + 1);
      stage32(qt + (size_t)bn * C_ * DQ_, DQ_, (bf16_t*)vs[0], wave, lane);
    }

    const float alpha = alphap[0];
#pragma unroll
    for (int i = 0; i < 2; ++i)
#pragma unroll
      for (int jn = 0; jn < 2; ++jn)
#pragma unroll
        for (int r = 0; r < 4; ++r) {
          const int c = c0 + i * 16 + quad * 4 + r;
          const int n = wave * 32 + jn * 16 + l16;
          const size_t idx = ((size_t)b * C_ + c) * N_ + n;
          out[idx] = alpha * (oacc[i][jn][r] * rowrinv[i * 16 + quad * 4 + r]) + x[idx];
        }
  }
}

extern "C" void kernel_launch(void* const* d_in, const int* in_sizes, int n_in,
                              void* d_out, int out_size, void* d_ws, size_t ws_size,
                              hipStream_t stream) {
  const float* x    = (const float*)d_in[0];
  const float* Wq   = (const float*)d_in[1];
  const float* Wk   = (const float*)d_in[2];
  const float* Wv   = (const float*)d_in[3];
  const float* bn1g = (const float*)d_in[4];
  const float* bn1b = (const float*)d_in[5];
  const float* bn1m = (const float*)d_in[6];
  const float* bn1v = (const float*)d_in[7];
  const float* bn2g = (const float*)d_in[8];
  const float* bn2b = (const float*)d_in[9];
  const float* bn2m = (const float*)d_in[10];
  const float* bn2v = (const float*)d_in[11];
  const float* bn3g = (const float*)d_in[12];
  const float* bn3b = (const float*)d_in[13];
  const float* bn3m = (const float*)d_in[14];
  const float* bn3v = (const float*)d_in[15];
  const float* alph = (const float*)d_in[16];
  float* outp = (float*)d_out;

  char* ws = (char*)d_ws;
  bf16_t* qt   = (bf16_t*)(ws);                              // 4 MiB  (B,C,DQ)
  bf16_t* kt   = (bf16_t*)(ws + (size_t)(4u << 20));         // 4 MiB  (B,C,DQ)
  bf16_t* vT   = (bf16_t*)(ws + (size_t)(8u << 20));         // 16 MiB (B,N,C)
  bf16_t* xT   = (bf16_t*)(ws + (size_t)(24u << 20));        // 16 MiB (B,N,C)
  bf16_t* Wvb  = (bf16_t*)(ws + (size_t)(40u << 20));        // 2 MiB  (C,C)
  bf16_t* Wqkb = (bf16_t*)(ws + (size_t)(42u << 20));        // 64 KiB (128,N)

  k_cvt<<<dim3(528), 256, 0, stream>>>(Wv, Wq, Wk, Wvb, Wqkb);
  k_qkt<<<dim3(16, 32), 256, 0, stream>>>(x, Wqkb,
                                          bn1g, bn1b, bn1m, bn1v,
                                          bn2g, bn2b, bn2m, bn2v, qt, kt, xT);
  k_vgemm<<<dim3(8, 64), 256, 0, stream>>>(Wvb, xT, bn3g, bn3b, bn3m, bn3v, vT);
  k_fused<<<dim3(256), 512, 0, stream>>>(qt, kt, vT, x, alph, outp);
}

// Round 16
// 221.879 us; speedup vs baseline: 1.2188x; 1.0181x over previous
//
#include <hip/hip_runtime.h>
#include <hip/hip_bf16.h>

#define B_  32
#define C_  1024
#define N_  256
#define DQ_ 64

typedef __bf16 bf16_t;
typedef __bf16 bf16x4 __attribute__((ext_vector_type(4)));
typedef __bf16 bf16x8 __attribute__((ext_vector_type(8)));
typedef float  f32x4  __attribute__((ext_vector_type(4)));

static __device__ __forceinline__ f32x4 mfma16(bf16x8 a, bf16x8 b, f32x4 c) {
  return __builtin_amdgcn_mfma_f32_16x16x32_bf16(a, b, c, 0, 0, 0);
}

static __device__ __forceinline__ bf16x8 ldcvt(const float* p) {
  const float4 a = *(const float4*)p;
  const float4 b = *(const float4*)(p + 4);
  bf16x8 r;
  r[0] = (bf16_t)a.x; r[1] = (bf16_t)a.y; r[2] = (bf16_t)a.z; r[3] = (bf16_t)a.w;
  r[4] = (bf16_t)b.x; r[5] = (bf16_t)b.y; r[6] = (bf16_t)b.z; r[7] = (bf16_t)b.w;
  return r;
}

// Swizzled global->LDS staging, 32 rows/wave (4 loads). Row r, slot j holds
// global chunk (j - r) & 7. Wave w touches only rows [w*32, w*32+32).
static __device__ __forceinline__ void stage32(const bf16_t* grow0, size_t gstride,
                                               bf16_t* tile, int wave, int lane) {
#pragma unroll
  for (int t = 0; t < 4; ++t) {
    const int rb = wave * 32 + t * 8;
    const int r  = rb + (lane >> 3);
    const int g  = ((lane & 7) - r) & 7;
    const bf16_t* src = grow0 + (size_t)r * gstride + g * 8;
    __builtin_amdgcn_global_load_lds(
        (const __attribute__((address_space(1))) void*)src,
        (__attribute__((address_space(3))) void*)(tile + rb * 64), 16, 0, 0);
  }
}

// ---------------- Kernel CVT: Wv, Wq, Wk f32 -> bf16 ----------------
__global__ __launch_bounds__(256) void k_cvt(const float* __restrict__ Wv,
                                             const float* __restrict__ Wq,
                                             const float* __restrict__ Wk,
                                             bf16_t* __restrict__ Wvb,
                                             bf16_t* __restrict__ Wqkb) {
  const int gid = blockIdx.x * 256 + threadIdx.x;
  if (blockIdx.x < 512) {
    const int i = gid * 8;
    *(bf16x8*)(Wvb + i) = ldcvt(Wv + i);
  } else {
    const int g2 = (gid - 512 * 256) * 8;
    if (g2 < 16384) *(bf16x8*)(Wqkb + g2) = ldcvt(Wq + g2);
    else            *(bf16x8*)(Wqkb + g2) = ldcvt(Wk + (g2 - 16384));
  }
}

// ---------------- Kernel 1: fused q+k projection + x transpose (r11) ----------
__global__ __launch_bounds__(256) void k_qkt(const float* __restrict__ x,
                                             const bf16_t* __restrict__ Wqkb,
                                             const float* __restrict__ g1,
                                             const float* __restrict__ b1,
                                             const float* __restrict__ m1,
                                             const float* __restrict__ v1,
                                             const float* __restrict__ g2,
                                             const float* __restrict__ b2,
                                             const float* __restrict__ m2,
                                             const float* __restrict__ v2,
                                             bf16_t* __restrict__ qt,
                                             bf16_t* __restrict__ kt,
                                             bf16_t* __restrict__ xT) {
  __shared__ __align__(16) bf16_t txp[64][264];
  __shared__ float bnsc[128], bnsh[128];
  const int tid  = threadIdx.x;
  const int wave = tid >> 6;
  const int lane = tid & 63;
  const int quad = lane >> 4;
  const int l16  = lane & 15;
  const int b    = blockIdx.y;
  const int c16  = blockIdx.x * 64 + wave * 16;
  const int cl   = wave * 16 + l16;
  const float* xb = x + (size_t)b * C_ * N_;

  if (tid < 128) {
    const int o = tid & 63;
    const bool isq = tid < 64;
    const float sc = (isq ? g1[o] : g2[o]) * rsqrtf((isq ? v1[o] : v2[o]) + 1e-5f);
    bnsc[tid] = sc;
    bnsh[tid] = (isq ? b1[o] : b2[o]) - (isq ? m1[o] : m2[o]) * sc;
  }

  f32x4 acc[8];
#pragma unroll
  for (int i = 0; i < 8; ++i) acc[i] = (f32x4){0.f, 0.f, 0.f, 0.f};

  for (int ks = 0; ks < 8; ++ks) {
    const int k0 = ks * 32 + quad * 8;
    const bf16x8 bx = ldcvt(xb + (size_t)(c16 + l16) * N_ + k0);
    *(bf16x8*)(&txp[cl][k0]) = bx;
#pragma unroll
    for (int i = 0; i < 8; ++i) {
      const bf16x8 aw = *(const bf16x8*)(Wqkb + (size_t)(i * 16 + l16) * N_ + k0);
      acc[i] = mfma16(aw, bx, acc[i]);
    }
  }
  __syncthreads();

  {
    bf16_t* xtb = xT + (size_t)b * N_ * C_ + (size_t)tid * C_ + blockIdx.x * 64;
#pragma unroll
    for (int cc = 0; cc < 8; ++cc) {
      bf16x8 o8;
#pragma unroll
      for (int j = 0; j < 8; ++j) o8[j] = txp[cc * 8 + j][tid];
      *(bf16x8*)(xtb + cc * 8) = o8;
    }
  }

  const int c = c16 + l16;
#pragma unroll
  for (int i = 0; i < 8; ++i) {
    const bool isq = (i < 4);
    bf16_t* dst = isq ? qt : kt;
    const int o0  = (i & 3) * 16 + quad * 4;
    const int bno = (isq ? 0 : 64) + o0;
    bf16x4 w;
#pragma unroll
    for (int r = 0; r < 4; ++r) {
      float y = acc[i][r] * bnsc[bno + r] + bnsh[bno + r];
      y = fmaxf(y, 0.f);
      w[r] = (bf16_t)y;
    }
    *(bf16x4*)(dst + ((size_t)b * C_ + c) * DQ_ + o0) = w;
  }
}

// ---------------- Kernel 2: v GEMM (XCD-pinned; r16: counted-vmcnt barriers) --
// Replaces the single __syncthreads (whose compiler-inserted vmcnt(0) drained
// the just-issued next-tile DMAs -- the m97 ~20% barrier-drain stall) with the
// two-raw-barrier counted protocol:
//   barrier_a: all waves done compute(ks-1)  -> safe to overwrite buf (ks+1)&1
//   stage(ks+1); vmcnt(8): own 8 S(ks) DMAs landed, S(ks+1) stays IN FLIGHT
//   barrier_b: every wave passed its vmcnt(8) -> ALL of tile ks landed
//   compute(ks)
// Per-wave vmcnt counts own DMAs only; barrier_b globalizes the guarantee.
// No other in-loop vmem ops (BN loads are post-loop, behind final vmcnt(0)).
__global__ __launch_bounds__(256, 2) void k_vgemm(const bf16_t* __restrict__ Wvb,
                                                  const bf16_t* __restrict__ xT,
                                                  const float* __restrict__ g,
                                                  const float* __restrict__ be,
                                                  const float* __restrict__ mu,
                                                  const float* __restrict__ va,
                                                  bf16_t* __restrict__ vT) {
  __shared__ __align__(16) bf16_t As[2][128 * 64];
  __shared__ __align__(16) bf16_t Bs[2][128 * 64];
  const int tid  = threadIdx.x;
  const int wave = tid >> 6;
  const int lane = tid & 63;
  const int quad = lane >> 4;
  const int l16  = lane & 15;
  const int wid  = blockIdx.y * 8 + blockIdx.x;
  const int xcd  = wid & 7;
  const int j    = wid >> 3;
  const int o0 = (j >> 3) * 128;
  const int r0 = ((xcd << 3) | (j & 7)) * 128;
  const bf16_t* Ab = Wvb + (size_t)o0 * C_;
  const bf16_t* Bb = xT + (size_t)r0 * C_;
  const int wr = (wave >> 1) * 64, wc = (wave & 1) * 64;

  stage32(Ab, C_, (bf16_t*)As[0], wave, lane);
  stage32(Bb, C_, (bf16_t*)Bs[0], wave, lane);

  f32x4 acc[4][4];
#pragma unroll
  for (int i = 0; i < 4; ++i)
#pragma unroll
    for (int j2 = 0; j2 < 4; ++j2) acc[i][j2] = (f32x4){0.f, 0.f, 0.f, 0.f};

  for (int ks = 0; ks < 16; ++ks) {
    __builtin_amdgcn_s_barrier();                 // (a) compute(ks-1) done everywhere
    if (ks < 15) {
      stage32(Ab + (ks + 1) * 64, C_, (bf16_t*)As[(ks + 1) & 1], wave, lane);
      stage32(Bb + (ks + 1) * 64, C_, (bf16_t*)Bs[(ks + 1) & 1], wave, lane);
      asm volatile("s_waitcnt vmcnt(8)" ::: "memory");   // own S(ks) landed
    } else {
      asm volatile("s_waitcnt vmcnt(0)" ::: "memory");
    }
    __builtin_amdgcn_s_barrier();                 // (b) ALL waves' S(ks) landed
    const bf16_t* ca = As[ks & 1];
    const bf16_t* cb = Bs[ks & 1];
#pragma unroll
    for (int ksub = 0; ksub < 2; ++ksub) {
      bf16x8 a[4], bfr[4];
#pragma unroll
      for (int i = 0; i < 4; ++i) {
        const int r = wr + i * 16 + l16;
        const int s = ((ksub * 4 + quad) + r) & 7;
        a[i] = *(const bf16x8*)(ca + r * 64 + s * 8);
      }
#pragma unroll
      for (int j2 = 0; j2 < 4; ++j2) {
        const int r = wc + j2 * 16 + l16;
        const int s = ((ksub * 4 + quad) + r) & 7;
        bfr[j2] = *(const bf16x8*)(cb + r * 64 + s * 8);
      }
#pragma unroll
      for (int i = 0; i < 4; ++i)
#pragma unroll
        for (int j2 = 0; j2 < 4; ++j2)
          acc[i][j2] = mfma16(a[i], bfr[j2], acc[i][j2]);
    }
  }

#pragma unroll
  for (int i = 0; i < 4; ++i)
#pragma unroll
    for (int r = 0; r < 4; ++r) {
      const int o = o0 + wr + i * 16 + quad * 4 + r;
      const float sc = g[o] * rsqrtf(va[o] + 1e-5f);
      const float mm = mu[o], bt = be[o];
#pragma unroll
      for (int j2 = 0; j2 < 4; ++j2) {
        const int rG = r0 + wc + j2 * 16 + l16;
        float y = (acc[i][j2][r] - mm) * sc + bt;
        y = fmaxf(y, 0.f);
        vT[(size_t)rG * C_ + o] = (bf16_t)y;
      }
    }
}

// ---------------- Kernel 3: fused sim -> softmax -> out (r15-verified) --------
// Persistent 256-block grid, 4 iters/block, Q-tile0 prefetch, setprio; 8-wave
// barrier-free Phases A/C with per-wave counted vmcnt(4).
static __device__ __forceinline__ int eaddr(int c, int d) {
  const int ch = d >> 3;
  const int ph = (ch & ~7) | ((ch + c) & 7);
  return (c << 10) + (ph << 3) + (d & 7);
}

__global__ __launch_bounds__(512, 2) void k_fused(const bf16_t* __restrict__ qt,
                                                  const bf16_t* __restrict__ kt,
                                                  const bf16_t* __restrict__ vT,
                                                  const float* __restrict__ x,
                                                  const float* __restrict__ alphap,
                                                  float* __restrict__ out) {
  __shared__ __align__(16) bf16_t ebuf[32 * 1024];
  __shared__ __align__(16) bf16_t vs[2][256 * 64];
  __shared__ float redmin[8][32];
  __shared__ float redsum[8][32];
  __shared__ float rowmin[32];
  __shared__ float rowrinv[32];

  const int tid  = threadIdx.x;
  const int wave = tid >> 6;
  const int lane = tid & 63;
  const int quad = lane >> 4;
  const int l16  = lane & 15;
  const int id   = blockIdx.x;                 // 0..255
  const int c0   = ((id >> 3) & 31) << 5;

#pragma unroll 1
  for (int it = 0; it < 4; ++it) {
    const int b = ((id & 7) << 2) | it;
    const bf16_t* qb  = qt + (size_t)b * C_ * DQ_;
    const bf16_t* ktb = kt + ((size_t)b * C_ + c0) * DQ_;
    const bf16_t* vb  = vT + (size_t)b * N_ * C_;

    bf16x8 am[2][2];
#pragma unroll
    for (int i = 0; i < 2; ++i)
#pragma unroll
      for (int ksub = 0; ksub < 2; ++ksub)
        am[i][ksub] = *(const bf16x8*)(ktb + (size_t)(i * 16 + l16) * DQ_ + ksub * 32 + quad * 8);

    // ---- Phase A: sim (32 c x 1024 d), per-wave staged, barrier-free ----
    if (it == 0) stage32(qb, DQ_, (bf16_t*)vs[0], wave, lane);  // else: prefetched
    f32x4 sim[2][8];
#pragma unroll
    for (int i = 0; i < 2; ++i)
#pragma unroll
      for (int nt = 0; nt < 8; ++nt) sim[i][nt] = (f32x4){0.f, 0.f, 0.f, 0.f};

#pragma unroll
    for (int t = 0; t < 4; ++t) {
      if (t < 3) {
        stage32(qb + (size_t)(t + 1) * 256 * DQ_, DQ_, (bf16_t*)vs[(t + 1) & 1], wave, lane);
        asm volatile("s_waitcnt vmcnt(4)" ::: "memory");
      } else {
        asm volatile("s_waitcnt vmcnt(0)" ::: "memory");
      }
      const bf16_t* cur = vs[t & 1];
      __builtin_amdgcn_s_setprio(1);
#pragma unroll
      for (int jn = 0; jn < 2; ++jn) {
        const int r = wave * 32 + jn * 16 + l16;
#pragma unroll
        for (int ksub = 0; ksub < 2; ++ksub) {
          const int s = ((ksub * 4 + quad) + r) & 7;
          const bf16x8 bq = *(const bf16x8*)(cur + r * 64 + s * 8);
          sim[0][t * 2 + jn] = mfma16(am[0][ksub], bq, sim[0][t * 2 + jn]);
          sim[1][t * 2 + jn] = mfma16(am[1][ksub], bq, sim[1][t * 2 + jn]);
        }
      }
      __builtin_amdgcn_s_setprio(0);
    }

    // Prologue staging for Phase C (latency hidden under Phase B)
    stage32(vb, C_, (bf16_t*)vs[0], wave, lane);

    // ---- Phase B: row-min shift, exp, row-sum (ebuf cross-wave: barriers) ----
    float pmin[2][4];
#pragma unroll
    for (int i = 0; i < 2; ++i)
#pragma unroll
      for (int r = 0; r < 4; ++r) pmin[i][r] = sim[i][0][r];
#pragma unroll
    for (int nt = 1; nt < 8; ++nt)
#pragma unroll
      for (int i = 0; i < 2; ++i)
#pragma unroll
        for (int r = 0; r < 4; ++r) pmin[i][r] = fminf(pmin[i][r], sim[i][nt][r]);
#pragma unroll
    for (int m = 1; m < 16; m <<= 1)
#pragma unroll
      for (int i = 0; i < 2; ++i)
#pragma unroll
        for (int r = 0; r < 4; ++r) pmin[i][r] = fminf(pmin[i][r], __shfl_xor(pmin[i][r], m));
    if (l16 == 0)
#pragma unroll
      for (int i = 0; i < 2; ++i)
#pragma unroll
        for (int r = 0; r < 4; ++r) redmin[wave][i * 16 + quad * 4 + r] = pmin[i][r];
    __syncthreads();
    if (tid < 32) {
      float v = redmin[0][tid];
#pragma unroll
      for (int w = 1; w < 8; ++w) v = fminf(v, redmin[w][tid]);
      rowmin[tid] = v;
    }
    __syncthreads();

    float mn[2][4], psum[2][4];
#pragma unroll
    for (int i = 0; i < 2; ++i)
#pragma unroll
      for (int r = 0; r < 4; ++r) {
        mn[i][r] = rowmin[i * 16 + quad * 4 + r];
        psum[i][r] = 0.f;
      }
#pragma unroll
    for (int nt = 0; nt < 8; ++nt) {
      const int d = ((nt >> 1) << 8) + wave * 32 + ((nt & 1) << 4) + l16;
#pragma unroll
      for (int i = 0; i < 2; ++i)
#pragma unroll
        for (int r = 0; r < 4; ++r) {
          const int c = i * 16 + quad * 4 + r;
          const float e = __expf(mn[i][r] - sim[i][nt][r]);
          ebuf[eaddr(c, d)] = (bf16_t)e;
          psum[i][r] += e;
        }
    }
#pragma unroll
    for (int m = 1; m < 16; m <<= 1)
#pragma unroll
      for (int i = 0; i < 2; ++i)
#pragma unroll
        for (int r = 0; r < 4; ++r) psum[i][r] += __shfl_xor(psum[i][r], m);
    if (l16 == 0)
#pragma unroll
      for (int i = 0; i < 2; ++i)
#pragma unroll
        for (int r = 0; r < 4; ++r) redsum[wave][i * 16 + quad * 4 + r] = psum[i][r];
    __syncthreads();
    if (tid < 32) {
      float s = redsum[0][tid];
#pragma unroll
      for (int w = 1; w < 8; ++w) s += redsum[w][tid];
      rowrinv[tid] = 1.f / s;
    }
    __syncthreads();   // ebuf + rowrinv visible; also drains V prologue

    // ---- Phase C: out = e @ vT, per-wave staged, barrier-free ----
    f32x4 oacc[2][2];
#pragma unroll
    for (int i = 0; i < 2; ++i)
#pragma unroll
      for (int jn = 0; jn < 2; ++jn) oacc[i][jn] = (f32x4){0.f, 0.f, 0.f, 0.f};

#pragma unroll
    for (int ks = 0; ks < 16; ++ks) {
      if (ks < 15) {
        stage32(vb + (ks + 1) * 64, C_, (bf16_t*)vs[(ks + 1) & 1], wave, lane);
        asm volatile("s_waitcnt vmcnt(4)" ::: "memory");
      } else {
        asm volatile("s_waitcnt vmcnt(0)" ::: "memory");
      }
      const bf16_t* cur = vs[ks & 1];
      __builtin_amdgcn_s_setprio(1);
#pragma unroll
      for (int ksub = 0; ksub < 2; ++ksub) {
        const int gch = ks * 8 + ksub * 4 + quad;
        const int ph  = (gch & ~7) | ((gch + l16) & 7);
        const bf16x8 ae0 = *(const bf16x8*)(ebuf + ((size_t)l16 << 10) + ph * 8);
        const bf16x8 ae1 = *(const bf16x8*)(ebuf + ((size_t)(16 + l16) << 10) + ph * 8);
#pragma unroll
        for (int jn = 0; jn < 2; ++jn) {
          const int r = wave * 32 + jn * 16 + l16;
          const int s = ((ksub * 4 + quad) + r) & 7;
          const bf16x8 bv = *(const bf16x8*)(cur + r * 64 + s * 8);
          oacc[0][jn] = mfma16(ae0, bv, oacc[0][jn]);
          oacc[1][jn] = mfma16(ae1, bv, oacc[1][jn]);
        }
      }
      __builtin_amdgcn_s_setprio(0);
    }

    // Prefetch next iteration's Q tile0 into vs[0]: all vs reads are complete
    // (vmcnt(0) at ks=15); DMA latency hides under the epilogue below.
    if (it < 3) {
      const int bn = ((id & 7) << 2) | (it + 1);
      stage32(qt + (size_t)bn * C_ * DQ_, DQ_, (bf16_t*)vs[0], wave, lane);
    }

    const float alpha = alphap[0];
#pragma unroll
    for (int i = 0; i < 2; ++i)
#pragma unroll
      for (int jn = 0; jn < 2; ++jn)
#pragma unroll
        for (int r = 0; r < 4; ++r) {
          const int c = c0 + i * 16 + quad * 4 + r;
          const int n = wave * 32 + jn * 16 + l16;
          const size_t idx = ((size_t)b * C_ + c) * N_ + n;
          out[idx] = alpha * (oacc[i][jn][r] * rowrinv[i * 16 + quad * 4 + r]) + x[idx];
        }
  }
}

extern "C" void kernel_launch(void* const* d_in, const int* in_sizes, int n_in,
                              void* d_out, int out_size, void* d_ws, size_t ws_size,
                              hipStream_t stream) {
  const float* x    = (const float*)d_in[0];
  const float* Wq   = (const float*)d_in[1];
  const float* Wk   = (const float*)d_in[2];
  const float* Wv   = (const float*)d_in[3];
  const float* bn1g = (const float*)d_in[4];
  const float* bn1b = (const float*)d_in[5];
  const float* bn1m = (const float*)d_in[6];
  const float* bn1v = (const float*)d_in[7];
  const float* bn2g = (const float*)d_in[8];
  const float* bn2b = (const float*)d_in[9];
  const float* bn2m = (const float*)d_in[10];
  const float* bn2v = (const float*)d_in[11];
  const float* bn3g = (const float*)d_in[12];
  const float* bn3b = (const float*)d_in[13];
  const float* bn3m = (const float*)d_in[14];
  const float* bn3v = (const float*)d_in[15];
  const float* alph = (const float*)d_in[16];
  float* outp = (float*)d_out;

  char* ws = (char*)d_ws;
  bf16_t* qt   = (bf16_t*)(ws);                              // 4 MiB  (B,C,DQ)
  bf16_t* kt   = (bf16_t*)(ws + (size_t)(4u << 20));         // 4 MiB  (B,C,DQ)
  bf16_t* vT   = (bf16_t*)(ws + (size_t)(8u << 20));         // 16 MiB (B,N,C)
  bf16_t* xT   = (bf16_t*)(ws + (size_t)(24u << 20));        // 16 MiB (B,N,C)
  bf16_t* Wvb  = (bf16_t*)(ws + (size_t)(40u << 20));        // 2 MiB  (C,C)
  bf16_t* Wqkb = (bf16_t*)(ws + (size_t)(42u << 20));        // 64 KiB (128,N)

  k_cvt<<<dim3(528), 256, 0, stream>>>(Wv, Wq, Wk, Wvb, Wqkb);
  k_qkt<<<dim3(16, 32), 256, 0, stream>>>(x, Wqkb,
                                          bn1g, bn1b, bn1m, bn1v,
                                          bn2g, bn2b, bn2m, bn2v, qt, kt, xT);
  k_vgemm<<<dim3(8, 64), 256, 0, stream>>>(Wvb, xT, bn3g, bn3b, bn3m, bn3v, vT);
  k_fused<<<dim3(256), 512, 0, stream>>>(qt, kt, vT, x, alph, outp);
}

// Round 17
// 219.894 us; speedup vs baseline: 1.2298x; 1.0090x over previous
//
#include <hip/hip_runtime.h>
#include <hip/hip_bf16.h>

#define B_  32
#define C_  1024
#define N_  256
#define DQ_ 64

typedef __bf16 bf16_t;
typedef __bf16 bf16x4 __attribute__((ext_vector_type(4)));
typedef __bf16 bf16x8 __attribute__((ext_vector_type(8)));
typedef float  f32x4  __attribute__((ext_vector_type(4)));

static __device__ __forceinline__ f32x4 mfma16(bf16x8 a, bf16x8 b, f32x4 c) {
  return __builtin_amdgcn_mfma_f32_16x16x32_bf16(a, b, c, 0, 0, 0);
}

static __device__ __forceinline__ bf16x8 ldcvt(const float* p) {
  const float4 a = *(const float4*)p;
  const float4 b = *(const float4*)(p + 4);
  bf16x8 r;
  r[0] = (bf16_t)a.x; r[1] = (bf16_t)a.y; r[2] = (bf16_t)a.z; r[3] = (bf16_t)a.w;
  r[4] = (bf16_t)b.x; r[5] = (bf16_t)b.y; r[6] = (bf16_t)b.z; r[7] = (bf16_t)b.w;
  return r;
}

// Swizzled global->LDS staging, 32 rows/wave (4 loads). Row r, slot j holds
// global chunk (j - r) & 7. Wave w touches only rows [w*32, w*32+32).
static __device__ __forceinline__ void stage32(const bf16_t* grow0, size_t gstride,
                                               bf16_t* tile, int wave, int lane) {
#pragma unroll
  for (int t = 0; t < 4; ++t) {
    const int rb = wave * 32 + t * 8;
    const int r  = rb + (lane >> 3);
    const int g  = ((lane & 7) - r) & 7;
    const bf16_t* src = grow0 + (size_t)r * gstride + g * 8;
    __builtin_amdgcn_global_load_lds(
        (const __attribute__((address_space(1))) void*)src,
        (__attribute__((address_space(3))) void*)(tile + rb * 64), 16, 0, 0);
  }
}

// ---------------- Kernel CVT: Wv, Wq, Wk f32 -> bf16 ----------------
__global__ __launch_bounds__(256) void k_cvt(const float* __restrict__ Wv,
                                             const float* __restrict__ Wq,
                                             const float* __restrict__ Wk,
                                             bf16_t* __restrict__ Wvb,
                                             bf16_t* __restrict__ Wqkb) {
  const int gid = blockIdx.x * 256 + threadIdx.x;
  if (blockIdx.x < 512) {
    const int i = gid * 8;
    *(bf16x8*)(Wvb + i) = ldcvt(Wv + i);
  } else {
    const int g2 = (gid - 512 * 256) * 8;
    if (g2 < 16384) *(bf16x8*)(Wqkb + g2) = ldcvt(Wq + g2);
    else            *(bf16x8*)(Wqkb + g2) = ldcvt(Wk + (g2 - 16384));
  }
}

// ---------------- Kernel 1: fused q+k projection + x transpose (r11) ----------
__global__ __launch_bounds__(256) void k_qkt(const float* __restrict__ x,
                                             const bf16_t* __restrict__ Wqkb,
                                             const float* __restrict__ g1,
                                             const float* __restrict__ b1,
                                             const float* __restrict__ m1,
                                             const float* __restrict__ v1,
                                             const float* __restrict__ g2,
                                             const float* __restrict__ b2,
                                             const float* __restrict__ m2,
                                             const float* __restrict__ v2,
                                             bf16_t* __restrict__ qt,
                                             bf16_t* __restrict__ kt,
                                             bf16_t* __restrict__ xT) {
  __shared__ __align__(16) bf16_t txp[64][264];
  __shared__ float bnsc[128], bnsh[128];
  const int tid  = threadIdx.x;
  const int wave = tid >> 6;
  const int lane = tid & 63;
  const int quad = lane >> 4;
  const int l16  = lane & 15;
  const int b    = blockIdx.y;
  const int c16  = blockIdx.x * 64 + wave * 16;
  const int cl   = wave * 16 + l16;
  const float* xb = x + (size_t)b * C_ * N_;

  if (tid < 128) {
    const int o = tid & 63;
    const bool isq = tid < 64;
    const float sc = (isq ? g1[o] : g2[o]) * rsqrtf((isq ? v1[o] : v2[o]) + 1e-5f);
    bnsc[tid] = sc;
    bnsh[tid] = (isq ? b1[o] : b2[o]) - (isq ? m1[o] : m2[o]) * sc;
  }

  f32x4 acc[8];
#pragma unroll
  for (int i = 0; i < 8; ++i) acc[i] = (f32x4){0.f, 0.f, 0.f, 0.f};

  for (int ks = 0; ks < 8; ++ks) {
    const int k0 = ks * 32 + quad * 8;
    const bf16x8 bx = ldcvt(xb + (size_t)(c16 + l16) * N_ + k0);
    *(bf16x8*)(&txp[cl][k0]) = bx;
#pragma unroll
    for (int i = 0; i < 8; ++i) {
      const bf16x8 aw = *(const bf16x8*)(Wqkb + (size_t)(i * 16 + l16) * N_ + k0);
      acc[i] = mfma16(aw, bx, acc[i]);
    }
  }
  __syncthreads();

  {
    bf16_t* xtb = xT + (size_t)b * N_ * C_ + (size_t)tid * C_ + blockIdx.x * 64;
#pragma unroll
    for (int cc = 0; cc < 8; ++cc) {
      bf16x8 o8;
#pragma unroll
      for (int j = 0; j < 8; ++j) o8[j] = txp[cc * 8 + j][tid];
      *(bf16x8*)(xtb + cc * 8) = o8;
    }
  }

  const int c = c16 + l16;
#pragma unroll
  for (int i = 0; i < 8; ++i) {
    const bool isq = (i < 4);
    bf16_t* dst = isq ? qt : kt;
    const int o0  = (i & 3) * 16 + quad * 4;
    const int bno = (isq ? 0 : 64) + o0;
    bf16x4 w;
#pragma unroll
    for (int r = 0; r < 4; ++r) {
      float y = acc[i][r] * bnsc[bno + r] + bnsh[bno + r];
      y = fmaxf(y, 0.f);
      w[r] = (bf16_t)y;
    }
    *(bf16x4*)(dst + ((size_t)b * C_ + c) * DQ_ + o0) = w;
  }
}

// ---------------- Kernel 2: v GEMM (r17: 8-wave, 16 waves/CU) ----------
// Same 128^2 tile and r16 two-barrier counted protocol, but 512 threads /
// 8 waves: per-wave output 64x32 (acc[4][2]); waves 0-3 stage the A-half,
// 4-7 the B-half (4 DMAs/wave -> vmcnt(4)). barrier_b still globalizes the
// "tile ks landed" guarantee (protocol safety identical to r16). LDS 64KB ->
// still 2 blocks/CU => waves/CU 8 -> 16 for latency hiding.
__global__ __launch_bounds__(512, 4) void k_vgemm(const bf16_t* __restrict__ Wvb,
                                                  const bf16_t* __restrict__ xT,
                                                  const float* __restrict__ g,
                                                  const float* __restrict__ be,
                                                  const float* __restrict__ mu,
                                                  const float* __restrict__ va,
                                                  bf16_t* __restrict__ vT) {
  __shared__ __align__(16) bf16_t As[2][128 * 64];
  __shared__ __align__(16) bf16_t Bs[2][128 * 64];
  const int tid  = threadIdx.x;
  const int wave = tid >> 6;          // 0..7
  const int lane = tid & 63;
  const int quad = lane >> 4;
  const int l16  = lane & 15;
  const int wid  = blockIdx.y * 8 + blockIdx.x;
  const int xcd  = wid & 7;
  const int j    = wid >> 3;
  const int o0 = (j >> 3) * 128;
  const int r0 = ((xcd << 3) | (j & 7)) * 128;
  const bf16_t* Ab = Wvb + (size_t)o0 * C_;
  const bf16_t* Bb = xT + (size_t)r0 * C_;
  const int wr = (wave >> 2) * 64;    // 0 or 64
  const int wc = (wave & 3) * 32;     // 0,32,64,96

  if (wave < 4) stage32(Ab, C_, (bf16_t*)As[0], wave, lane);
  else          stage32(Bb, C_, (bf16_t*)Bs[0], wave - 4, lane);

  f32x4 acc[4][2];
#pragma unroll
  for (int i = 0; i < 4; ++i)
#pragma unroll
    for (int j2 = 0; j2 < 2; ++j2) acc[i][j2] = (f32x4){0.f, 0.f, 0.f, 0.f};

  for (int ks = 0; ks < 16; ++ks) {
    __builtin_amdgcn_s_barrier();                 // (a) compute(ks-1) done everywhere
    if (ks < 15) {
      if (wave < 4) stage32(Ab + (ks + 1) * 64, C_, (bf16_t*)As[(ks + 1) & 1], wave, lane);
      else          stage32(Bb + (ks + 1) * 64, C_, (bf16_t*)Bs[(ks + 1) & 1], wave - 4, lane);
      asm volatile("s_waitcnt vmcnt(4)" ::: "memory");   // own S(ks) landed
    } else {
      asm volatile("s_waitcnt vmcnt(0)" ::: "memory");
    }
    __builtin_amdgcn_s_barrier();                 // (b) ALL waves' S(ks) landed
    const bf16_t* ca = As[ks & 1];
    const bf16_t* cb = Bs[ks & 1];
#pragma unroll
    for (int ksub = 0; ksub < 2; ++ksub) {
      bf16x8 a[4], bfr[2];
#pragma unroll
      for (int i = 0; i < 4; ++i) {
        const int r = wr + i * 16 + l16;
        const int s = ((ksub * 4 + quad) + r) & 7;
        a[i] = *(const bf16x8*)(ca + r * 64 + s * 8);
      }
#pragma unroll
      for (int j2 = 0; j2 < 2; ++j2) {
        const int r = wc + j2 * 16 + l16;
        const int s = ((ksub * 4 + quad) + r) & 7;
        bfr[j2] = *(const bf16x8*)(cb + r * 64 + s * 8);
      }
#pragma unroll
      for (int i = 0; i < 4; ++i)
#pragma unroll
        for (int j2 = 0; j2 < 2; ++j2)
          acc[i][j2] = mfma16(a[i], bfr[j2], acc[i][j2]);
    }
  }

#pragma unroll
  for (int i = 0; i < 4; ++i)
#pragma unroll
    for (int r = 0; r < 4; ++r) {
      const int o = o0 + wr + i * 16 + quad * 4 + r;
      const float sc = g[o] * rsqrtf(va[o] + 1e-5f);
      const float mm = mu[o], bt = be[o];
#pragma unroll
      for (int j2 = 0; j2 < 2; ++j2) {
        const int rG = r0 + wc + j2 * 16 + l16;
        float y = (acc[i][j2][r] - mm) * sc + bt;
        y = fmaxf(y, 0.f);
        vT[(size_t)rG * C_ + o] = (bf16_t)y;
      }
    }
}

// ---------------- Kernel 3: fused sim -> softmax -> out (r15-verified) --------
// Persistent 256-block grid, 4 iters/block, Q-tile0 prefetch, setprio; 8-wave
// barrier-free Phases A/C with per-wave counted vmcnt(4).
static __device__ __forceinline__ int eaddr(int c, int d) {
  const int ch = d >> 3;
  const int ph = (ch & ~7) | ((ch + c) & 7);
  return (c << 10) + (ph << 3) + (d & 7);
}

__global__ __launch_bounds__(512, 2) void k_fused(const bf16_t* __restrict__ qt,
                                                  const bf16_t* __restrict__ kt,
                                                  const bf16_t* __restrict__ vT,
                                                  const float* __restrict__ x,
                                                  const float* __restrict__ alphap,
                                                  float* __restrict__ out) {
  __shared__ __align__(16) bf16_t ebuf[32 * 1024];
  __shared__ __align__(16) bf16_t vs[2][256 * 64];
  __shared__ float redmin[8][32];
  __shared__ float redsum[8][32];
  __shared__ float rowmin[32];
  __shared__ float rowrinv[32];

  const int tid  = threadIdx.x;
  const int wave = tid >> 6;
  const int lane = tid & 63;
  const int quad = lane >> 4;
  const int l16  = lane & 15;
  const int id   = blockIdx.x;                 // 0..255
  const int c0   = ((id >> 3) & 31) << 5;

#pragma unroll 1
  for (int it = 0; it < 4; ++it) {
    const int b = ((id & 7) << 2) | it;
    const bf16_t* qb  = qt + (size_t)b * C_ * DQ_;
    const bf16_t* ktb = kt + ((size_t)b * C_ + c0) * DQ_;
    const bf16_t* vb  = vT + (size_t)b * N_ * C_;

    bf16x8 am[2][2];
#pragma unroll
    for (int i = 0; i < 2; ++i)
#pragma unroll
      for (int ksub = 0; ksub < 2; ++ksub)
        am[i][ksub] = *(const bf16x8*)(ktb + (size_t)(i * 16 + l16) * DQ_ + ksub * 32 + quad * 8);

    // ---- Phase A: sim (32 c x 1024 d), per-wave staged, barrier-free ----
    if (it == 0) stage32(qb, DQ_, (bf16_t*)vs[0], wave, lane);  // else: prefetched
    f32x4 sim[2][8];
#pragma unroll
    for (int i = 0; i < 2; ++i)
#pragma unroll
      for (int nt = 0; nt < 8; ++nt) sim[i][nt] = (f32x4){0.f, 0.f, 0.f, 0.f};

#pragma unroll
    for (int t = 0; t < 4; ++t) {
      if (t < 3) {
        stage32(qb + (size_t)(t + 1) * 256 * DQ_, DQ_, (bf16_t*)vs[(t + 1) & 1], wave, lane);
        asm volatile("s_waitcnt vmcnt(4)" ::: "memory");
      } else {
        asm volatile("s_waitcnt vmcnt(0)" ::: "memory");
      }
      const bf16_t* cur = vs[t & 1];
      __builtin_amdgcn_s_setprio(1);
#pragma unroll
      for (int jn = 0; jn < 2; ++jn) {
        const int r = wave * 32 + jn * 16 + l16;
#pragma unroll
        for (int ksub = 0; ksub < 2; ++ksub) {
          const int s = ((ksub * 4 + quad) + r) & 7;
          const bf16x8 bq = *(const bf16x8*)(cur + r * 64 + s * 8);
          sim[0][t * 2 + jn] = mfma16(am[0][ksub], bq, sim[0][t * 2 + jn]);
          sim[1][t * 2 + jn] = mfma16(am[1][ksub], bq, sim[1][t * 2 + jn]);
        }
      }
      __builtin_amdgcn_s_setprio(0);
    }

    // Prologue staging for Phase C (latency hidden under Phase B)
    stage32(vb, C_, (bf16_t*)vs[0], wave, lane);

    // ---- Phase B: row-min shift, exp, row-sum (ebuf cross-wave: barriers) ----
    float pmin[2][4];
#pragma unroll
    for (int i = 0; i < 2; ++i)
#pragma unroll
      for (int r = 0; r < 4; ++r) pmin[i][r] = sim[i][0][r];
#pragma unroll
    for (int nt = 1; nt < 8; ++nt)
#pragma unroll
      for (int i = 0; i < 2; ++i)
#pragma unroll
        for (int r = 0; r < 4; ++r) pmin[i][r] = fminf(pmin[i][r], sim[i][nt][r]);
#pragma unroll
    for (int m = 1; m < 16; m <<= 1)
#pragma unroll
      for (int i = 0; i < 2; ++i)
#pragma unroll
        for (int r = 0; r < 4; ++r) pmin[i][r] = fminf(pmin[i][r], __shfl_xor(pmin[i][r], m));
    if (l16 == 0)
#pragma unroll
      for (int i = 0; i < 2; ++i)
#pragma unroll
        for (int r = 0; r < 4; ++r) redmin[wave][i * 16 + quad * 4 + r] = pmin[i][r];
    __syncthreads();
    if (tid < 32) {
      float v = redmin[0][tid];
#pragma unroll
      for (int w = 1; w < 8; ++w) v = fminf(v, redmin[w][tid]);
      rowmin[tid] = v;
    }
    __syncthreads();

    float mn[2][4], psum[2][4];
#pragma unroll
    for (int i = 0; i < 2; ++i)
#pragma unroll
      for (int r = 0; r < 4; ++r) {
        mn[i][r] = rowmin[i * 16 + quad * 4 + r];
        psum[i][r] = 0.f;
      }
#pragma unroll
    for (int nt = 0; nt < 8; ++nt) {
      const int d = ((nt >> 1) << 8) + wave * 32 + ((nt & 1) << 4) + l16;
#pragma unroll
      for (int i = 0; i < 2; ++i)
#pragma unroll
        for (int r = 0; r < 4; ++r) {
          const int c = i * 16 + quad * 4 + r;
          const float e = __expf(mn[i][r] - sim[i][nt][r]);
          ebuf[eaddr(c, d)] = (bf16_t)e;
          psum[i][r] += e;
        }
    }
#pragma unroll
    for (int m = 1; m < 16; m <<= 1)
#pragma unroll
      for (int i = 0; i < 2; ++i)
#pragma unroll
        for (int r = 0; r < 4; ++r) psum[i][r] += __shfl_xor(psum[i][r], m);
    if (l16 == 0)
#pragma unroll
      for (int i = 0; i < 2; ++i)
#pragma unroll
        for (int r = 0; r < 4; ++r) redsum[wave][i * 16 + quad * 4 + r] = psum[i][r];
    __syncthreads();
    if (tid < 32) {
      float s = redsum[0][tid];
#pragma unroll
      for (int w = 1; w < 8; ++w) s += redsum[w][tid];
      rowrinv[tid] = 1.f / s;
    }
    __syncthreads();   // ebuf + rowrinv visible; also drains V prologue

    // ---- Phase C: out = e @ vT, per-wave staged, barrier-free ----
    f32x4 oacc[2][2];
#pragma unroll
    for (int i = 0; i < 2; ++i)
#pragma unroll
      for (int jn = 0; jn < 2; ++jn) oacc[i][jn] = (f32x4){0.f, 0.f, 0.f, 0.f};

#pragma unroll
    for (int ks = 0; ks < 16; ++ks) {
      if (ks < 15) {
        stage32(vb + (ks + 1) * 64, C_, (bf16_t*)vs[(ks + 1) & 1], wave, lane);
        asm volatile("s_waitcnt vmcnt(4)" ::: "memory");
      } else {
        asm volatile("s_waitcnt vmcnt(0)" ::: "memory");
      }
      const bf16_t* cur = vs[ks & 1];
      __builtin_amdgcn_s_setprio(1);
#pragma unroll
      for (int ksub = 0; ksub < 2; ++ksub) {
        const int gch = ks * 8 + ksub * 4 + quad;
        const int ph  = (gch & ~7) | ((gch + l16) & 7);
        const bf16x8 ae0 = *(const bf16x8*)(ebuf + ((size_t)l16 << 10) + ph * 8);
        const bf16x8 ae1 = *(const bf16x8*)(ebuf + ((size_t)(16 + l16) << 10) + ph * 8);
#pragma unroll
        for (int jn = 0; jn < 2; ++jn) {
          const int r = wave * 32 + jn * 16 + l16;
          const int s = ((ksub * 4 + quad) + r) & 7;
          const bf16x8 bv = *(const bf16x8*)(cur + r * 64 + s * 8);
          oacc[0][jn] = mfma16(ae0, bv, oacc[0][jn]);
          oacc[1][jn] = mfma16(ae1, bv, oacc[1][jn]);
        }
      }
      __builtin_amdgcn_s_setprio(0);
    }

    // Prefetch next iteration's Q tile0 into vs[0]: all vs reads are complete
    // (vmcnt(0) at ks=15); DMA latency hides under the epilogue below.
    if (it < 3) {
      const int bn = ((id & 7) << 2) | (it + 1);
      stage32(qt + (size_t)bn * C_ * DQ_, DQ_, (bf16_t*)vs[0], wave, lane);
    }

    const float alpha = alphap[0];
#pragma unroll
    for (int i = 0; i < 2; ++i)
#pragma unroll
      for (int jn = 0; jn < 2; ++jn)
#pragma unroll
        for (int r = 0; r < 4; ++r) {
          const int c = c0 + i * 16 + quad * 4 + r;
          const int n = wave * 32 + jn * 16 + l16;
          const size_t idx = ((size_t)b * C_ + c) * N_ + n;
          out[idx] = alpha * (oacc[i][jn][r] * rowrinv[i * 16 + quad * 4 + r]) + x[idx];
        }
  }
}

extern "C" void kernel_launch(void* const* d_in, const int* in_sizes, int n_in,
                              void* d_out, int out_size, void* d_ws, size_t ws_size,
                              hipStream_t stream) {
  const float* x    = (const float*)d_in[0];
  const float* Wq   = (const float*)d_in[1];
  const float* Wk   = (const float*)d_in[2];
  const float* Wv   = (const float*)d_in[3];
  const float* bn1g = (const float*)d_in[4];
  const float* bn1b = (const float*)d_in[5];
  const float* bn1m = (const float*)d_in[6];
  const float* bn1v = (const float*)d_in[7];
  const float* bn2g = (const float*)d_in[8];
  const float* bn2b = (const float*)d_in[9];
  const float* bn2m = (const float*)d_in[10];
  const float* bn2v = (const float*)d_in[11];
  const float* bn3g = (const float*)d_in[12];
  const float* bn3b = (const float*)d_in[13];
  const float* bn3m = (const float*)d_in[14];
  const float* bn3v = (const float*)d_in[15];
  const float* alph = (const float*)d_in[16];
  float* outp = (float*)d_out;

  char* ws = (char*)d_ws;
  bf16_t* qt   = (bf16_t*)(ws);                              // 4 MiB  (B,C,DQ)
  bf16_t* kt   = (bf16_t*)(ws + (size_t)(4u << 20));         // 4 MiB  (B,C,DQ)
  bf16_t* vT   = (bf16_t*)(ws + (size_t)(8u << 20));         // 16 MiB (B,N,C)
  bf16_t* xT   = (bf16_t*)(ws + (size_t)(24u << 20));        // 16 MiB (B,N,C)
  bf16_t* Wvb  = (bf16_t*)(ws + (size_t)(40u << 20));        // 2 MiB  (C,C)
  bf16_t* Wqkb = (bf16_t*)(ws + (size_t)(42u << 20));        // 64 KiB (128,N)

  k_cvt<<<dim3(528), 256, 0, stream>>>(Wv, Wq, Wk, Wvb, Wqkb);
  k_qkt<<<dim3(16, 32), 256, 0, stream>>>(x, Wqkb,
                                          bn1g, bn1b, bn1m, bn1v,
                                          bn2g, bn2b, bn2m, bn2v, qt, kt, xT);
  k_vgemm<<<dim3(8, 64), 512, 0, stream>>>(Wvb, xT, bn3g, bn3b, bn3m, bn3v, vT);
  k_fused<<<dim3(256), 512, 0, stream>>>(qt, kt, vT, x, alph, outp);
}

// Round 18
// 218.675 us; speedup vs baseline: 1.2367x; 1.0056x over previous
//
#include <hip/hip_runtime.h>
#include <hip/hip_bf16.h>

#define B_  32
#define C_  1024
#define N_  256
#define DQ_ 64

typedef __bf16 bf16_t;
typedef __bf16 bf16x4 __attribute__((ext_vector_type(4)));
typedef __bf16 bf16x8 __attribute__((ext_vector_type(8)));
typedef float  f32x4  __attribute__((ext_vector_type(4)));

static __device__ __forceinline__ f32x4 mfma16(bf16x8 a, bf16x8 b, f32x4 c) {
  return __builtin_amdgcn_mfma_f32_16x16x32_bf16(a, b, c, 0, 0, 0);
}

static __device__ __forceinline__ bf16x8 ldcvt(const float* p) {
  const float4 a = *(const float4*)p;
  const float4 b = *(const float4*)(p + 4);
  bf16x8 r;
  r[0] = (bf16_t)a.x; r[1] = (bf16_t)a.y; r[2] = (bf16_t)a.z; r[3] = (bf16_t)a.w;
  r[4] = (bf16_t)b.x; r[5] = (bf16_t)b.y; r[6] = (bf16_t)b.z; r[7] = (bf16_t)b.w;
  return r;
}

// Raw barrier, LDS-ordering only: does NOT drain vmcnt, so in-flight DMAs
// (Q-prefetch) survive. Used only where the fence is about LDS visibility.
#define BAR_LGKM() do { \
  asm volatile("s_waitcnt lgkmcnt(0)" ::: "memory"); \
  __builtin_amdgcn_s_barrier(); \
} while (0)

// Swizzled global->LDS staging, 32 rows/wave (4 loads). Row r, slot j holds
// global chunk (j - r) & 7. Wave w touches only rows [w*32, w*32+32).
static __device__ __forceinline__ void stage32(const bf16_t* grow0, size_t gstride,
                                               bf16_t* tile, int wave, int lane) {
#pragma unroll
  for (int t = 0; t < 4; ++t) {
    const int rb = wave * 32 + t * 8;
    const int r  = rb + (lane >> 3);
    const int g  = ((lane & 7) - r) & 7;
    const bf16_t* src = grow0 + (size_t)r * gstride + g * 8;
    __builtin_amdgcn_global_load_lds(
        (const __attribute__((address_space(1))) void*)src,
        (__attribute__((address_space(3))) void*)(tile + rb * 64), 16, 0, 0);
  }
}

// ---------------- Kernel CVT: Wv, Wq, Wk f32 -> bf16 ----------------
__global__ __launch_bounds__(256) void k_cvt(const float* __restrict__ Wv,
                                             const float* __restrict__ Wq,
                                             const float* __restrict__ Wk,
                                             bf16_t* __restrict__ Wvb,
                                             bf16_t* __restrict__ Wqkb) {
  const int gid = blockIdx.x * 256 + threadIdx.x;
  if (blockIdx.x < 512) {
    const int i = gid * 8;
    *(bf16x8*)(Wvb + i) = ldcvt(Wv + i);
  } else {
    const int g2 = (gid - 512 * 256) * 8;
    if (g2 < 16384) *(bf16x8*)(Wqkb + g2) = ldcvt(Wq + g2);
    else            *(bf16x8*)(Wqkb + g2) = ldcvt(Wk + (g2 - 16384));
  }
}

// ---------------- Kernel 1: fused q+k projection + x transpose (r11) ----------
__global__ __launch_bounds__(256) void k_qkt(const float* __restrict__ x,
                                             const bf16_t* __restrict__ Wqkb,
                                             const float* __restrict__ g1,
                                             const float* __restrict__ b1,
                                             const float* __restrict__ m1,
                                             const float* __restrict__ v1,
                                             const float* __restrict__ g2,
                                             const float* __restrict__ b2,
                                             const float* __restrict__ m2,
                                             const float* __restrict__ v2,
                                             bf16_t* __restrict__ qt,
                                             bf16_t* __restrict__ kt,
                                             bf16_t* __restrict__ xT) {
  __shared__ __align__(16) bf16_t txp[64][264];
  __shared__ float bnsc[128], bnsh[128];
  const int tid  = threadIdx.x;
  const int wave = tid >> 6;
  const int lane = tid & 63;
  const int quad = lane >> 4;
  const int l16  = lane & 15;
  const int b    = blockIdx.y;
  const int c16  = blockIdx.x * 64 + wave * 16;
  const int cl   = wave * 16 + l16;
  const float* xb = x + (size_t)b * C_ * N_;

  if (tid < 128) {
    const int o = tid & 63;
    const bool isq = tid < 64;
    const float sc = (isq ? g1[o] : g2[o]) * rsqrtf((isq ? v1[o] : v2[o]) + 1e-5f);
    bnsc[tid] = sc;
    bnsh[tid] = (isq ? b1[o] : b2[o]) - (isq ? m1[o] : m2[o]) * sc;
  }

  f32x4 acc[8];
#pragma unroll
  for (int i = 0; i < 8; ++i) acc[i] = (f32x4){0.f, 0.f, 0.f, 0.f};

  for (int ks = 0; ks < 8; ++ks) {
    const int k0 = ks * 32 + quad * 8;
    const bf16x8 bx = ldcvt(xb + (size_t)(c16 + l16) * N_ + k0);
    *(bf16x8*)(&txp[cl][k0]) = bx;
#pragma unroll
    for (int i = 0; i < 8; ++i) {
      const bf16x8 aw = *(const bf16x8*)(Wqkb + (size_t)(i * 16 + l16) * N_ + k0);
      acc[i] = mfma16(aw, bx, acc[i]);
    }
  }
  __syncthreads();

  {
    bf16_t* xtb = xT + (size_t)b * N_ * C_ + (size_t)tid * C_ + blockIdx.x * 64;
#pragma unroll
    for (int cc = 0; cc < 8; ++cc) {
      bf16x8 o8;
#pragma unroll
      for (int j = 0; j < 8; ++j) o8[j] = txp[cc * 8 + j][tid];
      *(bf16x8*)(xtb + cc * 8) = o8;
    }
  }

  const int c = c16 + l16;
#pragma unroll
  for (int i = 0; i < 8; ++i) {
    const bool isq = (i < 4);
    bf16_t* dst = isq ? qt : kt;
    const int o0  = (i & 3) * 16 + quad * 4;
    const int bno = (isq ? 0 : 64) + o0;
    bf16x4 w;
#pragma unroll
    for (int r = 0; r < 4; ++r) {
      float y = acc[i][r] * bnsc[bno + r] + bnsh[bno + r];
      y = fmaxf(y, 0.f);
      w[r] = (bf16_t)y;
    }
    *(bf16x4*)(dst + ((size_t)b * C_ + c) * DQ_ + o0) = w;
  }
}

// ---------------- Kernel 2: v GEMM (r17-verified: 8-wave, counted barriers) ---
__global__ __launch_bounds__(512, 4) void k_vgemm(const bf16_t* __restrict__ Wvb,
                                                  const bf16_t* __restrict__ xT,
                                                  const float* __restrict__ g,
                                                  const float* __restrict__ be,
                                                  const float* __restrict__ mu,
                                                  const float* __restrict__ va,
                                                  bf16_t* __restrict__ vT) {
  __shared__ __align__(16) bf16_t As[2][128 * 64];
  __shared__ __align__(16) bf16_t Bs[2][128 * 64];
  const int tid  = threadIdx.x;
  const int wave = tid >> 6;          // 0..7
  const int lane = tid & 63;
  const int quad = lane >> 4;
  const int l16  = lane & 15;
  const int wid  = blockIdx.y * 8 + blockIdx.x;
  const int xcd  = wid & 7;
  const int j    = wid >> 3;
  const int o0 = (j >> 3) * 128;
  const int r0 = ((xcd << 3) | (j & 7)) * 128;
  const bf16_t* Ab = Wvb + (size_t)o0 * C_;
  const bf16_t* Bb = xT + (size_t)r0 * C_;
  const int wr = (wave >> 2) * 64;    // 0 or 64
  const int wc = (wave & 3) * 32;     // 0,32,64,96

  if (wave < 4) stage32(Ab, C_, (bf16_t*)As[0], wave, lane);
  else          stage32(Bb, C_, (bf16_t*)Bs[0], wave - 4, lane);

  f32x4 acc[4][2];
#pragma unroll
  for (int i = 0; i < 4; ++i)
#pragma unroll
    for (int j2 = 0; j2 < 2; ++j2) acc[i][j2] = (f32x4){0.f, 0.f, 0.f, 0.f};

  for (int ks = 0; ks < 16; ++ks) {
    __builtin_amdgcn_s_barrier();                 // (a) compute(ks-1) done everywhere
    if (ks < 15) {
      if (wave < 4) stage32(Ab + (ks + 1) * 64, C_, (bf16_t*)As[(ks + 1) & 1], wave, lane);
      else          stage32(Bb + (ks + 1) * 64, C_, (bf16_t*)Bs[(ks + 1) & 1], wave - 4, lane);
      asm volatile("s_waitcnt vmcnt(4)" ::: "memory");   // own S(ks) landed
    } else {
      asm volatile("s_waitcnt vmcnt(0)" ::: "memory");
    }
    __builtin_amdgcn_s_barrier();                 // (b) ALL waves' S(ks) landed
    const bf16_t* ca = As[ks & 1];
    const bf16_t* cb = Bs[ks & 1];
#pragma unroll
    for (int ksub = 0; ksub < 2; ++ksub) {
      bf16x8 a[4], bfr[2];
#pragma unroll
      for (int i = 0; i < 4; ++i) {
        const int r = wr + i * 16 + l16;
        const int s = ((ksub * 4 + quad) + r) & 7;
        a[i] = *(const bf16x8*)(ca + r * 64 + s * 8);
      }
#pragma unroll
      for (int j2 = 0; j2 < 2; ++j2) {
        const int r = wc + j2 * 16 + l16;
        const int s = ((ksub * 4 + quad) + r) & 7;
        bfr[j2] = *(const bf16x8*)(cb + r * 64 + s * 8);
      }
#pragma unroll
      for (int i = 0; i < 4; ++i)
#pragma unroll
        for (int j2 = 0; j2 < 2; ++j2)
          acc[i][j2] = mfma16(a[i], bfr[j2], acc[i][j2]);
    }
  }

#pragma unroll
  for (int i = 0; i < 4; ++i)
#pragma unroll
    for (int r = 0; r < 4; ++r) {
      const int o = o0 + wr + i * 16 + quad * 4 + r;
      const float sc = g[o] * rsqrtf(va[o] + 1e-5f);
      const float mm = mu[o], bt = be[o];
#pragma unroll
      for (int j2 = 0; j2 < 2; ++j2) {
        const int rG = r0 + wc + j2 * 16 + l16;
        float y = (acc[i][j2][r] - mm) * sc + bt;
        y = fmaxf(y, 0.f);
        vT[(size_t)rG * C_ + o] = (bf16_t)y;
      }
    }
}

// ---------------- Kernel 3: fused sim -> softmax -> out (r18: vec epilogue) ---
// r15 persistent structure + vectorized epilogue: x prefetched as 4x float4
// per thread before Phase B (drained free at Phase B's barrier); after Phase C,
// alpha*oacc*rinv repacked through vs[1] as f32[32][256]; re-read with flat
// mapping (each wave = one contiguous 1KB c-row) -> float4 x/out, conflict-free
// ds_read_b128. lgkm-only barriers fence the repack (vs[1] spans all rows,
// breaking per-wave privacy) without draining the in-flight Q-prefetch DMAs.
static __device__ __forceinline__ int eaddr(int c, int d) {
  const int ch = d >> 3;
  const int ph = (ch & ~7) | ((ch + c) & 7);
  return (c << 10) + (ph << 3) + (d & 7);
}

__global__ __launch_bounds__(512, 2) void k_fused(const bf16_t* __restrict__ qt,
                                                  const bf16_t* __restrict__ kt,
                                                  const bf16_t* __restrict__ vT,
                                                  const float* __restrict__ x,
                                                  const float* __restrict__ alphap,
                                                  float* __restrict__ out) {
  __shared__ __align__(16) bf16_t ebuf[32 * 1024];
  __shared__ __align__(16) bf16_t vs[2][256 * 64];
  __shared__ float redmin[8][32];
  __shared__ float redsum[8][32];
  __shared__ float rowmin[32];
  __shared__ float rowrinv[32];

  const int tid  = threadIdx.x;
  const int wave = tid >> 6;
  const int lane = tid & 63;
  const int quad = lane >> 4;
  const int l16  = lane & 15;
  const int id   = blockIdx.x;                 // 0..255
  const int c0   = ((id >> 3) & 31) << 5;
  const float alpha = alphap[0];

#pragma unroll 1
  for (int it = 0; it < 4; ++it) {
    const int b = ((id & 7) << 2) | it;
    const bf16_t* qb  = qt + (size_t)b * C_ * DQ_;
    const bf16_t* ktb = kt + ((size_t)b * C_ + c0) * DQ_;
    const bf16_t* vb  = vT + (size_t)b * N_ * C_;

    bf16x8 am[2][2];
#pragma unroll
    for (int i = 0; i < 2; ++i)
#pragma unroll
      for (int ksub = 0; ksub < 2; ++ksub)
        am[i][ksub] = *(const bf16x8*)(ktb + (size_t)(i * 16 + l16) * DQ_ + ksub * 32 + quad * 8);

    // ---- Phase A: sim (32 c x 1024 d), per-wave staged, barrier-free ----
    if (it == 0) stage32(qb, DQ_, (bf16_t*)vs[0], wave, lane);  // else: prefetched
    f32x4 sim[2][8];
#pragma unroll
    for (int i = 0; i < 2; ++i)
#pragma unroll
      for (int nt = 0; nt < 8; ++nt) sim[i][nt] = (f32x4){0.f, 0.f, 0.f, 0.f};

#pragma unroll
    for (int t = 0; t < 4; ++t) {
      if (t < 3) {
        stage32(qb + (size_t)(t + 1) * 256 * DQ_, DQ_, (bf16_t*)vs[(t + 1) & 1], wave, lane);
        asm volatile("s_waitcnt vmcnt(4)" ::: "memory");
      } else {
        asm volatile("s_waitcnt vmcnt(0)" ::: "memory");
      }
      const bf16_t* cur = vs[t & 1];
      __builtin_amdgcn_s_setprio(1);
#pragma unroll
      for (int jn = 0; jn < 2; ++jn) {
        const int r = wave * 32 + jn * 16 + l16;
#pragma unroll
        for (int ksub = 0; ksub < 2; ++ksub) {
          const int s = ((ksub * 4 + quad) + r) & 7;
          const bf16x8 bq = *(const bf16x8*)(cur + r * 64 + s * 8);
          sim[0][t * 2 + jn] = mfma16(am[0][ksub], bq, sim[0][t * 2 + jn]);
          sim[1][t * 2 + jn] = mfma16(am[1][ksub], bq, sim[1][t * 2 + jn]);
        }
      }
      __builtin_amdgcn_s_setprio(0);
    }

    // x epilogue prefetch (independent; drains for free at Phase B's barrier).
    // Flat mapping: f = g*2048 + tid*4 over f32[32 c][256 n]; c=f>>8, n=f&255.
    float4 xr[4];
#pragma unroll
    for (int gph = 0; gph < 4; ++gph) {
      const int f0 = gph * 2048 + tid * 4;
      xr[gph] = *(const float4*)(x + ((size_t)b * C_ + c0 + (f0 >> 8)) * N_ + (f0 & 255));
    }

    // Prologue staging for Phase C (latency hidden under Phase B)
    stage32(vb, C_, (bf16_t*)vs[0], wave, lane);

    // ---- Phase B: row-min shift, exp, row-sum (ebuf cross-wave: barriers) ----
    float pmin[2][4];
#pragma unroll
    for (int i = 0; i < 2; ++i)
#pragma unroll
      for (int r = 0; r < 4; ++r) pmin[i][r] = sim[i][0][r];
#pragma unroll
    for (int nt = 1; nt < 8; ++nt)
#pragma unroll
      for (int i = 0; i < 2; ++i)
#pragma unroll
        for (int r = 0; r < 4; ++r) pmin[i][r] = fminf(pmin[i][r], sim[i][nt][r]);
#pragma unroll
    for (int m = 1; m < 16; m <<= 1)
#pragma unroll
      for (int i = 0; i < 2; ++i)
#pragma unroll
        for (int r = 0; r < 4; ++r) pmin[i][r] = fminf(pmin[i][r], __shfl_xor(pmin[i][r], m));
    if (l16 == 0)
#pragma unroll
      for (int i = 0; i < 2; ++i)
#pragma unroll
        for (int r = 0; r < 4; ++r) redmin[wave][i * 16 + quad * 4 + r] = pmin[i][r];
    __syncthreads();
    if (tid < 32) {
      float v = redmin[0][tid];
#pragma unroll
      for (int w = 1; w < 8; ++w) v = fminf(v, redmin[w][tid]);
      rowmin[tid] = v;
    }
    __syncthreads();

    float mn[2][4], psum[2][4];
#pragma unroll
    for (int i = 0; i < 2; ++i)
#pragma unroll
      for (int r = 0; r < 4; ++r) {
        mn[i][r] = rowmin[i * 16 + quad * 4 + r];
        psum[i][r] = 0.f;
      }
#pragma unroll
    for (int nt = 0; nt < 8; ++nt) {
      const int d = ((nt >> 1) << 8) + wave * 32 + ((nt & 1) << 4) + l16;
#pragma unroll
      for (int i = 0; i < 2; ++i)
#pragma unroll
        for (int r = 0; r < 4; ++r) {
          const int c = i * 16 + quad * 4 + r;
          const float e = __expf(mn[i][r] - sim[i][nt][r]);
          ebuf[eaddr(c, d)] = (bf16_t)e;
          psum[i][r] += e;
        }
    }
#pragma unroll
    for (int m = 1; m < 16; m <<= 1)
#pragma unroll
      for (int i = 0; i < 2; ++i)
#pragma unroll
        for (int r = 0; r < 4; ++r) psum[i][r] += __shfl_xor(psum[i][r], m);
    if (l16 == 0)
#pragma unroll
      for (int i = 0; i < 2; ++i)
#pragma unroll
        for (int r = 0; r < 4; ++r) redsum[wave][i * 16 + quad * 4 + r] = psum[i][r];
    __syncthreads();
    if (tid < 32) {
      float s = redsum[0][tid];
#pragma unroll
      for (int w = 1; w < 8; ++w) s += redsum[w][tid];
      rowrinv[tid] = 1.f / s;
    }
    __syncthreads();   // ebuf + rowrinv visible; also drains V prologue

    // ---- Phase C: out = e @ vT, per-wave staged, barrier-free ----
    f32x4 oacc[2][2];
#pragma unroll
    for (int i = 0; i < 2; ++i)
#pragma unroll
      for (int jn = 0; jn < 2; ++jn) oacc[i][jn] = (f32x4){0.f, 0.f, 0.f, 0.f};

#pragma unroll
    for (int ks = 0; ks < 16; ++ks) {
      if (ks < 15) {
        stage32(vb + (ks + 1) * 64, C_, (bf16_t*)vs[(ks + 1) & 1], wave, lane);
        asm volatile("s_waitcnt vmcnt(4)" ::: "memory");
      } else {
        asm volatile("s_waitcnt vmcnt(0)" ::: "memory");
      }
      const bf16_t* cur = vs[ks & 1];
      __builtin_amdgcn_s_setprio(1);
#pragma unroll
      for (int ksub = 0; ksub < 2; ++ksub) {
        const int gch = ks * 8 + ksub * 4 + quad;
        const int ph  = (gch & ~7) | ((gch + l16) & 7);
        const bf16x8 ae0 = *(const bf16x8*)(ebuf + ((size_t)l16 << 10) + ph * 8);
        const bf16x8 ae1 = *(const bf16x8*)(ebuf + ((size_t)(16 + l16) << 10) + ph * 8);
#pragma unroll
        for (int jn = 0; jn < 2; ++jn) {
          const int r = wave * 32 + jn * 16 + l16;
          const int s = ((ksub * 4 + quad) + r) & 7;
          const bf16x8 bv = *(const bf16x8*)(cur + r * 64 + s * 8);
          oacc[0][jn] = mfma16(ae0, bv, oacc[0][jn]);
          oacc[1][jn] = mfma16(ae1, bv, oacc[1][jn]);
        }
      }
      __builtin_amdgcn_s_setprio(0);
    }

    // Q-prefetch for next iter into vs[0]: per-wave-private rows, safe without
    // a barrier (same as r15); issued before the repack fences so the DMA
    // latency hides under the epilogue.
    if (it < 3) {
      const int bn = ((id & 7) << 2) | (it + 1);
      stage32(qt + (size_t)bn * C_ * DQ_, DQ_, (bf16_t*)vs[0], wave, lane);
    }

    // ---- Vectorized epilogue via f32 repack in vs[1] ----
    BAR_LGKM();                              // all waves' Phase C ds_reads done
    float* lf = (float*)vs[1];
#pragma unroll
    for (int i = 0; i < 2; ++i)
#pragma unroll
      for (int jn = 0; jn < 2; ++jn)
#pragma unroll
        for (int r = 0; r < 4; ++r) {
          const int cl2 = i * 16 + quad * 4 + r;
          const int n   = wave * 32 + jn * 16 + l16;
          lf[cl2 * 256 + n] = alpha * (oacc[i][jn][r] * rowrinv[cl2]);
        }
    BAR_LGKM();                              // repack visible to all waves
#pragma unroll
    for (int gph = 0; gph < 4; ++gph) {
      const int f0 = gph * 2048 + tid * 4;
      const float4 ov = *(const float4*)(lf + f0);
      float4 res;
      res.x = ov.x + xr[gph].x; res.y = ov.y + xr[gph].y;
      res.z = ov.z + xr[gph].z; res.w = ov.w + xr[gph].w;
      *(float4*)(out + ((size_t)b * C_ + c0 + (f0 >> 8)) * N_ + (f0 & 255)) = res;
    }
    BAR_LGKM();                              // epilogue lf reads done before
  }                                          // next iter stages vs[1] at t=0
}

extern "C" void kernel_launch(void* const* d_in, const int* in_sizes, int n_in,
                              void* d_out, int out_size, void* d_ws, size_t ws_size,
                              hipStream_t stream) {
  const float* x    = (const float*)d_in[0];
  const float* Wq   = (const float*)d_in[1];
  const float* Wk   = (const float*)d_in[2];
  const float* Wv   = (const float*)d_in[3];
  const float* bn1g = (const float*)d_in[4];
  const float* bn1b = (const float*)d_in[5];
  const float* bn1m = (const float*)d_in[6];
  const float* bn1v = (const float*)d_in[7];
  const float* bn2g = (const float*)d_in[8];
  const float* bn2b = (const float*)d_in[9];
  const float* bn2m = (const float*)d_in[10];
  const float* bn2v = (const float*)d_in[11];
  const float* bn3g = (const float*)d_in[12];
  const float* bn3b = (const float*)d_in[13];
  const float* bn3m = (const float*)d_in[14];
  const float* bn3v = (const float*)d_in[15];
  const float* alph = (const float*)d_in[16];
  float* outp = (float*)d_out;

  char* ws = (char*)d_ws;
  bf16_t* qt   = (bf16_t*)(ws);                              // 4 MiB  (B,C,DQ)
  bf16_t* kt   = (bf16_t*)(ws + (size_t)(4u << 20));         // 4 MiB  (B,C,DQ)
  bf16_t* vT   = (bf16_t*)(ws + (size_t)(8u << 20));         // 16 MiB (B,N,C)
  bf16_t* xT   = (bf16_t*)(ws + (size_t)(24u << 20));        // 16 MiB (B,N,C)
  bf16_t* Wvb  = (bf16_t*)(ws + (size_t)(40u << 20));        // 2 MiB  (C,C)
  bf16_t* Wqkb = (bf16_t*)(ws + (size_t)(42u << 20));        // 64 KiB (128,N)

  k_cvt<<<dim3(528), 256, 0, stream>>>(Wv, Wq, Wk, Wvb, Wqkb);
  k_qkt<<<dim3(16, 32), 256, 0, stream>>>(x, Wqkb,
                                          bn1g, bn1b, bn1m, bn1v,
                                          bn2g, bn2b, bn2m, bn2v, qt, kt, xT);
  k_vgemm<<<dim3(8, 64), 512, 0, stream>>>(Wvb, xT, bn3g, bn3b, bn3m, bn3v, vT);
  k_fused<<<dim3(256), 512, 0, stream>>>(qt, kt, vT, x, alph, outp);
}